// Round 1
// baseline (4174.618 us; speedup 1.0000x reference)
//
#include <hip/hip_runtime.h>
#include <math.h>

#define N_  256
#define NN  65536
#define CZ  128
#define CH  128
#define H_  4
#define CA  32
#define PTH 512

__device__ __forceinline__ float sigmoidf_(float x){ return 1.f/(1.f+__expf(-x)); }

__device__ __forceinline__ float wave_red_sum(float v){
  #pragma unroll
  for(int o=32;o>0;o>>=1) v += __shfl_xor(v,o,64);
  return v;
}
__device__ __forceinline__ float wave_red_max(float v){
  #pragma unroll
  for(int o=32;o>0;o>>=1) v = fmaxf(v,__shfl_xor(v,o,64));
  return v;
}

// LayerNorm over last dim (128). One wave per row; lane handles c and c+64.
// TRANS: output row (i,j) reads input row (j,i)  (for ending-node attention).
template<bool TRANS>
__global__ void __launch_bounds__(256) ln_kernel(const float* __restrict__ in,
                                                 const float* __restrict__ w,
                                                 const float* __restrict__ b,
                                                 float* __restrict__ out){
  int wid  = threadIdx.x >> 6;
  int lane = threadIdx.x & 63;
  int row  = blockIdx.x*4 + wid;
  int irow;
  if (TRANS){ int i = row >> 8, j = row & 255; irow = (j<<8) | i; } else irow = row;
  float v0 = in[irow*CZ + lane];
  float v1 = in[irow*CZ + lane + 64];
  float m  = wave_red_sum(v0+v1) * (1.f/128.f);
  float d0 = v0-m, d1 = v1-m;
  float var = wave_red_sum(d0*d0 + d1*d1) * (1.f/128.f);
  float r = rsqrtf(var + 1e-5f);
  out[row*CZ + lane]      = d0*r*w[lane]    + b[lane];
  out[row*CZ + lane + 64] = d1*r*w[lane+64] + b[lane+64];
}

// out[r,c] = sigmoid(x@Wg + bg) * (x@Wp + bp)   -- [NN,128]x[128,128] dual GEMM
__global__ void __launch_bounds__(256) dual_gate_gemm(const float* __restrict__ X,
                                                      const float* __restrict__ Wg,
                                                      const float* __restrict__ bg,
                                                      const float* __restrict__ Wp,
                                                      const float* __restrict__ bp,
                                                      float* __restrict__ out){
  __shared__ float xs[32][CZ];
  int r0 = blockIdx.x * 32;
  for (int idx = threadIdx.x; idx < 32*CZ; idx += 256)
    xs[idx>>7][idx&127] = X[(r0 + (idx>>7))*CZ + (idx&127)];
  __syncthreads();
  int rr = threadIdx.x >> 7, c = threadIdx.x & 127;
  float ag[16], ap[16];
  #pragma unroll
  for(int r=0;r<16;r++){ ag[r]=0.f; ap[r]=0.f; }
  #pragma unroll 4
  for(int k=0;k<CZ;k++){
    float wg = Wg[k*CH + c];
    float wp = Wp[k*CH + c];
    #pragma unroll
    for(int r=0;r<16;r++){
      float xv = xs[rr*16+r][k];
      ag[r] += xv*wg; ap[r] += xv*wp;
    }
  }
  float bgc = bg[c], bpc = bp[c];
  #pragma unroll
  for(int r=0;r<16;r++)
    out[(r0+rr*16+r)*CH + c] = (ap[r]+bpc) * sigmoidf_(ag[r]+bgc);
}

// out[r,c] = (x@W)[r,c] * scale     (no bias; used for q/k/v)
__global__ void __launch_bounds__(256) gemm_scale(const float* __restrict__ X,
                                                  const float* __restrict__ W,
                                                  float* __restrict__ out, float scale){
  __shared__ float xs[32][CZ];
  int r0 = blockIdx.x * 32;
  for (int idx = threadIdx.x; idx < 32*CZ; idx += 256)
    xs[idx>>7][idx&127] = X[(r0 + (idx>>7))*CZ + (idx&127)];
  __syncthreads();
  int rr = threadIdx.x >> 7, c = threadIdx.x & 127;
  float acc[16];
  #pragma unroll
  for(int r=0;r<16;r++) acc[r]=0.f;
  #pragma unroll 4
  for(int k=0;k<CZ;k++){
    float w = W[k*CH + c];
    #pragma unroll
    for(int r=0;r<16;r++) acc[r] += xs[rr*16+r][k]*w;
  }
  #pragma unroll
  for(int r=0;r<16;r++)
    out[(r0+rr*16+r)*CH + c] = acc[r]*scale;
}

// Triangle einsum. OUTGOING: t[i,j,c] = sum_k a[i,k,c]*b[j,k,c]
//                  else:      t[i,j,c] = sum_k a[k,i,c]*b[k,j,c]
template<bool OUTGOING>
__global__ void __launch_bounds__(256) tri_einsum(const float* __restrict__ A,
                                                  const float* __restrict__ B,
                                                  float* __restrict__ T){
  __shared__ float as_[8][8][CH];   // [kk][ii][c]
  __shared__ float bs_[8][8][CH];   // [kk][jj][c]
  int i0 = blockIdx.x*8, j0 = blockIdx.y*8;
  int p = threadIdx.x >> 7, c = threadIdx.x & 127;
  float acc[8][4];
  #pragma unroll
  for(int a2=0;a2<8;a2++)
    #pragma unroll
    for(int b2=0;b2<4;b2++) acc[a2][b2]=0.f;
  for(int k0=0;k0<N_;k0+=8){
    __syncthreads();
    for(int idx=threadIdx.x; idx<8*8*CH; idx+=256){
      int cc = idx & 127, ii = (idx>>7)&7, kk = idx>>10;
      int arow = OUTGOING ? ((i0+ii)*N_ + k0+kk) : ((k0+kk)*N_ + i0+ii);
      int brow = OUTGOING ? ((j0+ii)*N_ + k0+kk) : ((k0+kk)*N_ + j0+ii);
      as_[kk][ii][cc] = A[arow*CH + cc];
      bs_[kk][ii][cc] = B[brow*CH + cc];
    }
    __syncthreads();
    #pragma unroll
    for(int kk=0;kk<8;kk++){
      float bv[4];
      #pragma unroll
      for(int jj=0;jj<4;jj++) bv[jj] = bs_[kk][p*4+jj][c];
      #pragma unroll
      for(int ii=0;ii<8;ii++){
        float av = as_[kk][ii][c];
        #pragma unroll
        for(int jj=0;jj<4;jj++) acc[ii][jj] += av*bv[jj];
      }
    }
  }
  #pragma unroll
  for(int ii=0;ii<8;ii++)
    #pragma unroll
    for(int jj=0;jj<4;jj++)
      T[((i0+ii)*N_ + j0 + p*4 + jj)*CH + c] = acc[ii][jj];
}

// z[r,c] += (t2@Wz + bz) * sigmoid(x@Wg + bg)
__global__ void __launch_bounds__(256) tri_finish(const float* __restrict__ T2,
                                                  const float* __restrict__ X,
                                                  const float* __restrict__ Wz,
                                                  const float* __restrict__ bz,
                                                  const float* __restrict__ Wg,
                                                  const float* __restrict__ bg,
                                                  float* __restrict__ z){
  __shared__ float ts[32][CH];
  __shared__ float xs[32][CZ];
  int r0 = blockIdx.x * 32;
  for (int idx = threadIdx.x; idx < 32*CZ; idx += 256){
    int r = idx>>7, cc = idx&127;
    ts[r][cc] = T2[(r0+r)*CH + cc];
    xs[r][cc] = X[(r0+r)*CZ + cc];
  }
  __syncthreads();
  int rr = threadIdx.x >> 7, c = threadIdx.x & 127;
  float az[16], ag[16];
  #pragma unroll
  for(int r=0;r<16;r++){ az[r]=0.f; ag[r]=0.f; }
  #pragma unroll 4
  for(int k=0;k<CZ;k++){
    float wz = Wz[k*CZ + c];
    float wg = Wg[k*CZ + c];
    #pragma unroll
    for(int r=0;r<16;r++){
      az[r] += ts[rr*16+r][k]*wz;
      ag[r] += xs[rr*16+r][k]*wg;
    }
  }
  float bzc = bz[c], bgc = bg[c];
  #pragma unroll
  for(int r=0;r<16;r++)
    z[(r0+rr*16+r)*CZ + c] += (az[r]+bzc) * sigmoidf_(ag[r]+bgc);
}

// bias[h, r] = x[r,:] @ bw[:,h]    stored BS[h*NN + r]
__global__ void __launch_bounds__(256) bias_gemm(const float* __restrict__ X,
                                                 const float* __restrict__ bw,
                                                 float* __restrict__ BS){
  __shared__ float xs[64][129];
  int r0 = blockIdx.x*64;
  for(int idx=threadIdx.x; idx<64*128; idx+=256)
    xs[idx>>7][idx&127] = X[(r0+(idx>>7))*CZ + (idx&127)];
  __syncthreads();
  int h = threadIdx.x>>6, r = threadIdx.x&63;
  float acc=0.f;
  #pragma unroll 4
  for(int k=0;k<CZ;k++) acc += xs[r][k]*bw[k*H_+h];
  BS[h*NN + r0 + r] = acc;
}

// One block per (row i, head h). K/V staged in LDS (stride 33, conflict-free).
__global__ void __launch_bounds__(256) attn_kernel(const float* __restrict__ Q,
                                                   const float* __restrict__ K,
                                                   const float* __restrict__ V,
                                                   const float* __restrict__ BS,
                                                   float* __restrict__ O){
  int i = blockIdx.x, h = blockIdx.y;
  __shared__ float Ks[N_*33];
  __shared__ float Vs[N_*33];
  __shared__ float sp[N_];
  __shared__ float qs[CA];
  __shared__ float red[8][CA];
  __shared__ float wmax[4], wsum[4];
  int tid = threadIdx.x;
  for(int idx=tid; idx<N_*CA; idx+=256){
    int j = idx>>5, cc = idx&31;
    Ks[j*33+cc] = K[(i*N_+j)*CH + h*CA + cc];
    Vs[j*33+cc] = V[(i*N_+j)*CH + h*CA + cc];
  }
  __syncthreads();
  int lane = tid&63, wid = tid>>6;
  int jg = tid>>5, cc = tid&31;
  for(int q=0;q<N_;q++){
    if (tid < CA) qs[tid] = Q[(i*N_+q)*CH + h*CA + tid];
    __syncthreads();
    float s = BS[h*NN + q*N_ + tid];
    #pragma unroll
    for(int c2=0;c2<CA;c2++) s += qs[c2]*Ks[tid*33+c2];
    float m = wave_red_max(s);
    if (lane==0) wmax[wid]=m;
    __syncthreads();
    m = fmaxf(fmaxf(wmax[0],wmax[1]),fmaxf(wmax[2],wmax[3]));
    float p = __expf(s-m);
    float l = wave_red_sum(p);
    if (lane==0) wsum[wid]=l;
    sp[tid]=p;
    __syncthreads();
    l = wsum[0]+wsum[1]+wsum[2]+wsum[3];
    float acc=0.f;
    #pragma unroll
    for(int jj=0;jj<32;jj++) acc += sp[jg*32+jj]*Vs[(jg*32+jj)*33+cc];
    red[jg][cc]=acc;
    __syncthreads();
    if (tid < CA){
      float o=0.f;
      #pragma unroll
      for(int g2=0;g2<8;g2++) o += red[g2][tid];
      O[(i*N_+q)*CH + h*CA + tid] = o / l;
    }
    __syncthreads();
  }
}

// z += ( (o * sigmoid(x@Wg+bg)) @ Wo + bo )   ; TRANS: write to z[(j,i)]
template<bool TRANS>
__global__ void __launch_bounds__(256) attn_out(const float* __restrict__ O,
                                                const float* __restrict__ X,
                                                const float* __restrict__ Wg,
                                                const float* __restrict__ bg,
                                                const float* __restrict__ Wo,
                                                const float* __restrict__ bo,
                                                float* __restrict__ z){
  __shared__ float xs[32][CZ];
  __shared__ float os[32][CH];
  __shared__ float ogs[32][CH];
  int r0 = blockIdx.x * 32;
  for (int idx = threadIdx.x; idx < 32*CZ; idx += 256){
    int r = idx>>7, cc = idx&127;
    xs[r][cc] = X[(r0+r)*CZ + cc];
    os[r][cc] = O[(r0+r)*CH + cc];
  }
  __syncthreads();
  int rr = threadIdx.x >> 7, c = threadIdx.x & 127;
  float ag[16];
  #pragma unroll
  for(int r=0;r<16;r++) ag[r]=0.f;
  #pragma unroll 4
  for(int k=0;k<CZ;k++){
    float wg = Wg[k*CH + c];
    #pragma unroll
    for(int r=0;r<16;r++) ag[r] += xs[rr*16+r][k]*wg;
  }
  float bgc = bg[c];
  #pragma unroll
  for(int r=0;r<16;r++)
    ogs[rr*16+r][c] = os[rr*16+r][c] * sigmoidf_(ag[r]+bgc);
  __syncthreads();
  float a2[16];
  #pragma unroll
  for(int r=0;r<16;r++) a2[r]=0.f;
  #pragma unroll 4
  for(int k=0;k<CH;k++){
    float wo = Wo[k*CZ + c];
    #pragma unroll
    for(int r=0;r<16;r++) a2[r] += ogs[rr*16+r][k]*wo;
  }
  float boc = bo[c];
  #pragma unroll
  for(int r=0;r<16;r++){
    int orow = r0+rr*16+r;
    int zrow = TRANS ? (((orow&255)<<8) | (orow>>8)) : orow;
    z[zrow*CZ + c] += a2[r]+boc;
  }
}

// pair transition: z += relu(x@W1+b1)@W2 + b2
__global__ void __launch_bounds__(256) pt_kernel(const float* __restrict__ X,
                                                 const float* __restrict__ W1,
                                                 const float* __restrict__ b1,
                                                 const float* __restrict__ W2,
                                                 const float* __restrict__ b2,
                                                 float* __restrict__ z){
  __shared__ float xs[32][CZ];
  __shared__ float hs[32][PTH];
  int r0 = blockIdx.x * 32;
  for (int idx = threadIdx.x; idx < 32*CZ; idx += 256)
    xs[idx>>7][idx&127] = X[(r0 + (idx>>7))*CZ + (idx&127)];
  __syncthreads();
  int rr = threadIdx.x >> 7, c = threadIdx.x & 127;
  for(int m=0;m<4;m++){
    float acc[16];
    #pragma unroll
    for(int r=0;r<16;r++) acc[r]=0.f;
    int n = m*128 + c;
    #pragma unroll 4
    for(int k=0;k<CZ;k++){
      float w = W1[k*PTH + n];
      #pragma unroll
      for(int r=0;r<16;r++) acc[r] += xs[rr*16+r][k]*w;
    }
    float bn = b1[n];
    #pragma unroll
    for(int r=0;r<16;r++) hs[rr*16+r][n] = fmaxf(acc[r]+bn, 0.f);
  }
  __syncthreads();
  float a2[16];
  #pragma unroll
  for(int r=0;r<16;r++) a2[r]=0.f;
  #pragma unroll 4
  for(int k=0;k<PTH;k++){
    float w = W2[k*CZ + c];
    #pragma unroll
    for(int r=0;r<16;r++) a2[r] += hs[rr*16+r][k]*w;
  }
  float bc = b2[c];
  #pragma unroll
  for(int r=0;r<16;r++)
    z[(r0+rr*16+r)*CZ + c] += a2[r]+bc;
}

extern "C" void kernel_launch(void* const* d_in, const int* in_sizes, int n_in,
                              void* d_out, int out_size, void* d_ws, size_t ws_size,
                              hipStream_t stream) {
  const float* z_in      = (const float*)d_in[0];
  const float* tm_lnin_w = (const float*)d_in[1];
  const float* tm_lnin_b = (const float*)d_in[2];
  const float* tm_ap_w   = (const float*)d_in[3];
  const float* tm_ap_b   = (const float*)d_in[4];
  const float* tm_ag_w   = (const float*)d_in[5];
  const float* tm_ag_b   = (const float*)d_in[6];
  const float* tm_bp_w   = (const float*)d_in[7];
  const float* tm_bp_b   = (const float*)d_in[8];
  const float* tm_bg_w   = (const float*)d_in[9];
  const float* tm_bg_b   = (const float*)d_in[10];
  const float* tm_g_w    = (const float*)d_in[11];
  const float* tm_g_b    = (const float*)d_in[12];
  const float* tm_zo_w   = (const float*)d_in[13];
  const float* tm_zo_b   = (const float*)d_in[14];
  const float* tm_lno_w  = (const float*)d_in[15];
  const float* tm_lno_b  = (const float*)d_in[16];
  const float* ta_ln_w   = (const float*)d_in[17];
  const float* ta_ln_b   = (const float*)d_in[18];
  const float* ta_q_w    = (const float*)d_in[19];
  const float* ta_k_w    = (const float*)d_in[20];
  const float* ta_v_w    = (const float*)d_in[21];
  const float* ta_b_w    = (const float*)d_in[22];
  const float* ta_g_w    = (const float*)d_in[23];
  const float* ta_g_b    = (const float*)d_in[24];
  const float* ta_o_w    = (const float*)d_in[25];
  const float* ta_o_b    = (const float*)d_in[26];
  const float* pt_ln_w   = (const float*)d_in[27];
  const float* pt_ln_b   = (const float*)d_in[28];
  const float* pt_1_w    = (const float*)d_in[29];
  const float* pt_1_b    = (const float*)d_in[30];
  const float* pt_2_w    = (const float*)d_in[31];
  const float* pt_2_b    = (const float*)d_in[32];

  float* z  = (float*)d_out;
  float* ws = (float*)d_ws;
  const size_t BUF = (size_t)NN*CZ;   // 8388608 floats
  float* X  = ws;
  float* BA = ws + BUF;
  float* BB = ws + 2*BUF;
  float* BT = ws + 3*BUF;
  float* BO = ws + 4*BUF;
  float* BS = ws + 5*BUF;             // NN*H floats

  hipMemcpyAsync(z, z_in, BUF*sizeof(float), hipMemcpyDeviceToDevice, stream);

  // ---- triangle multiplication: outgoing (i=0), incoming (i=1) ----
  for (int i=0;i<2;i++){
    ln_kernel<false><<<NN/4, 256, 0, stream>>>(z, tm_lnin_w+i*CZ, tm_lnin_b+i*CZ, X);
    dual_gate_gemm<<<NN/32, 256, 0, stream>>>(X, tm_ag_w+i*CZ*CH, tm_ag_b+i*CH,
                                              tm_ap_w+i*CZ*CH, tm_ap_b+i*CH, BA);
    dual_gate_gemm<<<NN/32, 256, 0, stream>>>(X, tm_bg_w+i*CZ*CH, tm_bg_b+i*CH,
                                              tm_bp_w+i*CZ*CH, tm_bp_b+i*CH, BB);
    if (i==0) tri_einsum<true ><<<dim3(32,32), 256, 0, stream>>>(BA, BB, BT);
    else      tri_einsum<false><<<dim3(32,32), 256, 0, stream>>>(BA, BB, BT);
    ln_kernel<false><<<NN/4, 256, 0, stream>>>(BT, tm_lno_w+i*CH, tm_lno_b+i*CH, BT); // in-place LN
    tri_finish<<<NN/32, 256, 0, stream>>>(BT, X, tm_zo_w+i*CH*CZ, tm_zo_b+i*CZ,
                                          tm_g_w+i*CZ*CZ, tm_g_b+i*CZ, z);
  }

  // ---- triangle attention: starting (i=0), ending (i=1, transposed coords) ----
  for (int i=0;i<2;i++){
    if (i==0) ln_kernel<false><<<NN/4, 256, 0, stream>>>(z, ta_ln_w, ta_ln_b, X);
    else      ln_kernel<true ><<<NN/4, 256, 0, stream>>>(z, ta_ln_w+CZ, ta_ln_b+CZ, X);
    gemm_scale<<<NN/32, 256, 0, stream>>>(X, ta_q_w+i*CZ*H_*CA, BA, 0.17677669529663687f);
    gemm_scale<<<NN/32, 256, 0, stream>>>(X, ta_k_w+i*CZ*H_*CA, BB, 1.f);
    gemm_scale<<<NN/32, 256, 0, stream>>>(X, ta_v_w+i*CZ*H_*CA, BT, 1.f);
    bias_gemm<<<NN/64, 256, 0, stream>>>(X, ta_b_w+i*CZ*H_, BS);
    attn_kernel<<<dim3(N_,H_), 256, 0, stream>>>(BA, BB, BT, BS, BO);
    if (i==0) attn_out<false><<<NN/32, 256, 0, stream>>>(BO, X, ta_g_w+i*CZ*H_*CA, ta_g_b+i*H_*CA,
                                                         ta_o_w+i*H_*CA*CZ, ta_o_b+i*CZ, z);
    else      attn_out<true ><<<NN/32, 256, 0, stream>>>(BO, X, ta_g_w+i*CZ*H_*CA, ta_g_b+i*H_*CA,
                                                         ta_o_w+i*H_*CA*CZ, ta_o_b+i*CZ, z);
  }

  // ---- pair transition ----
  ln_kernel<false><<<NN/4, 256, 0, stream>>>(z, pt_ln_w, pt_ln_b, X);
  pt_kernel<<<NN/32, 256, 0, stream>>>(X, pt_1_w, pt_1_b, pt_2_w, pt_2_b, z);
}

// Round 2
// 2544.502 us; speedup vs baseline: 1.6406x; 1.6406x over previous
//
#include <hip/hip_runtime.h>
#include <math.h>

#define N_  256
#define NN  65536
#define CZ  128
#define CH  128
#define H_  4
#define CA  32
#define PTH 512

typedef __attribute__((ext_vector_type(8))) short bf16x8;
typedef __attribute__((ext_vector_type(4))) float f32x4;

__device__ __forceinline__ float sigmoidf_(float x){ return 1.f/(1.f+__expf(-x)); }

__device__ __forceinline__ short f2b(float f){
  unsigned u = __float_as_uint(f);
  unsigned r = (u + 0x7fffu + ((u>>16)&1u)) >> 16;
  return (short)r;
}

__device__ __forceinline__ float wave_red_sum(float v){
  #pragma unroll
  for(int o=32;o>0;o>>=1) v += __shfl_xor(v,o,64);
  return v;
}

// LayerNorm over last dim (128). One wave per row; lane handles c and c+64.
// TRANS: output row (i,j) reads input row (j,i)  (for ending-node attention).
template<bool TRANS>
__global__ void __launch_bounds__(256) ln_kernel(const float* __restrict__ in,
                                                 const float* __restrict__ w,
                                                 const float* __restrict__ b,
                                                 float* __restrict__ out){
  int wid  = threadIdx.x >> 6;
  int lane = threadIdx.x & 63;
  int row  = blockIdx.x*4 + wid;
  int irow;
  if (TRANS){ int i = row >> 8, j = row & 255; irow = (j<<8) | i; } else irow = row;
  float v0 = in[irow*CZ + lane];
  float v1 = in[irow*CZ + lane + 64];
  float m  = wave_red_sum(v0+v1) * (1.f/128.f);
  float d0 = v0-m, d1 = v1-m;
  float var = wave_red_sum(d0*d0 + d1*d1) * (1.f/128.f);
  float r = rsqrtf(var + 1e-5f);
  out[row*CZ + lane]      = d0*r*w[lane]    + b[lane];
  out[row*CZ + lane + 64] = d1*r*w[lane+64] + b[lane+64];
}

// out[r,c] = sigmoid(x@Wg + bg) * (x@Wp + bp)   -- [NN,128]x[128,128] dual GEMM
__global__ void __launch_bounds__(256) dual_gate_gemm(const float* __restrict__ X,
                                                      const float* __restrict__ Wg,
                                                      const float* __restrict__ bg,
                                                      const float* __restrict__ Wp,
                                                      const float* __restrict__ bp,
                                                      float* __restrict__ out){
  __shared__ float xs[32][CZ];
  int r0 = blockIdx.x * 32;
  for (int idx = threadIdx.x; idx < 32*CZ; idx += 256)
    xs[idx>>7][idx&127] = X[(r0 + (idx>>7))*CZ + (idx&127)];
  __syncthreads();
  int rr = threadIdx.x >> 7, c = threadIdx.x & 127;
  float ag[16], ap[16];
  #pragma unroll
  for(int r=0;r<16;r++){ ag[r]=0.f; ap[r]=0.f; }
  #pragma unroll 4
  for(int k=0;k<CZ;k++){
    float wg = Wg[k*CH + c];
    float wp = Wp[k*CH + c];
    #pragma unroll
    for(int r=0;r<16;r++){
      float xv = xs[rr*16+r][k];
      ag[r] += xv*wg; ap[r] += xv*wp;
    }
  }
  float bgc = bg[c], bpc = bp[c];
  #pragma unroll
  for(int r=0;r<16;r++)
    out[(r0+rr*16+r)*CH + c] = (ap[r]+bpc) * sigmoidf_(ag[r]+bgc);
}

// out[r,c] = (x@W)[r,c] * scale     (no bias; used for q/k/v)
__global__ void __launch_bounds__(256) gemm_scale(const float* __restrict__ X,
                                                  const float* __restrict__ W,
                                                  float* __restrict__ out, float scale){
  __shared__ float xs[32][CZ];
  int r0 = blockIdx.x * 32;
  for (int idx = threadIdx.x; idx < 32*CZ; idx += 256)
    xs[idx>>7][idx&127] = X[(r0 + (idx>>7))*CZ + (idx&127)];
  __syncthreads();
  int rr = threadIdx.x >> 7, c = threadIdx.x & 127;
  float acc[16];
  #pragma unroll
  for(int r=0;r<16;r++) acc[r]=0.f;
  #pragma unroll 4
  for(int k=0;k<CZ;k++){
    float w = W[k*CH + c];
    #pragma unroll
    for(int r=0;r<16;r++) acc[r] += xs[rr*16+r][k]*w;
  }
  #pragma unroll
  for(int r=0;r<16;r++)
    out[(r0+rr*16+r)*CH + c] = acc[r]*scale;
}

// Triangle einsum. OUTGOING: t[i,j,c] = sum_k a[i,k,c]*b[j,k,c]
//                  else:      t[i,j,c] = sum_k a[k,i,c]*b[k,j,c]
template<bool OUTGOING>
__global__ void __launch_bounds__(256) tri_einsum(const float* __restrict__ A,
                                                  const float* __restrict__ B,
                                                  float* __restrict__ T){
  __shared__ float as_[8][8][CH];   // [kk][ii][c]
  __shared__ float bs_[8][8][CH];   // [kk][jj][c]
  int i0 = blockIdx.x*8, j0 = blockIdx.y*8;
  int p = threadIdx.x >> 7, c = threadIdx.x & 127;
  float acc[8][4];
  #pragma unroll
  for(int a2=0;a2<8;a2++)
    #pragma unroll
    for(int b2=0;b2<4;b2++) acc[a2][b2]=0.f;
  for(int k0=0;k0<N_;k0+=8){
    __syncthreads();
    for(int idx=threadIdx.x; idx<8*8*CH; idx+=256){
      int cc = idx & 127, ii = (idx>>7)&7, kk = idx>>10;
      int arow = OUTGOING ? ((i0+ii)*N_ + k0+kk) : ((k0+kk)*N_ + i0+ii);
      int brow = OUTGOING ? ((j0+ii)*N_ + k0+kk) : ((k0+kk)*N_ + j0+ii);
      as_[kk][ii][cc] = A[arow*CH + cc];
      bs_[kk][ii][cc] = B[brow*CH + cc];
    }
    __syncthreads();
    #pragma unroll
    for(int kk=0;kk<8;kk++){
      float bv[4];
      #pragma unroll
      for(int jj=0;jj<4;jj++) bv[jj] = bs_[kk][p*4+jj][c];
      #pragma unroll
      for(int ii=0;ii<8;ii++){
        float av = as_[kk][ii][c];
        #pragma unroll
        for(int jj=0;jj<4;jj++) acc[ii][jj] += av*bv[jj];
      }
    }
  }
  #pragma unroll
  for(int ii=0;ii<8;ii++)
    #pragma unroll
    for(int jj=0;jj<4;jj++)
      T[((i0+ii)*N_ + j0 + p*4 + jj)*CH + c] = acc[ii][jj];
}

// z[r,c] += (t2@Wz + bz) * sigmoid(x@Wg + bg)
__global__ void __launch_bounds__(256) tri_finish(const float* __restrict__ T2,
                                                  const float* __restrict__ X,
                                                  const float* __restrict__ Wz,
                                                  const float* __restrict__ bz,
                                                  const float* __restrict__ Wg,
                                                  const float* __restrict__ bg,
                                                  float* __restrict__ z){
  __shared__ float ts[32][CH];
  __shared__ float xs[32][CZ];
  int r0 = blockIdx.x * 32;
  for (int idx = threadIdx.x; idx < 32*CZ; idx += 256){
    int r = idx>>7, cc = idx&127;
    ts[r][cc] = T2[(r0+r)*CH + cc];
    xs[r][cc] = X[(r0+r)*CZ + cc];
  }
  __syncthreads();
  int rr = threadIdx.x >> 7, c = threadIdx.x & 127;
  float az[16], ag[16];
  #pragma unroll
  for(int r=0;r<16;r++){ az[r]=0.f; ag[r]=0.f; }
  #pragma unroll 4
  for(int k=0;k<CZ;k++){
    float wz = Wz[k*CZ + c];
    float wg = Wg[k*CZ + c];
    #pragma unroll
    for(int r=0;r<16;r++){
      az[r] += ts[rr*16+r][k]*wz;
      ag[r] += xs[rr*16+r][k]*wg;
    }
  }
  float bzc = bz[c], bgc = bg[c];
  #pragma unroll
  for(int r=0;r<16;r++)
    z[(r0+rr*16+r)*CZ + c] += (az[r]+bzc) * sigmoidf_(ag[r]+bgc);
}

// bias[h,q,j] = x[q*256+j,:] @ bw[:,h], written in MFMA C-fragment order:
// BSF[((h*16+qs)*16 + jt)*256 + lane*4 + r], lane = (q&15) + 16*((j>>2)&3), r = j&3
__global__ void __launch_bounds__(256) bias_gemm(const float* __restrict__ X,
                                                 const float* __restrict__ bw,
                                                 float* __restrict__ BSF){
  __shared__ float xs[64][129];
  int r0 = blockIdx.x*64;
  for(int idx=threadIdx.x; idx<64*128; idx+=256)
    xs[idx>>7][idx&127] = X[(r0+(idx>>7))*CZ + (idx&127)];
  __syncthreads();
  int h = threadIdx.x>>6, r = threadIdx.x&63;
  float acc=0.f;
  #pragma unroll 4
  for(int k=0;k<CZ;k++) acc += xs[r][k]*bw[k*H_+h];
  int rr2 = r0 + r;
  int q = rr2 >> 8, j = rr2 & 255;
  int idx = (((h*16 + (q>>4))*16 + (j>>4)) << 8) + ((((j>>2)&3)*16 + (q&15)) << 2) + (j&3);
  BSF[idx] = acc;
}

// bf16 MFMA flash attention. One block per (i,h); 4 waves, each owns 64 q rows.
// S^T = K·Q^T via mfma(Kfrag, Qfrag, biasfrag); per-lane softmax (lane owns one q);
// O^T = V^T·P^T via mfma(Vfrag, Pfrag). No barriers after staging.
__global__ void __launch_bounds__(256) attn_mfma(const float* __restrict__ Qg,
                                                 const float* __restrict__ Kg,
                                                 const float* __restrict__ Vg,
                                                 const float* __restrict__ BSF,
                                                 float* __restrict__ O){
  __shared__ short Qf[8192];       // 16 q-subtiles x 64 lanes x 8 (B-frag)
  __shared__ short Kf[8192];       // 16 j-tiles   x 64 lanes x 8 (A-frag)
  __shared__ short Vf[8192];       // 2 ct x 8 jt  x 64 lanes x 8 (A-frag of V^T)
  __shared__ short Pf[4][4096];    // per-wave P^T B-frags: 8 jt x 64 lanes x 8
  int i = blockIdx.x, h = blockIdx.y;
  int tid = threadIdx.x;

  // ---- stage Q,K (same packing), V (transposed packing), all bf16 ----
  #pragma unroll
  for (int m=0; m<8; ++m){
    int qd = m*256 + tid;          // 0..2047 quads
    int r = qd >> 3, c0 = (qd & 7)*4;
    const float4 qv = *(const float4*)&Qg[(size_t)(i*N_ + r)*CZ + h*CA + c0];
    const float4 kv = *(const float4*)&Kg[(size_t)(i*N_ + r)*CZ + h*CA + c0];
    const float4 vv = *(const float4*)&Vg[(size_t)(i*N_ + r)*CZ + h*CA + c0];
    short4 qs4 = { f2b(qv.x), f2b(qv.y), f2b(qv.z), f2b(qv.w) };
    short4 ks4 = { f2b(kv.x), f2b(kv.y), f2b(kv.z), f2b(kv.w) };
    int lane = ((c0>>3)<<4) + (r&15);
    int base = (r>>4)*512 + lane*8 + (c0&7);
    *(short4*)&Qf[base] = qs4;
    *(short4*)&Kf[base] = ks4;
    // V: element (j=r, c) -> Vf[((ct*8 + j/32)*64 + ((j&31)>>3)*16 + (c&15))*8 + (j&7)]
    int jt2 = r>>5, lsub = ((r&31)>>3)<<4, e = r&7;
    short vs4[4] = { f2b(vv.x), f2b(vv.y), f2b(vv.z), f2b(vv.w) };
    #pragma unroll
    for (int cc=0; cc<4; ++cc){
      int c = c0+cc;
      Vf[(((c>>4)*8 + jt2)*64 + lsub + (c&15))*8 + e] = vs4[cc];
    }
  }
  __syncthreads();

  int wid = tid >> 6, l = tid & 63;
  int lg = l >> 4, ln = l & 15;
  short* pw = &Pf[wid][0];

  for (int ss=0; ss<4; ++ss){
    int sub = wid*4 + ss;          // q-subtile (16 q rows), q0 = sub*16
    bf16x8 qfrag = *(const bf16x8*)&Qf[sub*512 + l*8];
    const float* bbase = &BSF[(((h*16 + sub)*16) << 8) + (l<<2)];
    f32x4 acc[16];
    #pragma unroll
    for (int t=0;t<16;t++) acc[t] = *(const f32x4*)&bbase[t<<8];
    #pragma unroll
    for (int t=0;t<16;t++){
      bf16x8 kf = *(const bf16x8*)&Kf[t*512 + l*8];
      acc[t] = __builtin_amdgcn_mfma_f32_16x16x32_bf16(kf, qfrag, acc[t], 0,0,0);
    }
    // softmax: lane owns q = sub*16+ln; its 64 S values span j = t*16 + lg*4 + r
    float mx = -1e30f;
    #pragma unroll
    for (int t=0;t<16;t++){
      mx = fmaxf(mx, fmaxf(fmaxf(acc[t][0],acc[t][1]), fmaxf(acc[t][2],acc[t][3])));
    }
    mx = fmaxf(mx, __shfl_xor(mx,16,64));
    mx = fmaxf(mx, __shfl_xor(mx,32,64));
    float sum = 0.f;
    #pragma unroll
    for (int t=0;t<16;t++){
      #pragma unroll
      for (int r=0;r<4;r++){ float p = __expf(acc[t][r]-mx); acc[t][r]=p; sum += p; }
    }
    sum += __shfl_xor(sum,16,64);
    sum += __shfl_xor(sum,32,64);
    float inv = 1.0f / sum;
    // write P^T B-frags (8B contiguous per tile)
    #pragma unroll
    for (int t=0;t<16;t++){
      int j0 = t*16 + lg*4;
      short4 s4 = { f2b(acc[t][0]), f2b(acc[t][1]), f2b(acc[t][2]), f2b(acc[t][3]) };
      *(short4*)&pw[(j0>>5)*512 + ((((j0>>3)&3)<<4) + ln)*8 + (j0&7)] = s4;
    }
    // PV: O^T = V^T . P^T
    #pragma unroll
    for (int ct=0; ct<2; ++ct){
      f32x4 o = {0.f,0.f,0.f,0.f};
      #pragma unroll
      for (int jt=0;jt<8;jt++){
        bf16x8 vf = *(const bf16x8*)&Vf[((ct*8 + jt)*64 + l)*8];
        bf16x8 pf = *(const bf16x8*)&pw[jt*512 + l*8];
        o = __builtin_amdgcn_mfma_f32_16x16x32_bf16(vf, pf, o, 0,0,0);
      }
      int q = sub*16 + ln;
      int c = ct*16 + lg*4;
      float4 ov; ov.x=o[0]*inv; ov.y=o[1]*inv; ov.z=o[2]*inv; ov.w=o[3]*inv;
      *(float4*)&O[(size_t)(i*N_ + q)*CH + h*CA + c] = ov;
    }
  }
}

// z += ( (o * sigmoid(x@Wg+bg)) @ Wo + bo )   ; TRANS: write to z[(j,i)]
template<bool TRANS>
__global__ void __launch_bounds__(256) attn_out(const float* __restrict__ O,
                                                const float* __restrict__ X,
                                                const float* __restrict__ Wg,
                                                const float* __restrict__ bg,
                                                const float* __restrict__ Wo,
                                                const float* __restrict__ bo,
                                                float* __restrict__ z){
  __shared__ float xs[32][CZ];
  __shared__ float os[32][CH];
  __shared__ float ogs[32][CH];
  int r0 = blockIdx.x * 32;
  for (int idx = threadIdx.x; idx < 32*CZ; idx += 256){
    int r = idx>>7, cc = idx&127;
    xs[r][cc] = X[(r0+r)*CZ + cc];
    os[r][cc] = O[(r0+r)*CH + cc];
  }
  __syncthreads();
  int rr = threadIdx.x >> 7, c = threadIdx.x & 127;
  float ag[16];
  #pragma unroll
  for(int r=0;r<16;r++) ag[r]=0.f;
  #pragma unroll 4
  for(int k=0;k<CZ;k++){
    float wg = Wg[k*CH + c];
    #pragma unroll
    for(int r=0;r<16;r++) ag[r] += xs[rr*16+r][k]*wg;
  }
  float bgc = bg[c];
  #pragma unroll
  for(int r=0;r<16;r++)
    ogs[rr*16+r][c] = os[rr*16+r][c] * sigmoidf_(ag[r]+bgc);
  __syncthreads();
  float a2[16];
  #pragma unroll
  for(int r=0;r<16;r++) a2[r]=0.f;
  #pragma unroll 4
  for(int k=0;k<CH;k++){
    float wo = Wo[k*CZ + c];
    #pragma unroll
    for(int r=0;r<16;r++) a2[r] += ogs[rr*16+r][k]*wo;
  }
  float boc = bo[c];
  #pragma unroll
  for(int r=0;r<16;r++){
    int orow = r0+rr*16+r;
    int zrow = TRANS ? (((orow&255)<<8) | (orow>>8)) : orow;
    z[zrow*CZ + c] += a2[r]+boc;
  }
}

// pair transition: z += relu(x@W1+b1)@W2 + b2
__global__ void __launch_bounds__(256) pt_kernel(const float* __restrict__ X,
                                                 const float* __restrict__ W1,
                                                 const float* __restrict__ b1,
                                                 const float* __restrict__ W2,
                                                 const float* __restrict__ b2,
                                                 float* __restrict__ z){
  __shared__ float xs[32][CZ];
  __shared__ float hs[32][PTH];
  int r0 = blockIdx.x * 32;
  for (int idx = threadIdx.x; idx < 32*CZ; idx += 256)
    xs[idx>>7][idx&127] = X[(r0 + (idx>>7))*CZ + (idx&127)];
  __syncthreads();
  int rr = threadIdx.x >> 7, c = threadIdx.x & 127;
  for(int m=0;m<4;m++){
    float acc[16];
    #pragma unroll
    for(int r=0;r<16;r++) acc[r]=0.f;
    int n = m*128 + c;
    #pragma unroll 4
    for(int k=0;k<CZ;k++){
      float w = W1[k*PTH + n];
      #pragma unroll
      for(int r=0;r<16;r++) acc[r] += xs[rr*16+r][k]*w;
    }
    float bn = b1[n];
    #pragma unroll
    for(int r=0;r<16;r++) hs[rr*16+r][n] = fmaxf(acc[r]+bn, 0.f);
  }
  __syncthreads();
  float a2[16];
  #pragma unroll
  for(int r=0;r<16;r++) a2[r]=0.f;
  #pragma unroll 4
  for(int k=0;k<PTH;k++){
    float w = W2[k*CZ + c];
    #pragma unroll
    for(int r=0;r<16;r++) a2[r] += hs[rr*16+r][k]*w;
  }
  float bc = b2[c];
  #pragma unroll
  for(int r=0;r<16;r++)
    z[(r0+rr*16+r)*CZ + c] += a2[r]+bc;
}

extern "C" void kernel_launch(void* const* d_in, const int* in_sizes, int n_in,
                              void* d_out, int out_size, void* d_ws, size_t ws_size,
                              hipStream_t stream) {
  const float* z_in      = (const float*)d_in[0];
  const float* tm_lnin_w = (const float*)d_in[1];
  const float* tm_lnin_b = (const float*)d_in[2];
  const float* tm_ap_w   = (const float*)d_in[3];
  const float* tm_ap_b   = (const float*)d_in[4];
  const float* tm_ag_w   = (const float*)d_in[5];
  const float* tm_ag_b   = (const float*)d_in[6];
  const float* tm_bp_w   = (const float*)d_in[7];
  const float* tm_bp_b   = (const float*)d_in[8];
  const float* tm_bg_w   = (const float*)d_in[9];
  const float* tm_bg_b   = (const float*)d_in[10];
  const float* tm_g_w    = (const float*)d_in[11];
  const float* tm_g_b    = (const float*)d_in[12];
  const float* tm_zo_w   = (const float*)d_in[13];
  const float* tm_zo_b   = (const float*)d_in[14];
  const float* tm_lno_w  = (const float*)d_in[15];
  const float* tm_lno_b  = (const float*)d_in[16];
  const float* ta_ln_w   = (const float*)d_in[17];
  const float* ta_ln_b   = (const float*)d_in[18];
  const float* ta_q_w    = (const float*)d_in[19];
  const float* ta_k_w    = (const float*)d_in[20];
  const float* ta_v_w    = (const float*)d_in[21];
  const float* ta_b_w    = (const float*)d_in[22];
  const float* ta_g_w    = (const float*)d_in[23];
  const float* ta_g_b    = (const float*)d_in[24];
  const float* ta_o_w    = (const float*)d_in[25];
  const float* ta_o_b    = (const float*)d_in[26];
  const float* pt_ln_w   = (const float*)d_in[27];
  const float* pt_ln_b   = (const float*)d_in[28];
  const float* pt_1_w    = (const float*)d_in[29];
  const float* pt_1_b    = (const float*)d_in[30];
  const float* pt_2_w    = (const float*)d_in[31];
  const float* pt_2_b    = (const float*)d_in[32];

  float* z  = (float*)d_out;
  float* ws = (float*)d_ws;
  const size_t BUF = (size_t)NN*CZ;   // 8388608 floats
  float* X  = ws;
  float* BA = ws + BUF;
  float* BB = ws + 2*BUF;
  float* BT = ws + 3*BUF;
  float* BO = ws + 4*BUF;
  float* BS = ws + 5*BUF;             // NN*H floats (frag-layout bias)

  hipMemcpyAsync(z, z_in, BUF*sizeof(float), hipMemcpyDeviceToDevice, stream);

  // ---- triangle multiplication: outgoing (i=0), incoming (i=1) ----
  for (int i=0;i<2;i++){
    ln_kernel<false><<<NN/4, 256, 0, stream>>>(z, tm_lnin_w+i*CZ, tm_lnin_b+i*CZ, X);
    dual_gate_gemm<<<NN/32, 256, 0, stream>>>(X, tm_ag_w+i*CZ*CH, tm_ag_b+i*CH,
                                              tm_ap_w+i*CZ*CH, tm_ap_b+i*CH, BA);
    dual_gate_gemm<<<NN/32, 256, 0, stream>>>(X, tm_bg_w+i*CZ*CH, tm_bg_b+i*CH,
                                              tm_bp_w+i*CZ*CH, tm_bp_b+i*CH, BB);
    if (i==0) tri_einsum<true ><<<dim3(32,32), 256, 0, stream>>>(BA, BB, BT);
    else      tri_einsum<false><<<dim3(32,32), 256, 0, stream>>>(BA, BB, BT);
    ln_kernel<false><<<NN/4, 256, 0, stream>>>(BT, tm_lno_w+i*CH, tm_lno_b+i*CH, BT);
    tri_finish<<<NN/32, 256, 0, stream>>>(BT, X, tm_zo_w+i*CH*CZ, tm_zo_b+i*CZ,
                                          tm_g_w+i*CZ*CZ, tm_g_b+i*CZ, z);
  }

  // ---- triangle attention: starting (i=0), ending (i=1, transposed coords) ----
  for (int i=0;i<2;i++){
    if (i==0) ln_kernel<false><<<NN/4, 256, 0, stream>>>(z, ta_ln_w, ta_ln_b, X);
    else      ln_kernel<true ><<<NN/4, 256, 0, stream>>>(z, ta_ln_w+CZ, ta_ln_b+CZ, X);
    gemm_scale<<<NN/32, 256, 0, stream>>>(X, ta_q_w+i*CZ*H_*CA, BA, 0.17677669529663687f);
    gemm_scale<<<NN/32, 256, 0, stream>>>(X, ta_k_w+i*CZ*H_*CA, BB, 1.f);
    gemm_scale<<<NN/32, 256, 0, stream>>>(X, ta_v_w+i*CZ*H_*CA, BT, 1.f);
    bias_gemm<<<NN/64, 256, 0, stream>>>(X, ta_b_w+i*CZ*H_, BS);
    attn_mfma<<<dim3(N_,H_), 256, 0, stream>>>(BA, BB, BT, BS, BO);
    if (i==0) attn_out<false><<<NN/32, 256, 0, stream>>>(BO, X, ta_g_w+i*CZ*H_*CA, ta_g_b+i*H_*CA,
                                                         ta_o_w+i*H_*CA*CZ, ta_o_b+i*CZ, z);
    else      attn_out<true ><<<NN/32, 256, 0, stream>>>(BO, X, ta_g_w+i*CZ*H_*CA, ta_g_b+i*H_*CA,
                                                         ta_o_w+i*H_*CA*CZ, ta_o_b+i*CZ, z);
  }

  // ---- pair transition ----
  ln_kernel<false><<<NN/4, 256, 0, stream>>>(z, pt_ln_w, pt_ln_b, X);
  pt_kernel<<<NN/32, 256, 0, stream>>>(X, pt_1_w, pt_1_b, pt_2_w, pt_2_b, z);
}

// Round 3
// 673.000 us; speedup vs baseline: 6.2030x; 3.7808x over previous
//
#include <hip/hip_runtime.h>
#include <math.h>

#define N_  256
#define NN  65536
#define CZ  128
#define CH  128
#define H_  4
#define CA  32

typedef __attribute__((ext_vector_type(8))) short bf16x8;
typedef __attribute__((ext_vector_type(4))) float f32x4;

__device__ __forceinline__ float sigmoidf_(float x){ return 1.f/(1.f+__expf(-x)); }

__device__ __forceinline__ short f2b(float f){
  unsigned u = __float_as_uint(f);
  unsigned r = (u + 0x7fffu + ((u>>16)&1u)) >> 16;
  return (short)r;
}
__device__ __forceinline__ float b2f(short s){
  unsigned u = ((unsigned)(unsigned short)s) << 16;
  return __uint_as_float(u);
}

__device__ __forceinline__ float wave_red_sum(float v){
  #pragma unroll
  for(int o=32;o>0;o>>=1) v += __shfl_xor(v,o,64);
  return v;
}

// ---------- weight prep: fp32 [K][N] slices -> bf16 B-fragment-packed blobs ----------
// slice s blob: Wf[s*16384 + ((nt*4+ks)*64 + l)*8 + e] = bf16(W[k][n]),
//   n = nt*16 + (l&15), k = ks*32 + (l>>4)*8 + e
__global__ void __launch_bounds__(256) prep_weights(
    const float* tm_ag, const float* tm_ap, const float* tm_bg, const float* tm_bp,
    const float* tm_g, const float* tm_zo,
    const float* ta_q, const float* ta_k, const float* ta_v, const float* ta_g, const float* ta_o,
    const float* pt1, const float* pt2, short* Wf){
  int tid = threadIdx.x;
  int g = blockIdx.x*4 + (tid>>6);
  int l = tid & 63;
  int s = blockIdx.y;
  const float* src; int ldn = 128, koff = 0, noff = 0;
  if (s < 12){
    int i = s/6, w = s - i*6;
    switch(w){ case 0: src=tm_ag; break; case 1: src=tm_ap; break; case 2: src=tm_bg; break;
               case 3: src=tm_bp; break; case 4: src=tm_g;  break; default: src=tm_zo; }
    src += i*16384;
  } else if (s < 22){
    int t2 = s-12; int i = t2/5, w = t2 - i*5;
    switch(w){ case 0: src=ta_q; break; case 1: src=ta_k; break; case 2: src=ta_v; break;
               case 3: src=ta_g; break; default: src=ta_o; }
    src += i*16384;
  } else if (s < 26){
    src = pt1; ldn = 512; noff = (s-22)*128;
  } else {
    src = pt2; koff = (s-26)*128;
  }
  int nt = g>>2, ks = g&3;
  int n = noff + nt*16 + (l&15);
  int kb = koff + ks*32 + (l>>4)*8;
  short tmp[8];
  #pragma unroll
  for (int e=0;e<8;e++) tmp[e] = f2b(src[(size_t)(kb+e)*ldn + n]);
  short* dst = Wf + s*16384 + ((nt*4+ks)*64 + l)*8;
  *(short4*)dst     = *(short4*)&tmp[0];
  *(short4*)(dst+4) = *(short4*)&tmp[4];
}

// ---------- LayerNorm: fp32 in -> bf16 out; TRANS reads transposed grid ----------
template<bool TRANS>
__global__ void __launch_bounds__(256) ln_x(const float* __restrict__ in,
                                            const float* __restrict__ w,
                                            const float* __restrict__ b,
                                            short* __restrict__ out){
  int wid  = threadIdx.x >> 6;
  int lane = threadIdx.x & 63;
  int row  = blockIdx.x*4 + wid;
  int irow;
  if (TRANS){ int i = row >> 8, j = row & 255; irow = (j<<8) | i; } else irow = row;
  float v0 = in[(size_t)irow*CZ + lane];
  float v1 = in[(size_t)irow*CZ + lane + 64];
  float m  = wave_red_sum(v0+v1) * (1.f/128.f);
  float d0 = v0-m, d1 = v1-m;
  float var = wave_red_sum(d0*d0 + d1*d1) * (1.f/128.f);
  float r = rsqrtf(var + 1e-5f);
  out[(size_t)row*CZ + lane]      = f2b(d0*r*w[lane]    + b[lane]);
  out[(size_t)row*CZ + lane + 64] = f2b(d1*r*w[lane+64] + b[lane+64]);
}

// ---------- shared GEMM helpers ----------
// stage 128x128 bf16 tile, chunk-XOR swizzle (16 chunks of 8 bf16)
__device__ __forceinline__ void stage128(const short* __restrict__ g, short* xs, int r0, int tid){
  #pragma unroll
  for (int m=0;m<8;++m){
    int idx = m*256 + tid;
    int row = idx>>4, ch = idx&15;
    *(int4*)&xs[row*128 + ((ch ^ (row&15))<<3)] =
        *(const int4*)&g[(size_t)(r0+row)*128 + ch*8];
  }
}

__device__ __forceinline__ bf16x8 ldsA(const short* xs, int row, int ch){
  return *(const bf16x8*)&xs[row*128 + ((ch ^ (row&15))<<3)];
}

// core: 128 rows (LDS xs) x 128 cols (Wf frag blob), K=128
__device__ __forceinline__ void gemm_core(const short* xs, const short* __restrict__ wf,
                                          int wm, int wn, int l, f32x4 (&acc)[4][4]){
  #pragma unroll
  for (int ks=0; ks<4; ++ks){
    bf16x8 a[4], b[4];
    #pragma unroll
    for (int mt=0; mt<4; ++mt)
      a[mt] = ldsA(xs, wm*64 + mt*16 + (l&15), ks*4 + (l>>4));
    #pragma unroll
    for (int nt=0; nt<4; ++nt)
      b[nt] = *(const bf16x8*)&wf[(((wn*4+nt)*4 + ks)*64 + l)*8];
    #pragma unroll
    for (int mt=0; mt<4; ++mt)
      #pragma unroll
      for (int nt=0; nt<4; ++nt)
        acc[mt][nt] = __builtin_amdgcn_mfma_f32_16x16x32_bf16(a[mt], b[nt], acc[mt][nt], 0,0,0);
  }
}

// dual-W core sharing A-frags
__device__ __forceinline__ void gemm_core2(const short* xs, const short* __restrict__ wf1,
                                           const short* __restrict__ wf2,
                                           int wm, int wn, int l,
                                           f32x4 (&acc1)[4][4], f32x4 (&acc2)[4][4]){
  #pragma unroll
  for (int ks=0; ks<4; ++ks){
    bf16x8 a[4], b1[4], b2[4];
    #pragma unroll
    for (int mt=0; mt<4; ++mt)
      a[mt] = ldsA(xs, wm*64 + mt*16 + (l&15), ks*4 + (l>>4));
    #pragma unroll
    for (int nt=0; nt<4; ++nt){
      b1[nt] = *(const bf16x8*)&wf1[(((wn*4+nt)*4 + ks)*64 + l)*8];
      b2[nt] = *(const bf16x8*)&wf2[(((wn*4+nt)*4 + ks)*64 + l)*8];
    }
    #pragma unroll
    for (int mt=0; mt<4; ++mt)
      #pragma unroll
      for (int nt=0; nt<4; ++nt){
        acc1[mt][nt] = __builtin_amdgcn_mfma_f32_16x16x32_bf16(a[mt], b1[nt], acc1[mt][nt], 0,0,0);
        acc2[mt][nt] = __builtin_amdgcn_mfma_f32_16x16x32_bf16(a[mt], b2[nt], acc2[mt][nt], 0,0,0);
      }
  }
}

#define GEMM_PROLOG \
  int tid = threadIdx.x; int r0 = blockIdx.x*128; \
  int wid = tid>>6, l = tid&63; int wm = wid>>1, wn = wid&1;

#define EPI_COORDS \
  int row = wm*64 + mt*16 + ((l>>4)<<2) + reg; \
  int col = wn*64 + nt*16 + (l&15);

// ---------- out = sigmoid(X@Wg+bg) * (X@Wp+bp), bf16 out ----------
__global__ void __launch_bounds__(256) k_dual_gate(const short* __restrict__ X,
                                                   const short* __restrict__ Wgf, const float* __restrict__ bg,
                                                   const short* __restrict__ Wpf, const float* __restrict__ bp,
                                                   short* __restrict__ out){
  __shared__ short xs[128*128];
  GEMM_PROLOG
  stage128(X, xs, r0, tid);
  __syncthreads();
  f32x4 ag[4][4], ap[4][4];
  #pragma unroll
  for(int a=0;a<4;a++) for(int b=0;b<4;b++){ ag[a][b]=(f32x4){0,0,0,0}; ap[a][b]=(f32x4){0,0,0,0}; }
  gemm_core2(xs, Wgf, Wpf, wm, wn, l, ag, ap);
  #pragma unroll
  for (int mt=0; mt<4; ++mt)
    #pragma unroll
    for (int nt=0; nt<4; ++nt)
      #pragma unroll
      for (int reg=0; reg<4; ++reg){
        EPI_COORDS
        float v = (ap[mt][nt][reg] + bp[col]) * sigmoidf_(ag[mt][nt][reg] + bg[col]);
        out[(size_t)(r0+row)*128 + col] = f2b(v);
      }
}

// ---------- out = (X@W)*scale, bf16 out ----------
__global__ void __launch_bounds__(256) k_gemm(const short* __restrict__ X,
                                              const short* __restrict__ Wf,
                                              float scale, short* __restrict__ out){
  __shared__ short xs[128*128];
  GEMM_PROLOG
  stage128(X, xs, r0, tid);
  __syncthreads();
  f32x4 acc[4][4];
  #pragma unroll
  for(int a=0;a<4;a++) for(int b=0;b<4;b++) acc[a][b]=(f32x4){0,0,0,0};
  gemm_core(xs, Wf, wm, wn, l, acc);
  #pragma unroll
  for (int mt=0; mt<4; ++mt)
    #pragma unroll
    for (int nt=0; nt<4; ++nt)
      #pragma unroll
      for (int reg=0; reg<4; ++reg){
        EPI_COORDS
        out[(size_t)(r0+row)*128 + col] = f2b(acc[mt][nt][reg]*scale);
      }
}

// ---------- zout = zin + (T2@Wz+bz)*sigmoid(X@Wg+bg) ----------
__global__ void __launch_bounds__(256) k_tri_finish(const short* __restrict__ T2,
                                                    const short* __restrict__ X,
                                                    const short* __restrict__ Wzf, const float* __restrict__ bz,
                                                    const short* __restrict__ Wgf, const float* __restrict__ bg,
                                                    const float* __restrict__ zin, float* __restrict__ zout){
  __shared__ short ts[128*128];
  __shared__ short xs[128*128];
  GEMM_PROLOG
  stage128(T2, ts, r0, tid);
  stage128(X,  xs, r0, tid);
  __syncthreads();
  f32x4 az[4][4], ag[4][4];
  #pragma unroll
  for(int a=0;a<4;a++) for(int b=0;b<4;b++){ az[a][b]=(f32x4){0,0,0,0}; ag[a][b]=(f32x4){0,0,0,0}; }
  gemm_core(ts, Wzf, wm, wn, l, az);
  gemm_core(xs, Wgf, wm, wn, l, ag);
  #pragma unroll
  for (int mt=0; mt<4; ++mt)
    #pragma unroll
    for (int nt=0; nt<4; ++nt)
      #pragma unroll
      for (int reg=0; reg<4; ++reg){
        EPI_COORDS
        size_t idx = (size_t)(r0+row)*128 + col;
        float v = (az[mt][nt][reg] + bz[col]) * sigmoidf_(ag[mt][nt][reg] + bg[col]);
        zout[idx] = zin[idx] + v;
      }
}

// ---------- z(±T) += ((O*sigmoid(X@Wg+bg)) @ Wo + bo) ----------
template<bool TRANS>
__global__ void __launch_bounds__(256) k_attn_out(const short* __restrict__ O,
                                                  const short* __restrict__ X,
                                                  const short* __restrict__ Wgf, const float* __restrict__ bg,
                                                  const short* __restrict__ Wof, const float* __restrict__ bo,
                                                  float* __restrict__ z){
  __shared__ short xs[128*128];   // X, later og
  __shared__ short os[128*128];   // O, plain layout
  GEMM_PROLOG
  stage128(X, xs, r0, tid);
  #pragma unroll
  for (int m=0;m<8;++m){
    int idx = m*256 + tid;
    int row = idx>>4, ch = idx&15;
    *(int4*)&os[row*128 + ch*8] = *(const int4*)&O[(size_t)(r0+row)*128 + ch*8];
  }
  __syncthreads();
  f32x4 ag[4][4];
  #pragma unroll
  for(int a=0;a<4;a++) for(int b=0;b<4;b++) ag[a][b]=(f32x4){0,0,0,0};
  gemm_core(xs, Wgf, wm, wn, l, ag);
  __syncthreads();   // all waves done reading xs
  // og = O * sigmoid(gate), written into xs (swizzled)
  #pragma unroll
  for (int mt=0; mt<4; ++mt)
    #pragma unroll
    for (int nt=0; nt<4; ++nt)
      #pragma unroll
      for (int reg=0; reg<4; ++reg){
        EPI_COORDS
        float ov = b2f(os[row*128 + col]);
        float v = ov * sigmoidf_(ag[mt][nt][reg] + bg[col]);
        xs[row*128 + (((col>>3) ^ (row&15))<<3) + (col&7)] = f2b(v);
      }
  __syncthreads();
  f32x4 a2[4][4];
  #pragma unroll
  for(int a=0;a<4;a++) for(int b=0;b<4;b++) a2[a][b]=(f32x4){0,0,0,0};
  gemm_core(xs, Wof, wm, wn, l, a2);
  #pragma unroll
  for (int mt=0; mt<4; ++mt)
    #pragma unroll
    for (int nt=0; nt<4; ++nt)
      #pragma unroll
      for (int reg=0; reg<4; ++reg){
        EPI_COORDS
        int orow = r0+row;
        int zrow = TRANS ? (((orow&255)<<8) | (orow>>8)) : orow;
        z[(size_t)zrow*128 + col] += a2[mt][nt][reg] + bo[col];
      }
}

// ---------- pair transition: z += relu(X@W1+b1)@W2 + b2  (K2=512 via 4 slices) ----------
__global__ void __launch_bounds__(256) k_pt(const short* __restrict__ X,
                                            const short* __restrict__ W1f, const float* __restrict__ b1,
                                            const short* __restrict__ W2f, const float* __restrict__ b2,
                                            float* __restrict__ z){
  __shared__ short xs[128*128];
  __shared__ short hs[128*128];
  GEMM_PROLOG
  stage128(X, xs, r0, tid);
  __syncthreads();
  f32x4 a2[4][4];
  #pragma unroll
  for(int a=0;a<4;a++) for(int b=0;b<4;b++) a2[a][b]=(f32x4){0,0,0,0};
  for (int m=0;m<4;++m){
    f32x4 a1[4][4];
    #pragma unroll
    for(int a=0;a<4;a++) for(int b=0;b<4;b++) a1[a][b]=(f32x4){0,0,0,0};
    gemm_core(xs, W1f + m*16384, wm, wn, l, a1);
    #pragma unroll
    for (int mt=0; mt<4; ++mt)
      #pragma unroll
      for (int nt=0; nt<4; ++nt)
        #pragma unroll
        for (int reg=0; reg<4; ++reg){
          EPI_COORDS
          float v = fmaxf(a1[mt][nt][reg] + b1[m*128 + col], 0.f);
          hs[row*128 + (((col>>3) ^ (row&15))<<3) + (col&7)] = f2b(v);
        }
    __syncthreads();
    gemm_core(hs, W2f + m*16384, wm, wn, l, a2);
    __syncthreads();
  }
  #pragma unroll
  for (int mt=0; mt<4; ++mt)
    #pragma unroll
    for (int nt=0; nt<4; ++nt)
      #pragma unroll
      for (int reg=0; reg<4; ++reg){
        EPI_COORDS
        z[(size_t)(r0+row)*128 + col] += a2[mt][nt][reg] + b2[col];
      }
}

// ---------- pack: bf16 [r][c] -> per-channel bf16 [c][x][y]; r = TR ? y*256+x : x*256+y ----------
template<bool TR>
__global__ void __launch_bounds__(256) pack_cxy(const short* __restrict__ inA, const short* __restrict__ inB,
                                                short* __restrict__ outA, short* __restrict__ outB){
  __shared__ short tile[256*144];
  const short* in = blockIdx.y ? inB : inA;
  short* out      = blockIdx.y ? outB : outA;
  int x = blockIdx.x, tid = threadIdx.x;
  #pragma unroll
  for (int m=0;m<16;++m){
    int idx = m*256 + tid;
    int y = idx>>4, c0 = (idx&15)*8;
    int r = TR ? (y*256 + x) : (x*256 + y);
    *(int4*)&tile[y*144 + c0] = *(const int4*)&in[(size_t)r*128 + c0];
  }
  __syncthreads();
  int c = tid & 127, yh = tid >> 7;
  short* ob = out + (size_t)c*65536 + x*256 + yh*128;
  #pragma unroll
  for (int yc=0; yc<16; ++yc){
    short tmp[8];
    #pragma unroll
    for (int e=0;e<8;e++) tmp[e] = tile[(yh*128 + yc*8 + e)*144 + c];
    *(int4*)&ob[yc*8] = *(int4*)tmp;
  }
}

// ---------- triangle einsum: T[c][i][j] = sum_k A[c][i][k]*B[c][j][k] ----------
__global__ void __launch_bounds__(256) k_einsum(const short* __restrict__ Ab,
                                                const short* __restrict__ Bb,
                                                float* __restrict__ Tt){
  __shared__ short as[128*64];
  __shared__ short bs[128*64];
  int c = blockIdx.z;
  int i0 = blockIdx.x*128, j0 = blockIdx.y*128;
  const short* A = Ab + (size_t)c*65536;
  const short* B = Bb + (size_t)c*65536;
  int tid = threadIdx.x;
  int wid = tid>>6, l = tid&63; int wm = wid>>1, wn = wid&1;
  f32x4 acc[4][4];
  #pragma unroll
  for(int a=0;a<4;a++) for(int b=0;b<4;b++) acc[a][b]=(f32x4){0,0,0,0};
  for (int kt=0; kt<4; ++kt){
    __syncthreads();
    #pragma unroll
    for (int m=0;m<4;++m){
      int idx = m*256 + tid;
      int row = idx>>3, ch = idx&7;
      *(int4*)&as[row*64 + ((ch ^ (row&7))<<3)] = *(const int4*)&A[(size_t)(i0+row)*256 + kt*64 + ch*8];
      *(int4*)&bs[row*64 + ((ch ^ (row&7))<<3)] = *(const int4*)&B[(size_t)(j0+row)*256 + kt*64 + ch*8];
    }
    __syncthreads();
    #pragma unroll
    for (int ks=0; ks<2; ++ks){
      bf16x8 a[4], b[4];
      #pragma unroll
      for (int mt=0; mt<4; ++mt){
        int row = wm*64 + mt*16 + (l&15);
        int ch  = (ks*4 + (l>>4)) ^ (row&7);
        a[mt] = *(const bf16x8*)&as[row*64 + ch*8];
      }
      #pragma unroll
      for (int nt=0; nt<4; ++nt){
        int row = wn*64 + nt*16 + (l&15);
        int ch  = (ks*4 + (l>>4)) ^ (row&7);
        b[nt] = *(const bf16x8*)&bs[row*64 + ch*8];
      }
      #pragma unroll
      for (int mt=0; mt<4; ++mt)
        #pragma unroll
        for (int nt=0; nt<4; ++nt)
          acc[mt][nt] = __builtin_amdgcn_mfma_f32_16x16x32_bf16(a[mt], b[nt], acc[mt][nt], 0,0,0);
    }
  }
  float* To = Tt + (size_t)c*65536;
  #pragma unroll
  for (int mt=0; mt<4; ++mt)
    #pragma unroll
    for (int nt=0; nt<4; ++nt)
      #pragma unroll
      for (int reg=0; reg<4; ++reg){
        int row = wm*64 + mt*16 + ((l>>4)<<2) + reg;
        int col = wn*64 + nt*16 + (l&15);
        To[(size_t)(i0+row)*256 + j0+col] = acc[mt][nt][reg];
      }
}

// ---------- LN over c of T stored [c][r]; out bf16 [r][c] ----------
__global__ void __launch_bounds__(256) ln_t(const float* __restrict__ Tt,
                                            const float* __restrict__ w,
                                            const float* __restrict__ b,
                                            short* __restrict__ out){
  __shared__ float tile[128*68];
  __shared__ float red_s[4][64], red_q[4][64];
  __shared__ float mu[64], inv[64];
  int tid = threadIdx.x;
  int r0 = blockIdx.x*64;
  for (int m=0;m<32;++m){
    int idx = m*256 + tid;
    int c = idx>>6, rl = idx&63;
    tile[c*68 + rl] = Tt[(size_t)c*65536 + r0 + rl];
  }
  __syncthreads();
  {
    int rl = tid & 63, cq = tid >> 6;
    float s = 0.f, q = 0.f;
    #pragma unroll
    for (int cc=0; cc<32; ++cc){
      float v = tile[(cq*32+cc)*68 + rl];
      s += v; q += v*v;
    }
    red_s[cq][rl] = s; red_q[cq][rl] = q;
  }
  __syncthreads();
  if (tid < 64){
    float s = red_s[0][tid]+red_s[1][tid]+red_s[2][tid]+red_s[3][tid];
    float q = red_q[0][tid]+red_q[1][tid]+red_q[2][tid]+red_q[3][tid];
    float m = s * (1.f/128.f);
    float var = q * (1.f/128.f) - m*m;
    mu[tid] = m; inv[tid] = rsqrtf(var + 1e-5f);
  }
  __syncthreads();
  {
    int rl = tid >> 2, cq = tid & 3;
    float m = mu[rl], iv = inv[rl];
    #pragma unroll
    for (int i=0;i<32;++i){
      int cc = cq*32 + i;
      float v = (tile[cc*68 + rl] - m) * iv * w[cc] + b[cc];
      out[(size_t)(r0+rl)*128 + cc] = f2b(v);
    }
  }
}

// ---------- bias[h,q,j] in C-fragment order (bf16 X input) ----------
__global__ void __launch_bounds__(256) bias_gemm(const short* __restrict__ X,
                                                 const float* __restrict__ bw,
                                                 float* __restrict__ BSF){
  __shared__ float xs[64][129];
  int r0 = blockIdx.x*64;
  for(int idx=threadIdx.x; idx<64*128; idx+=256)
    xs[idx>>7][idx&127] = b2f(X[(size_t)(r0+(idx>>7))*CZ + (idx&127)]);
  __syncthreads();
  int h = threadIdx.x>>6, r = threadIdx.x&63;
  float acc=0.f;
  #pragma unroll 4
  for(int k=0;k<CZ;k++) acc += xs[r][k]*bw[k*H_+h];
  int rr2 = r0 + r;
  int q = rr2 >> 8, j = rr2 & 255;
  int idx = (((h*16 + (q>>4))*16 + (j>>4)) << 8) + ((((j>>2)&3)*16 + (q&15)) << 2) + (j&3);
  BSF[idx] = acc;
}

// ---------- bf16 MFMA flash attention (bf16 q/k/v in, bf16 O out) ----------
__global__ void __launch_bounds__(256) attn_mfma(const short* __restrict__ Qg,
                                                 const short* __restrict__ Kg,
                                                 const short* __restrict__ Vg,
                                                 const float* __restrict__ BSF,
                                                 short* __restrict__ O){
  __shared__ short Qf[8192];
  __shared__ short Kf[8192];
  __shared__ short Vf[8192];
  __shared__ short Pf[4][4096];
  int i = blockIdx.x, h = blockIdx.y;
  int tid = threadIdx.x;
  #pragma unroll
  for (int m=0; m<4; ++m){
    int idx = m*256 + tid;
    int j = idx>>2, c0 = (idx&3)*8;
    bf16x8 qv = *(const bf16x8*)&Qg[(size_t)(i*N_+j)*CH + h*CA + c0];
    bf16x8 kv = *(const bf16x8*)&Kg[(size_t)(i*N_+j)*CH + h*CA + c0];
    bf16x8 vv = *(const bf16x8*)&Vg[(size_t)(i*N_+j)*CH + h*CA + c0];
    int lane = ((c0>>3)<<4) + (j&15);
    int base = (j>>4)*512 + lane*8;
    *(bf16x8*)&Qf[base] = qv;
    *(bf16x8*)&Kf[base] = kv;
    int jt2 = j>>5, lsub = ((j&31)>>3)<<4, e = j&7;
    #pragma unroll
    for (int cc=0; cc<8; ++cc){
      int c = c0+cc;
      Vf[(((c>>4)*8 + jt2)*64 + lsub + (c&15))*8 + e] = vv[cc];
    }
  }
  __syncthreads();

  int wid = tid >> 6, l = tid & 63;
  int lg = l >> 4, ln = l & 15;
  short* pw = &Pf[wid][0];

  for (int ss=0; ss<4; ++ss){
    int sub = wid*4 + ss;
    bf16x8 qfrag = *(const bf16x8*)&Qf[sub*512 + l*8];
    const float* bbase = &BSF[(((h*16 + sub)*16) << 8) + (l<<2)];
    f32x4 acc[16];
    #pragma unroll
    for (int t=0;t<16;t++) acc[t] = *(const f32x4*)&bbase[t<<8];
    #pragma unroll
    for (int t=0;t<16;t++){
      bf16x8 kf = *(const bf16x8*)&Kf[t*512 + l*8];
      acc[t] = __builtin_amdgcn_mfma_f32_16x16x32_bf16(kf, qfrag, acc[t], 0,0,0);
    }
    float mx = -1e30f;
    #pragma unroll
    for (int t=0;t<16;t++)
      mx = fmaxf(mx, fmaxf(fmaxf(acc[t][0],acc[t][1]), fmaxf(acc[t][2],acc[t][3])));
    mx = fmaxf(mx, __shfl_xor(mx,16,64));
    mx = fmaxf(mx, __shfl_xor(mx,32,64));
    float sum = 0.f;
    #pragma unroll
    for (int t=0;t<16;t++){
      #pragma unroll
      for (int r=0;r<4;r++){ float p = __expf(acc[t][r]-mx); acc[t][r]=p; sum += p; }
    }
    sum += __shfl_xor(sum,16,64);
    sum += __shfl_xor(sum,32,64);
    float iv = 1.0f / sum;
    #pragma unroll
    for (int t=0;t<16;t++){
      int j0 = t*16 + lg*4;
      short4 s4 = { f2b(acc[t][0]), f2b(acc[t][1]), f2b(acc[t][2]), f2b(acc[t][3]) };
      *(short4*)&pw[(j0>>5)*512 + ((((j0>>3)&3)<<4) + ln)*8 + (j0&7)] = s4;
    }
    #pragma unroll
    for (int ct=0; ct<2; ++ct){
      f32x4 o = {0.f,0.f,0.f,0.f};
      #pragma unroll
      for (int jt=0;jt<8;jt++){
        bf16x8 vf = *(const bf16x8*)&Vf[((ct*8 + jt)*64 + l)*8];
        bf16x8 pf = *(const bf16x8*)&pw[jt*512 + l*8];
        o = __builtin_amdgcn_mfma_f32_16x16x32_bf16(vf, pf, o, 0,0,0);
      }
      int q = sub*16 + ln;
      int c = ct*16 + lg*4;
      short4 ov = { f2b(o[0]*iv), f2b(o[1]*iv), f2b(o[2]*iv), f2b(o[3]*iv) };
      *(short4*)&O[(size_t)(i*N_+q)*CH + h*CA + c] = ov;
    }
  }
}

extern "C" void kernel_launch(void* const* d_in, const int* in_sizes, int n_in,
                              void* d_out, int out_size, void* d_ws, size_t ws_size,
                              hipStream_t stream) {
  const float* z_in      = (const float*)d_in[0];
  const float* tm_lnin_w = (const float*)d_in[1];
  const float* tm_lnin_b = (const float*)d_in[2];
  const float* tm_ap_w   = (const float*)d_in[3];
  const float* tm_ap_b   = (const float*)d_in[4];
  const float* tm_ag_w   = (const float*)d_in[5];
  const float* tm_ag_b   = (const float*)d_in[6];
  const float* tm_bp_w   = (const float*)d_in[7];
  const float* tm_bp_b   = (const float*)d_in[8];
  const float* tm_bg_w   = (const float*)d_in[9];
  const float* tm_bg_b   = (const float*)d_in[10];
  const float* tm_g_w    = (const float*)d_in[11];
  const float* tm_g_b    = (const float*)d_in[12];
  const float* tm_zo_w   = (const float*)d_in[13];
  const float* tm_zo_b   = (const float*)d_in[14];
  const float* tm_lno_w  = (const float*)d_in[15];
  const float* tm_lno_b  = (const float*)d_in[16];
  const float* ta_ln_w   = (const float*)d_in[17];
  const float* ta_ln_b   = (const float*)d_in[18];
  const float* ta_q_w    = (const float*)d_in[19];
  const float* ta_k_w    = (const float*)d_in[20];
  const float* ta_v_w    = (const float*)d_in[21];
  const float* ta_b_w    = (const float*)d_in[22];
  const float* ta_g_w    = (const float*)d_in[23];
  const float* ta_g_b    = (const float*)d_in[24];
  const float* ta_o_w    = (const float*)d_in[25];
  const float* ta_o_b    = (const float*)d_in[26];
  const float* pt_ln_w   = (const float*)d_in[27];
  const float* pt_ln_b   = (const float*)d_in[28];
  const float* pt_1_w    = (const float*)d_in[29];
  const float* pt_1_b    = (const float*)d_in[30];
  const float* pt_2_w    = (const float*)d_in[31];
  const float* pt_2_b    = (const float*)d_in[32];

  float* z  = (float*)d_out;
  char* base = (char*)d_ws;
  const size_t MB = 1u<<20;
  short* wf  = (short*)base;                 // 30 x 32KB frag blobs
  short* Xb  = (short*)(base + 1*MB);        // 16MB bf16 [r][c]
  short* R1  = (short*)(base + 17*MB);
  short* R2  = (short*)(base + 33*MB);
  short* R3  = (short*)(base + 49*MB);
  short* R4  = (short*)(base + 65*MB);
  float* Tf  = (float*)(base + 81*MB);       // 32MB fp32 [c][r]
  float* BSF = (float*)(base + 113*MB);      // 1MB

  #define SL(s) (wf + (size_t)(s)*16384)

  prep_weights<<<dim3(8,30), 256, 0, stream>>>(tm_ag_w, tm_ap_w, tm_bg_w, tm_bp_w,
                                               tm_g_w, tm_zo_w,
                                               ta_q_w, ta_k_w, ta_v_w, ta_g_w, ta_o_w,
                                               pt_1_w, pt_2_w, wf);

  // ---- triangle multiplication: outgoing (i=0), incoming (i=1) ----
  for (int i=0;i<2;i++){
    const float* zsrc = (i==0) ? z_in : z;
    ln_x<false><<<NN/4, 256, 0, stream>>>(zsrc, tm_lnin_w+i*CZ, tm_lnin_b+i*CZ, Xb);
    k_dual_gate<<<NN/128, 256, 0, stream>>>(Xb, SL(i*6+0), tm_ag_b+i*CH, SL(i*6+1), tm_ap_b+i*CH, R1);
    k_dual_gate<<<NN/128, 256, 0, stream>>>(Xb, SL(i*6+2), tm_bg_b+i*CH, SL(i*6+3), tm_bp_b+i*CH, R2);
    if (i==0) pack_cxy<false><<<dim3(256,2), 256, 0, stream>>>(R1, R2, R3, R4);
    else      pack_cxy<true ><<<dim3(256,2), 256, 0, stream>>>(R1, R2, R3, R4);
    k_einsum<<<dim3(2,2,128), 256, 0, stream>>>(R3, R4, Tf);
    ln_t<<<NN/64, 256, 0, stream>>>(Tf, tm_lno_w+i*CH, tm_lno_b+i*CH, R1);
    k_tri_finish<<<NN/128, 256, 0, stream>>>(R1, Xb, SL(i*6+5), tm_zo_b+i*CZ,
                                             SL(i*6+4), tm_g_b+i*CZ, zsrc, z);
  }

  // ---- triangle attention: starting (i=0), ending (i=1, transposed coords) ----
  for (int i=0;i<2;i++){
    if (i==0) ln_x<false><<<NN/4, 256, 0, stream>>>(z, ta_ln_w, ta_ln_b, Xb);
    else      ln_x<true ><<<NN/4, 256, 0, stream>>>(z, ta_ln_w+CZ, ta_ln_b+CZ, Xb);
    k_gemm<<<NN/128, 256, 0, stream>>>(Xb, SL(12+i*5+0), 0.17677669529663687f, R1);
    k_gemm<<<NN/128, 256, 0, stream>>>(Xb, SL(12+i*5+1), 1.f, R2);
    k_gemm<<<NN/128, 256, 0, stream>>>(Xb, SL(12+i*5+2), 1.f, R3);
    bias_gemm<<<NN/64, 256, 0, stream>>>(Xb, ta_b_w+i*CZ*H_, BSF);
    attn_mfma<<<dim3(N_,H_), 256, 0, stream>>>(R1, R2, R3, BSF, R4);
    if (i==0) k_attn_out<false><<<NN/128, 256, 0, stream>>>(R4, Xb, SL(12+i*5+3), ta_g_b+i*H_*CA,
                                                            SL(12+i*5+4), ta_o_b+i*CZ, z);
    else      k_attn_out<true ><<<NN/128, 256, 0, stream>>>(R4, Xb, SL(12+i*5+3), ta_g_b+i*H_*CA,
                                                            SL(12+i*5+4), ta_o_b+i*CZ, z);
  }

  // ---- pair transition ----
  ln_x<false><<<NN/4, 256, 0, stream>>>(z, pt_ln_w, pt_ln_b, Xb);
  k_pt<<<NN/128, 256, 0, stream>>>(Xb, SL(22), pt_1_b, SL(26), pt_2_b, z);
}

// Round 4
// 613.121 us; speedup vs baseline: 6.8088x; 1.0977x over previous
//
#include <hip/hip_runtime.h>
#include <math.h>

#define N_  256
#define NN  65536
#define CZ  128
#define CH  128
#define H_  4
#define CA  32

typedef __attribute__((ext_vector_type(8))) short bf16x8;
typedef __attribute__((ext_vector_type(4))) float f32x4;

__device__ __forceinline__ float sigmoidf_(float x){ return 1.f/(1.f+__expf(-x)); }

__device__ __forceinline__ short f2b(float f){
  unsigned u = __float_as_uint(f);
  unsigned r = (u + 0x7fffu + ((u>>16)&1u)) >> 16;
  return (short)r;
}
__device__ __forceinline__ float b2f(short s){
  unsigned u = ((unsigned)(unsigned short)s) << 16;
  return __uint_as_float(u);
}
__device__ __forceinline__ unsigned pk_bf16(float lo, float hi){
  unsigned r;
  asm volatile("v_cvt_pk_bf16_f32 %0, %1, %2" : "=v"(r) : "v"(lo), "v"(hi));
  return r;
}

__device__ __forceinline__ void glds16(const void* g, const void* l){
  __builtin_amdgcn_global_load_lds((const __attribute__((address_space(1))) void*)g,
                                   (__attribute__((address_space(3))) void*)l, 16, 0, 0);
}

__device__ __forceinline__ float wave_red_sum(float v){
  #pragma unroll
  for(int o=32;o>0;o>>=1) v += __shfl_xor(v,o,64);
  return v;
}

// K-row permutation: QK tile t, C-row m -> true key index j
__device__ __forceinline__ int Gperm(int t, int m){
  return ((t>>1)<<5) + ((m>>2)<<3) + ((t&1)<<2) + (m&3);
}

// ---------- weight prep: fp32 [K][N] slices -> bf16 B-fragment-packed blobs ----------
__global__ void __launch_bounds__(256) prep_weights(
    const float* tm_ag, const float* tm_ap, const float* tm_bg, const float* tm_bp,
    const float* tm_g, const float* tm_zo,
    const float* ta_q, const float* ta_k, const float* ta_v, const float* ta_g, const float* ta_o,
    const float* pt1, const float* pt2, short* Wf){
  int tid = threadIdx.x;
  int g = blockIdx.x*4 + (tid>>6);
  int l = tid & 63;
  int s = blockIdx.y;
  const float* src; int ldn = 128, koff = 0, noff = 0;
  if (s < 12){
    int i = s/6, w = s - i*6;
    switch(w){ case 0: src=tm_ag; break; case 1: src=tm_ap; break; case 2: src=tm_bg; break;
               case 3: src=tm_bp; break; case 4: src=tm_g;  break; default: src=tm_zo; }
    src += i*16384;
  } else if (s < 22){
    int t2 = s-12; int i = t2/5, w = t2 - i*5;
    switch(w){ case 0: src=ta_q; break; case 1: src=ta_k; break; case 2: src=ta_v; break;
               case 3: src=ta_g; break; default: src=ta_o; }
    src += i*16384;
  } else if (s < 26){
    src = pt1; ldn = 512; noff = (s-22)*128;
  } else {
    src = pt2; koff = (s-26)*128;
  }
  int nt = g>>2, ks = g&3;
  int n = noff + nt*16 + (l&15);
  int kb = koff + ks*32 + (l>>4)*8;
  short tmp[8];
  #pragma unroll
  for (int e=0;e<8;e++) tmp[e] = f2b(src[(size_t)(kb+e)*ldn + n]);
  short* dst = Wf + s*16384 + ((nt*4+ks)*64 + l)*8;
  *(short4*)dst     = *(short4*)&tmp[0];
  *(short4*)(dst+4) = *(short4*)&tmp[4];
}

// ---------- LayerNorm: fp32 in -> bf16 out; TRANS reads transposed grid ----------
template<bool TRANS>
__global__ void __launch_bounds__(256) ln_x(const float* __restrict__ in,
                                            const float* __restrict__ w,
                                            const float* __restrict__ b,
                                            short* __restrict__ out){
  int wid  = threadIdx.x >> 6;
  int lane = threadIdx.x & 63;
  int row  = blockIdx.x*4 + wid;
  int irow;
  if (TRANS){ int i = row >> 8, j = row & 255; irow = (j<<8) | i; } else irow = row;
  float v0 = in[(size_t)irow*CZ + lane];
  float v1 = in[(size_t)irow*CZ + lane + 64];
  float m  = wave_red_sum(v0+v1) * (1.f/128.f);
  float d0 = v0-m, d1 = v1-m;
  float var = wave_red_sum(d0*d0 + d1*d1) * (1.f/128.f);
  float r = rsqrtf(var + 1e-5f);
  out[(size_t)row*CZ + lane]      = f2b(d0*r*w[lane]    + b[lane]);
  out[(size_t)row*CZ + lane + 64] = f2b(d1*r*w[lane+64] + b[lane+64]);
}

// ---------- shared GEMM helpers ----------
// stage 128x128 bf16 tile via global_load_lds: linear LDS dest, swizzled source
__device__ __forceinline__ void stage128(const short* __restrict__ g, short* xs, int r0, int tid){
  #pragma unroll
  for (int m=0;m<8;++m){
    int d = m*256 + tid;
    int row = d>>4, cw = d&15;
    glds16(&g[(size_t)(r0+row)*128 + ((cw ^ (row&15))<<3)], xs + (size_t)(d & ~63)*8);
  }
}

__device__ __forceinline__ bf16x8 ldsA(const short* xs, int row, int ch){
  return *(const bf16x8*)&xs[row*128 + ((ch ^ (row&15))<<3)];
}

// core: 128 rows (LDS xs) x 128 cols (Wf frag blob), K=128
__device__ __forceinline__ void gemm_core(const short* xs, const short* __restrict__ wf,
                                          int wm, int wn, int l, f32x4 (&acc)[4][4]){
  #pragma unroll
  for (int ks=0; ks<4; ++ks){
    bf16x8 a[4], b[4];
    #pragma unroll
    for (int mt=0; mt<4; ++mt)
      a[mt] = ldsA(xs, wm*64 + mt*16 + (l&15), ks*4 + (l>>4));
    #pragma unroll
    for (int nt=0; nt<4; ++nt)
      b[nt] = *(const bf16x8*)&wf[(((wn*4+nt)*4 + ks)*64 + l)*8];
    #pragma unroll
    for (int mt=0; mt<4; ++mt)
      #pragma unroll
      for (int nt=0; nt<4; ++nt)
        acc[mt][nt] = __builtin_amdgcn_mfma_f32_16x16x32_bf16(a[mt], b[nt], acc[mt][nt], 0,0,0);
  }
}

// dual-W core sharing A-frags
__device__ __forceinline__ void gemm_core2(const short* xs, const short* __restrict__ wf1,
                                           const short* __restrict__ wf2,
                                           int wm, int wn, int l,
                                           f32x4 (&acc1)[4][4], f32x4 (&acc2)[4][4]){
  #pragma unroll
  for (int ks=0; ks<4; ++ks){
    bf16x8 a[4], b1[4], b2[4];
    #pragma unroll
    for (int mt=0; mt<4; ++mt)
      a[mt] = ldsA(xs, wm*64 + mt*16 + (l&15), ks*4 + (l>>4));
    #pragma unroll
    for (int nt=0; nt<4; ++nt){
      b1[nt] = *(const bf16x8*)&wf1[(((wn*4+nt)*4 + ks)*64 + l)*8];
      b2[nt] = *(const bf16x8*)&wf2[(((wn*4+nt)*4 + ks)*64 + l)*8];
    }
    #pragma unroll
    for (int mt=0; mt<4; ++mt)
      #pragma unroll
      for (int nt=0; nt<4; ++nt){
        acc1[mt][nt] = __builtin_amdgcn_mfma_f32_16x16x32_bf16(a[mt], b1[nt], acc1[mt][nt], 0,0,0);
        acc2[mt][nt] = __builtin_amdgcn_mfma_f32_16x16x32_bf16(a[mt], b2[nt], acc2[mt][nt], 0,0,0);
      }
  }
}

#define GEMM_PROLOG \
  int tid = threadIdx.x; int r0 = blockIdx.x*128; \
  int wid = tid>>6, l = tid&63; int wm = wid>>1, wn = wid&1;

#define EPI_COORDS \
  int row = wm*64 + mt*16 + ((l>>4)<<2) + reg; \
  int col = wn*64 + nt*16 + (l&15);

// ---------- out = sigmoid(X@Wg+bg) * (X@Wp+bp), bf16 out ----------
__global__ void __launch_bounds__(256) k_dual_gate(const short* __restrict__ X,
                                                   const short* __restrict__ Wgf, const float* __restrict__ bg,
                                                   const short* __restrict__ Wpf, const float* __restrict__ bp,
                                                   short* __restrict__ out){
  __shared__ short xs[128*128];
  GEMM_PROLOG
  stage128(X, xs, r0, tid);
  __syncthreads();
  f32x4 ag[4][4], ap[4][4];
  #pragma unroll
  for(int a=0;a<4;a++) for(int b=0;b<4;b++){ ag[a][b]=(f32x4){0,0,0,0}; ap[a][b]=(f32x4){0,0,0,0}; }
  gemm_core2(xs, Wgf, Wpf, wm, wn, l, ag, ap);
  #pragma unroll
  for (int mt=0; mt<4; ++mt)
    #pragma unroll
    for (int nt=0; nt<4; ++nt)
      #pragma unroll
      for (int reg=0; reg<4; ++reg){
        EPI_COORDS
        float v = (ap[mt][nt][reg] + bp[col]) * sigmoidf_(ag[mt][nt][reg] + bg[col]);
        out[(size_t)(r0+row)*128 + col] = f2b(v);
      }
}

// ---------- dual-GEMM: out1 = (X@W1)*s1, out2 = (X@W2)*s2 ----------
__global__ void __launch_bounds__(256) k_dual_scale(const short* __restrict__ X,
                                                    const short* __restrict__ W1f, float s1,
                                                    const short* __restrict__ W2f, float s2,
                                                    short* __restrict__ out1, short* __restrict__ out2){
  __shared__ short xs[128*128];
  GEMM_PROLOG
  stage128(X, xs, r0, tid);
  __syncthreads();
  f32x4 a1[4][4], a2[4][4];
  #pragma unroll
  for(int a=0;a<4;a++) for(int b=0;b<4;b++){ a1[a][b]=(f32x4){0,0,0,0}; a2[a][b]=(f32x4){0,0,0,0}; }
  gemm_core2(xs, W1f, W2f, wm, wn, l, a1, a2);
  #pragma unroll
  for (int mt=0; mt<4; ++mt)
    #pragma unroll
    for (int nt=0; nt<4; ++nt)
      #pragma unroll
      for (int reg=0; reg<4; ++reg){
        EPI_COORDS
        out1[(size_t)(r0+row)*128 + col] = f2b(a1[mt][nt][reg]*s1);
        out2[(size_t)(r0+row)*128 + col] = f2b(a2[mt][nt][reg]*s2);
      }
}

// ---------- V projection with transposed output: Vt[((i*4+h)*32+ca)*256 + j] ----------
__global__ void __launch_bounds__(256) k_gemm_t(const short* __restrict__ X,
                                                const short* __restrict__ Wf,
                                                short* __restrict__ Vt){
  __shared__ short xs[128*128];
  __shared__ short tt[128*132];
  GEMM_PROLOG
  stage128(X, xs, r0, tid);
  __syncthreads();
  f32x4 acc[4][4];
  #pragma unroll
  for(int a=0;a<4;a++) for(int b=0;b<4;b++) acc[a][b]=(f32x4){0,0,0,0};
  gemm_core(xs, Wf, wm, wn, l, acc);
  #pragma unroll
  for (int mt=0; mt<4; ++mt)
    #pragma unroll
    for (int nt=0; nt<4; ++nt)
      #pragma unroll
      for (int reg=0; reg<4; reg+=2){
        int row = wm*64 + mt*16 + ((l>>4)<<2) + reg;
        int col = wn*64 + nt*16 + (l&15);
        short2 p = { f2b(acc[mt][nt][reg]), f2b(acc[mt][nt][reg+1]) };
        *(short2*)&tt[col*132 + row] = p;
      }
  __syncthreads();
  int i = r0>>8, j0 = r0&255;
  #pragma unroll
  for (int m=0;m<8;++m){
    int idx = m*256 + tid;
    int c = idx>>4, ch = idx&15;
    int4 val = *(const int4*)&tt[c*132 + ch*8];
    *(int4*)&Vt[(size_t)((i*4 + (c>>5))*32 + (c&31))*256 + j0 + ch*8] = val;
  }
}

// ---------- zout = zin + (T2@Wz+bz)*sigmoid(X@Wg+bg) ----------
__global__ void __launch_bounds__(256) k_tri_finish(const short* __restrict__ T2,
                                                    const short* __restrict__ X,
                                                    const short* __restrict__ Wzf, const float* __restrict__ bz,
                                                    const short* __restrict__ Wgf, const float* __restrict__ bg,
                                                    const float* __restrict__ zin, float* __restrict__ zout){
  __shared__ short ts[128*128];
  __shared__ short xs[128*128];
  GEMM_PROLOG
  stage128(T2, ts, r0, tid);
  stage128(X,  xs, r0, tid);
  __syncthreads();
  f32x4 az[4][4], ag[4][4];
  #pragma unroll
  for(int a=0;a<4;a++) for(int b=0;b<4;b++){ az[a][b]=(f32x4){0,0,0,0}; ag[a][b]=(f32x4){0,0,0,0}; }
  gemm_core(ts, Wzf, wm, wn, l, az);
  gemm_core(xs, Wgf, wm, wn, l, ag);
  #pragma unroll
  for (int mt=0; mt<4; ++mt)
    #pragma unroll
    for (int nt=0; nt<4; ++nt)
      #pragma unroll
      for (int reg=0; reg<4; ++reg){
        EPI_COORDS
        size_t idx = (size_t)(r0+row)*128 + col;
        float v = (az[mt][nt][reg] + bz[col]) * sigmoidf_(ag[mt][nt][reg] + bg[col]);
        zout[idx] = zin[idx] + v;
      }
}

// ---------- z(±T) += ((O*sigmoid(X@Wg+bg)) @ Wo + bo) ----------
template<bool TRANS>
__global__ void __launch_bounds__(256) k_attn_out(const short* __restrict__ O,
                                                  const short* __restrict__ X,
                                                  const short* __restrict__ Wgf, const float* __restrict__ bg,
                                                  const short* __restrict__ Wof, const float* __restrict__ bo,
                                                  float* __restrict__ z){
  __shared__ short xs[128*128];
  __shared__ short os[128*128];
  GEMM_PROLOG
  stage128(X, xs, r0, tid);
  #pragma unroll
  for (int m=0;m<8;++m){
    int d = m*256 + tid;
    int row = d>>4, ch = d&15;
    glds16(&O[(size_t)(r0+row)*128 + ch*8], os + (size_t)(d & ~63)*8);
  }
  __syncthreads();
  f32x4 ag[4][4];
  #pragma unroll
  for(int a=0;a<4;a++) for(int b=0;b<4;b++) ag[a][b]=(f32x4){0,0,0,0};
  gemm_core(xs, Wgf, wm, wn, l, ag);
  __syncthreads();
  #pragma unroll
  for (int mt=0; mt<4; ++mt)
    #pragma unroll
    for (int nt=0; nt<4; ++nt)
      #pragma unroll
      for (int reg=0; reg<4; ++reg){
        EPI_COORDS
        float ov = b2f(os[row*128 + col]);
        float v = ov * sigmoidf_(ag[mt][nt][reg] + bg[col]);
        xs[row*128 + (((col>>3) ^ (row&15))<<3) + (col&7)] = f2b(v);
      }
  __syncthreads();
  f32x4 a2[4][4];
  #pragma unroll
  for(int a=0;a<4;a++) for(int b=0;b<4;b++) a2[a][b]=(f32x4){0,0,0,0};
  gemm_core(xs, Wof, wm, wn, l, a2);
  #pragma unroll
  for (int mt=0; mt<4; ++mt)
    #pragma unroll
    for (int nt=0; nt<4; ++nt)
      #pragma unroll
      for (int reg=0; reg<4; ++reg){
        EPI_COORDS
        int orow = r0+row;
        int zrow = TRANS ? (((orow&255)<<8) | (orow>>8)) : orow;
        z[(size_t)zrow*128 + col] += a2[mt][nt][reg] + bo[col];
      }
}

// ---------- pair transition: z += relu(X@W1+b1)@W2 + b2 ----------
__global__ void __launch_bounds__(256) k_pt(const short* __restrict__ X,
                                            const short* __restrict__ W1f, const float* __restrict__ b1,
                                            const short* __restrict__ W2f, const float* __restrict__ b2,
                                            float* __restrict__ z){
  __shared__ short xs[128*128];
  __shared__ short hs[128*128];
  GEMM_PROLOG
  stage128(X, xs, r0, tid);
  __syncthreads();
  f32x4 a2[4][4];
  #pragma unroll
  for(int a=0;a<4;a++) for(int b=0;b<4;b++) a2[a][b]=(f32x4){0,0,0,0};
  for (int m=0;m<4;++m){
    f32x4 a1[4][4];
    #pragma unroll
    for(int a=0;a<4;a++) for(int b=0;b<4;b++) a1[a][b]=(f32x4){0,0,0,0};
    gemm_core(xs, W1f + m*16384, wm, wn, l, a1);
    #pragma unroll
    for (int mt=0; mt<4; ++mt)
      #pragma unroll
      for (int nt=0; nt<4; ++nt)
        #pragma unroll
        for (int reg=0; reg<4; ++reg){
          EPI_COORDS
          float v = fmaxf(a1[mt][nt][reg] + b1[m*128 + col], 0.f);
          hs[row*128 + (((col>>3) ^ (row&15))<<3) + (col&7)] = f2b(v);
        }
    __syncthreads();
    gemm_core(hs, W2f + m*16384, wm, wn, l, a2);
    __syncthreads();
  }
  #pragma unroll
  for (int mt=0; mt<4; ++mt)
    #pragma unroll
    for (int nt=0; nt<4; ++nt)
      #pragma unroll
      for (int reg=0; reg<4; ++reg){
        EPI_COORDS
        z[(size_t)(r0+row)*128 + col] += a2[mt][nt][reg] + b2[col];
      }
}

// ---------- pack: bf16 [r][c] -> per-channel bf16 [c][x][y]; r = TR ? y*256+x : x*256+y ----------
template<bool TR>
__global__ void __launch_bounds__(256) pack_cxy(const short* __restrict__ inA, const short* __restrict__ inB,
                                                short* __restrict__ outA, short* __restrict__ outB){
  __shared__ short tile[256*144];
  const short* in = blockIdx.y ? inB : inA;
  short* out      = blockIdx.y ? outB : outA;
  int x = blockIdx.x, tid = threadIdx.x;
  #pragma unroll
  for (int m=0;m<16;++m){
    int idx = m*256 + tid;
    int y = idx>>4, c0 = (idx&15)*8;
    int r = TR ? (y*256 + x) : (x*256 + y);
    *(int4*)&tile[y*144 + c0] = *(const int4*)&in[(size_t)r*128 + c0];
  }
  __syncthreads();
  int c = tid & 127, yh = tid >> 7;
  short* ob = out + (size_t)c*65536 + x*256 + yh*128;
  #pragma unroll
  for (int yc=0; yc<16; ++yc){
    short tmp[8];
    #pragma unroll
    for (int e=0;e<8;e++) tmp[e] = tile[(yh*128 + yc*8 + e)*144 + c];
    *(int4*)&ob[yc*8] = *(int4*)tmp;
  }
}

// ---------- triangle einsum: T[c][i][j] = sum_k A[c][i][k]*B[c][j][k] ----------
__global__ void __launch_bounds__(256) k_einsum(const short* __restrict__ Ab,
                                                const short* __restrict__ Bb,
                                                float* __restrict__ Tt){
  __shared__ short as[128*64];
  __shared__ short bs[128*64];
  int c = blockIdx.z;
  int i0 = blockIdx.x*128, j0 = blockIdx.y*128;
  const short* A = Ab + (size_t)c*65536;
  const short* B = Bb + (size_t)c*65536;
  int tid = threadIdx.x;
  int wid = tid>>6, l = tid&63; int wm = wid>>1, wn = wid&1;
  f32x4 acc[4][4];
  #pragma unroll
  for(int a=0;a<4;a++) for(int b=0;b<4;b++) acc[a][b]=(f32x4){0,0,0,0};
  for (int kt=0; kt<4; ++kt){
    __syncthreads();
    #pragma unroll
    for (int m=0;m<4;++m){
      int d = m*256 + tid;
      int row = d>>3, cw = d&7;
      glds16(&A[(size_t)(i0+row)*256 + kt*64 + ((cw ^ (row&7))<<3)], as + (size_t)(d & ~63)*8);
      glds16(&B[(size_t)(j0+row)*256 + kt*64 + ((cw ^ (row&7))<<3)], bs + (size_t)(d & ~63)*8);
    }
    __syncthreads();
    #pragma unroll
    for (int ks=0; ks<2; ++ks){
      bf16x8 a[4], b[4];
      #pragma unroll
      for (int mt=0; mt<4; ++mt){
        int row = wm*64 + mt*16 + (l&15);
        int ch  = (ks*4 + (l>>4)) ^ (row&7);
        a[mt] = *(const bf16x8*)&as[row*64 + ch*8];
      }
      #pragma unroll
      for (int nt=0; nt<4; ++nt){
        int row = wn*64 + nt*16 + (l&15);
        int ch  = (ks*4 + (l>>4)) ^ (row&7);
        b[nt] = *(const bf16x8*)&bs[row*64 + ch*8];
      }
      #pragma unroll
      for (int mt=0; mt<4; ++mt)
        #pragma unroll
        for (int nt=0; nt<4; ++nt)
          acc[mt][nt] = __builtin_amdgcn_mfma_f32_16x16x32_bf16(a[mt], b[nt], acc[mt][nt], 0,0,0);
    }
  }
  float* To = Tt + (size_t)c*65536;
  #pragma unroll
  for (int mt=0; mt<4; ++mt)
    #pragma unroll
    for (int nt=0; nt<4; ++nt)
      #pragma unroll
      for (int reg=0; reg<4; ++reg){
        int row = wm*64 + mt*16 + ((l>>4)<<2) + reg;
        int col = wn*64 + nt*16 + (l&15);
        To[(size_t)(i0+row)*256 + j0+col] = acc[mt][nt][reg];
      }
}

// ---------- LN over c of T stored [c][r]; out bf16 [r][c] ----------
__global__ void __launch_bounds__(256) ln_t(const float* __restrict__ Tt,
                                            const float* __restrict__ w,
                                            const float* __restrict__ b,
                                            short* __restrict__ out){
  __shared__ float tile[128*68];
  __shared__ float red_s[4][64], red_q[4][64];
  __shared__ float mu[64], inv[64];
  int tid = threadIdx.x;
  int r0 = blockIdx.x*64;
  for (int m=0;m<32;++m){
    int idx = m*256 + tid;
    int c = idx>>6, rl = idx&63;
    tile[c*68 + rl] = Tt[(size_t)c*65536 + r0 + rl];
  }
  __syncthreads();
  {
    int rl = tid & 63, cq = tid >> 6;
    float s = 0.f, q = 0.f;
    #pragma unroll
    for (int cc=0; cc<32; ++cc){
      float v = tile[(cq*32+cc)*68 + rl];
      s += v; q += v*v;
    }
    red_s[cq][rl] = s; red_q[cq][rl] = q;
  }
  __syncthreads();
  if (tid < 64){
    float s = red_s[0][tid]+red_s[1][tid]+red_s[2][tid]+red_s[3][tid];
    float q = red_q[0][tid]+red_q[1][tid]+red_q[2][tid]+red_q[3][tid];
    float m = s * (1.f/128.f);
    float var = q * (1.f/128.f) - m*m;
    mu[tid] = m; inv[tid] = rsqrtf(var + 1e-5f);
  }
  __syncthreads();
  {
    int rl = tid >> 2, cq = tid & 3;
    float m = mu[rl], iv = inv[rl];
    #pragma unroll
    for (int i=0;i<32;++i){
      int cc = cq*32 + i;
      float v = (tile[cc*68 + rl] - m) * iv * w[cc] + b[cc];
      out[(size_t)(r0+rl)*128 + cc] = f2b(v);
    }
  }
}

// ---------- bias in PERMUTED C-fragment order matching Gperm ----------
__global__ void __launch_bounds__(256) bias_gemm(const short* __restrict__ X,
                                                 const float* __restrict__ bw,
                                                 float* __restrict__ BSF){
  __shared__ float xs[64][129];
  int r0 = blockIdx.x*64;
  for(int idx=threadIdx.x; idx<64*128; idx+=256)
    xs[idx>>7][idx&127] = b2f(X[(size_t)(r0+(idx>>7))*CZ + (idx&127)]);
  __syncthreads();
  int h = threadIdx.x>>6, r = threadIdx.x&63;
  float acc=0.f;
  #pragma unroll 4
  for(int k=0;k<CZ;k++) acc += xs[r][k]*bw[k*H_+h];
  int rr2 = r0 + r;
  int q = rr2 >> 8, j = rr2 & 255;
  int t = ((j>>5)<<1) + ((j>>2)&1);
  int m = (((j>>3)&3)<<2) + (j&3);
  int idx = (((h*16 + (q>>4))*16 + t) << 8) + (((m>>2)*16 + (q&15)) << 2) + (m&3);
  BSF[idx] = acc;
}

// ---------- bf16 MFMA flash attention, Gperm-K, reg-Q, transposed-V, no P LDS ----------
__global__ void __launch_bounds__(256, 3) attn_mfma(const short* __restrict__ Qg,
                                                    const short* __restrict__ Kg,
                                                    const short* __restrict__ Vt,
                                                    const float* __restrict__ BSF,
                                                    short* __restrict__ O){
  __shared__ short Kf[8192];
  __shared__ short Vf[8192];
  int i = blockIdx.x, h = blockIdx.y;
  int tid = threadIdx.x;
  // stage K blob (G-permuted rows) and V blob (from transposed Vt), linear LDS dest
  #pragma unroll
  for (int m=0;m<4;++m){
    int d = m*256 + tid;
    int t = d>>6, ll = d&63;
    glds16(&Kg[(size_t)(i*N_ + Gperm(t, ll&15))*CH + h*CA + ((ll>>4)<<3)],
           Kf + (size_t)(d & ~63)*8);
    glds16(&Vt[(size_t)(((i*H_ + h)*CA) + ((t>>3)<<4) + (ll&15))*N_ + ((t&7)<<5) + ((ll>>4)<<3)],
           Vf + (size_t)(d & ~63)*8);
  }
  __syncthreads();

  int wid = tid >> 6, l = tid & 63;
  int lg = l >> 4, ln = l & 15;

  for (int ss=0; ss<4; ++ss){
    int sub = wid*4 + ss;
    bf16x8 qfrag = *(const bf16x8*)&Qg[(size_t)(i*N_ + sub*16 + ln)*CH + h*CA + (lg<<3)];
    const float* bb = BSF + (size_t)(h*16 + sub)*4096 + (l<<2);
    f32x4 acc[16];
    #pragma unroll
    for (int t=0;t<16;t++) acc[t] = *(const f32x4*)&bb[t<<8];
    #pragma unroll
    for (int t=0;t<16;t++){
      bf16x8 kf = *(const bf16x8*)&Kf[t*512 + l*8];
      acc[t] = __builtin_amdgcn_mfma_f32_16x16x32_bf16(kf, qfrag, acc[t], 0,0,0);
    }
    // softmax (lane owns q = sub*16+ln across 64 regs; q replicated over lg -> xor16/32 reduce)
    float mx = -1e30f;
    #pragma unroll
    for (int t=0;t<16;t++)
      mx = fmaxf(mx, fmaxf(fmaxf(acc[t][0],acc[t][1]), fmaxf(acc[t][2],acc[t][3])));
    mx = fmaxf(mx, __shfl_xor(mx,16,64));
    mx = fmaxf(mx, __shfl_xor(mx,32,64));
    float sum = 0.f;
    #pragma unroll
    for (int t=0;t<16;t++){
      #pragma unroll
      for (int r=0;r<4;r++){ float p = __expf(acc[t][r]-mx); acc[t][r]=p; sum += p; }
    }
    sum += __shfl_xor(sum,16,64);
    sum += __shfl_xor(sum,32,64);
    float iv = 1.0f / sum;
    // P B-frags are lane-local thanks to Gperm
    bf16x8 pf[8];
    #pragma unroll
    for (int jt=0;jt<8;jt++){
      int4 w4;
      w4.x = pk_bf16(acc[2*jt  ][0], acc[2*jt  ][1]);
      w4.y = pk_bf16(acc[2*jt  ][2], acc[2*jt  ][3]);
      w4.z = pk_bf16(acc[2*jt+1][0], acc[2*jt+1][1]);
      w4.w = pk_bf16(acc[2*jt+1][2], acc[2*jt+1][3]);
      pf[jt] = *(bf16x8*)&w4;
    }
    // PV: O^T = V^T . P^T  (two interleaved chains to halve dependent-MFMA latency)
    #pragma unroll
    for (int ct=0; ct<2; ++ct){
      f32x4 oe = {0.f,0.f,0.f,0.f}, oo = {0.f,0.f,0.f,0.f};
      #pragma unroll
      for (int jt=0;jt<8;jt+=2){
        bf16x8 ve = *(const bf16x8*)&Vf[((ct*8 + jt  )*64 + l)*8];
        bf16x8 vo = *(const bf16x8*)&Vf[((ct*8 + jt+1)*64 + l)*8];
        oe = __builtin_amdgcn_mfma_f32_16x16x32_bf16(ve, pf[jt  ], oe, 0,0,0);
        oo = __builtin_amdgcn_mfma_f32_16x16x32_bf16(vo, pf[jt+1], oo, 0,0,0);
      }
      int q = sub*16 + ln;
      int c = ct*16 + lg*4;
      short4 ov = { f2b((oe[0]+oo[0])*iv), f2b((oe[1]+oo[1])*iv),
                    f2b((oe[2]+oo[2])*iv), f2b((oe[3]+oo[3])*iv) };
      *(short4*)&O[(size_t)(i*N_ + q)*CH + h*CA + c] = ov;
    }
  }
}

extern "C" void kernel_launch(void* const* d_in, const int* in_sizes, int n_in,
                              void* d_out, int out_size, void* d_ws, size_t ws_size,
                              hipStream_t stream) {
  const float* z_in      = (const float*)d_in[0];
  const float* tm_lnin_w = (const float*)d_in[1];
  const float* tm_lnin_b = (const float*)d_in[2];
  const float* tm_ap_w   = (const float*)d_in[3];
  const float* tm_ap_b   = (const float*)d_in[4];
  const float* tm_ag_w   = (const float*)d_in[5];
  const float* tm_ag_b   = (const float*)d_in[6];
  const float* tm_bp_w   = (const float*)d_in[7];
  const float* tm_bp_b   = (const float*)d_in[8];
  const float* tm_bg_w   = (const float*)d_in[9];
  const float* tm_bg_b   = (const float*)d_in[10];
  const float* tm_g_w    = (const float*)d_in[11];
  const float* tm_g_b    = (const float*)d_in[12];
  const float* tm_zo_w   = (const float*)d_in[13];
  const float* tm_zo_b   = (const float*)d_in[14];
  const float* tm_lno_w  = (const float*)d_in[15];
  const float* tm_lno_b  = (const float*)d_in[16];
  const float* ta_ln_w   = (const float*)d_in[17];
  const float* ta_ln_b   = (const float*)d_in[18];
  const float* ta_q_w    = (const float*)d_in[19];
  const float* ta_k_w    = (const float*)d_in[20];
  const float* ta_v_w    = (const float*)d_in[21];
  const float* ta_b_w    = (const float*)d_in[22];
  const float* ta_g_w    = (const float*)d_in[23];
  const float* ta_g_b    = (const float*)d_in[24];
  const float* ta_o_w    = (const float*)d_in[25];
  const float* ta_o_b    = (const float*)d_in[26];
  const float* pt_ln_w   = (const float*)d_in[27];
  const float* pt_ln_b   = (const float*)d_in[28];
  const float* pt_1_w    = (const float*)d_in[29];
  const float* pt_1_b    = (const float*)d_in[30];
  const float* pt_2_w    = (const float*)d_in[31];
  const float* pt_2_b    = (const float*)d_in[32];

  float* z  = (float*)d_out;
  char* base = (char*)d_ws;
  const size_t MB = 1u<<20;
  short* wf  = (short*)base;                 // 30 x 32KB frag blobs
  short* Xb  = (short*)(base + 1*MB);        // 16MB bf16 [r][c]
  short* R1  = (short*)(base + 17*MB);
  short* R2  = (short*)(base + 33*MB);
  short* R3  = (short*)(base + 49*MB);       // Vt for attention
  short* R4  = (short*)(base + 65*MB);
  float* Tf  = (float*)(base + 81*MB);       // 32MB fp32 [c][r]
  float* BSF = (float*)(base + 113*MB);      // 1MB

  #define SL(s) (wf + (size_t)(s)*16384)

  prep_weights<<<dim3(8,30), 256, 0, stream>>>(tm_ag_w, tm_ap_w, tm_bg_w, tm_bp_w,
                                               tm_g_w, tm_zo_w,
                                               ta_q_w, ta_k_w, ta_v_w, ta_g_w, ta_o_w,
                                               pt_1_w, pt_2_w, wf);

  // ---- triangle multiplication: outgoing (i=0), incoming (i=1) ----
  for (int i=0;i<2;i++){
    const float* zsrc = (i==0) ? z_in : z;
    ln_x<false><<<NN/4, 256, 0, stream>>>(zsrc, tm_lnin_w+i*CZ, tm_lnin_b+i*CZ, Xb);
    k_dual_gate<<<NN/128, 256, 0, stream>>>(Xb, SL(i*6+0), tm_ag_b+i*CH, SL(i*6+1), tm_ap_b+i*CH, R1);
    k_dual_gate<<<NN/128, 256, 0, stream>>>(Xb, SL(i*6+2), tm_bg_b+i*CH, SL(i*6+3), tm_bp_b+i*CH, R2);
    if (i==0) pack_cxy<false><<<dim3(256,2), 256, 0, stream>>>(R1, R2, R3, R4);
    else      pack_cxy<true ><<<dim3(256,2), 256, 0, stream>>>(R1, R2, R3, R4);
    k_einsum<<<dim3(2,2,128), 256, 0, stream>>>(R3, R4, Tf);
    ln_t<<<NN/64, 256, 0, stream>>>(Tf, tm_lno_w+i*CH, tm_lno_b+i*CH, R1);
    k_tri_finish<<<NN/128, 256, 0, stream>>>(R1, Xb, SL(i*6+5), tm_zo_b+i*CZ,
                                             SL(i*6+4), tm_g_b+i*CZ, zsrc, z);
  }

  // ---- triangle attention: starting (i=0), ending (i=1, transposed coords) ----
  for (int i=0;i<2;i++){
    if (i==0) ln_x<false><<<NN/4, 256, 0, stream>>>(z, ta_ln_w, ta_ln_b, Xb);
    else      ln_x<true ><<<NN/4, 256, 0, stream>>>(z, ta_ln_w+CZ, ta_ln_b+CZ, Xb);
    k_dual_scale<<<NN/128, 256, 0, stream>>>(Xb, SL(12+i*5+0), 0.17677669529663687f,
                                             SL(12+i*5+1), 1.f, R1, R2);
    k_gemm_t<<<NN/128, 256, 0, stream>>>(Xb, SL(12+i*5+2), R3);
    bias_gemm<<<NN/64, 256, 0, stream>>>(Xb, ta_b_w+i*CZ*H_, BSF);
    attn_mfma<<<dim3(N_,H_), 256, 0, stream>>>(R1, R2, R3, BSF, R4);
    if (i==0) k_attn_out<false><<<NN/128, 256, 0, stream>>>(R4, Xb, SL(12+i*5+3), ta_g_b+i*H_*CA,
                                                            SL(12+i*5+4), ta_o_b+i*CZ, z);
    else      k_attn_out<true ><<<NN/128, 256, 0, stream>>>(R4, Xb, SL(12+i*5+3), ta_g_b+i*H_*CA,
                                                            SL(12+i*5+4), ta_o_b+i*CZ, z);
  }

  // ---- pair transition ----
  ln_x<false><<<NN/4, 256, 0, stream>>>(z, pt_ln_w, pt_ln_b, Xb);
  k_pt<<<NN/128, 256, 0, stream>>>(Xb, SL(22), pt_1_b, SL(26), pt_2_b, z);
}

// Round 5
// 602.960 us; speedup vs baseline: 6.9235x; 1.0169x over previous
//
#include <hip/hip_runtime.h>
#include <math.h>

#define N_  256
#define NN  65536
#define CZ  128
#define CH  128
#define H_  4
#define CA  32

typedef __attribute__((ext_vector_type(8))) short bf16x8;
typedef __attribute__((ext_vector_type(4))) float f32x4;

__device__ __forceinline__ float sigmoidf_(float x){ return 1.f/(1.f+__expf(-x)); }

__device__ __forceinline__ short f2b(float f){
  unsigned u = __float_as_uint(f);
  unsigned r = (u + 0x7fffu + ((u>>16)&1u)) >> 16;
  return (short)r;
}
__device__ __forceinline__ float b2f(short s){
  unsigned u = ((unsigned)(unsigned short)s) << 16;
  return __uint_as_float(u);
}
__device__ __forceinline__ unsigned pk_bf16(float lo, float hi){
  unsigned r;
  asm volatile("v_cvt_pk_bf16_f32 %0, %1, %2" : "=v"(r) : "v"(lo), "v"(hi));
  return r;
}

__device__ __forceinline__ void glds16(const void* g, const void* l){
  __builtin_amdgcn_global_load_lds((const __attribute__((address_space(1))) void*)g,
                                   (__attribute__((address_space(3))) void*)l, 16, 0, 0);
}

__device__ __forceinline__ float wave_red_sum(float v){
  #pragma unroll
  for(int o=32;o>0;o>>=1) v += __shfl_xor(v,o,64);
  return v;
}

// K-row permutation: QK tile t, C-row m -> true key index j
__device__ __forceinline__ int Gperm(int t, int m){
  return ((t>>1)<<5) + ((m>>2)<<3) + ((t&1)<<2) + (m&3);
}

// ---------- weight prep: fp32 [K][N] slices -> bf16 B-fragment-packed blobs ----------
__global__ void __launch_bounds__(256) prep_weights(
    const float* tm_ag, const float* tm_ap, const float* tm_bg, const float* tm_bp,
    const float* tm_g, const float* tm_zo,
    const float* ta_q, const float* ta_k, const float* ta_v, const float* ta_g, const float* ta_o,
    const float* pt1, const float* pt2, short* Wf){
  int tid = threadIdx.x;
  int g = blockIdx.x*4 + (tid>>6);
  int l = tid & 63;
  int s = blockIdx.y;
  const float* src; int ldn = 128, koff = 0, noff = 0;
  if (s < 12){
    int i = s/6, w = s - i*6;
    switch(w){ case 0: src=tm_ag; break; case 1: src=tm_ap; break; case 2: src=tm_bg; break;
               case 3: src=tm_bp; break; case 4: src=tm_g;  break; default: src=tm_zo; }
    src += i*16384;
  } else if (s < 22){
    int t2 = s-12; int i = t2/5, w = t2 - i*5;
    switch(w){ case 0: src=ta_q; break; case 1: src=ta_k; break; case 2: src=ta_v; break;
               case 3: src=ta_g; break; default: src=ta_o; }
    src += i*16384;
  } else if (s < 26){
    src = pt1; ldn = 512; noff = (s-22)*128;
  } else {
    src = pt2; koff = (s-26)*128;
  }
  int nt = g>>2, ks = g&3;
  int n = noff + nt*16 + (l&15);
  int kb = koff + ks*32 + (l>>4)*8;
  short tmp[8];
  #pragma unroll
  for (int e=0;e<8;e++) tmp[e] = f2b(src[(size_t)(kb+e)*ldn + n]);
  short* dst = Wf + s*16384 + ((nt*4+ks)*64 + l)*8;
  *(short4*)dst     = *(short4*)&tmp[0];
  *(short4*)(dst+4) = *(short4*)&tmp[4];
}

// ---------- LayerNorm: fp32 in -> bf16 out; TRANS reads transposed grid ----------
template<bool TRANS>
__global__ void __launch_bounds__(256) ln_x(const float* __restrict__ in,
                                            const float* __restrict__ w,
                                            const float* __restrict__ b,
                                            short* __restrict__ out){
  int wid  = threadIdx.x >> 6;
  int lane = threadIdx.x & 63;
  int row  = blockIdx.x*4 + wid;
  int irow;
  if (TRANS){ int i = row >> 8, j = row & 255; irow = (j<<8) | i; } else irow = row;
  float v0 = in[(size_t)irow*CZ + lane];
  float v1 = in[(size_t)irow*CZ + lane + 64];
  float m  = wave_red_sum(v0+v1) * (1.f/128.f);
  float d0 = v0-m, d1 = v1-m;
  float var = wave_red_sum(d0*d0 + d1*d1) * (1.f/128.f);
  float r = rsqrtf(var + 1e-5f);
  out[(size_t)row*CZ + lane]      = f2b(d0*r*w[lane]    + b[lane]);
  out[(size_t)row*CZ + lane + 64] = f2b(d1*r*w[lane+64] + b[lane+64]);
}

// ---------- 8-wave GEMM helpers (512 threads, 128x128 tile) ----------
__device__ __forceinline__ void stage128_8(const short* __restrict__ g, short* xs, int r0, int tid){
  #pragma unroll
  for (int m=0;m<4;++m){
    int d = m*512 + tid;
    int row = d>>4, cw = d&15;
    glds16(&g[(size_t)(r0+row)*128 + ((cw ^ (row&15))<<3)], xs + (size_t)(d & ~63)*8);
  }
}

__device__ __forceinline__ bf16x8 ldsA(const short* xs, int row, int ch){
  return *(const bf16x8*)&xs[row*128 + ((ch ^ (row&15))<<3)];
}

// wave wm in 0..3 owns rows wm*32..+32 ; wn in 0..1 owns cols wn*64..+64
__device__ __forceinline__ void gemm_core8(const short* xs, const short* __restrict__ wf,
                                           int wm, int wn, int l, f32x4 (&acc)[2][4]){
  #pragma unroll
  for (int ks=0; ks<4; ++ks){
    bf16x8 a[2], b[4];
    #pragma unroll
    for (int mt=0; mt<2; ++mt)
      a[mt] = ldsA(xs, wm*32 + mt*16 + (l&15), ks*4 + (l>>4));
    #pragma unroll
    for (int nt=0; nt<4; ++nt)
      b[nt] = *(const bf16x8*)&wf[(((wn*4+nt)*4 + ks)*64 + l)*8];
    #pragma unroll
    for (int mt=0; mt<2; ++mt)
      #pragma unroll
      for (int nt=0; nt<4; ++nt)
        acc[mt][nt] = __builtin_amdgcn_mfma_f32_16x16x32_bf16(a[mt], b[nt], acc[mt][nt], 0,0,0);
  }
}

__device__ __forceinline__ void gemm_core28(const short* xs, const short* __restrict__ wf1,
                                            const short* __restrict__ wf2,
                                            int wm, int wn, int l,
                                            f32x4 (&acc1)[2][4], f32x4 (&acc2)[2][4]){
  #pragma unroll
  for (int ks=0; ks<4; ++ks){
    bf16x8 a[2], b1[4], b2[4];
    #pragma unroll
    for (int mt=0; mt<2; ++mt)
      a[mt] = ldsA(xs, wm*32 + mt*16 + (l&15), ks*4 + (l>>4));
    #pragma unroll
    for (int nt=0; nt<4; ++nt){
      b1[nt] = *(const bf16x8*)&wf1[(((wn*4+nt)*4 + ks)*64 + l)*8];
      b2[nt] = *(const bf16x8*)&wf2[(((wn*4+nt)*4 + ks)*64 + l)*8];
    }
    #pragma unroll
    for (int mt=0; mt<2; ++mt)
      #pragma unroll
      for (int nt=0; nt<4; ++nt){
        acc1[mt][nt] = __builtin_amdgcn_mfma_f32_16x16x32_bf16(a[mt], b1[nt], acc1[mt][nt], 0,0,0);
        acc2[mt][nt] = __builtin_amdgcn_mfma_f32_16x16x32_bf16(a[mt], b2[nt], acc2[mt][nt], 0,0,0);
      }
  }
}

#define ZERO_ACC(A) { _Pragma("unroll") for(int _a=0;_a<2;_a++) _Pragma("unroll") for(int _b=0;_b<4;_b++) A[_a][_b]=(f32x4){0,0,0,0}; }

#define GEMM_PROLOG8 \
  int tid = threadIdx.x; int r0 = blockIdx.x*128; \
  int wid = tid>>6, l = tid&63; int wm = wid>>1, wn = wid&1; (void)r0;

#define EPI8 \
  int row = wm*32 + mt*16 + ((l>>4)<<2) + reg; \
  int col = wn*64 + nt*16 + (l&15);

#define FOR_EPI for (int mt=0;mt<2;++mt) for (int nt=0;nt<4;++nt) for (int reg=0;reg<4;++reg)

// ---------- fused dual dual-gate: out1 = sig(X@Wag+bag)*(X@Wap+bap); out2 likewise ----------
__global__ void __launch_bounds__(512) k_quad_gate(const short* __restrict__ X,
                                                   const short* __restrict__ Wagf, const float* __restrict__ bag,
                                                   const short* __restrict__ Wapf, const float* __restrict__ bap,
                                                   const short* __restrict__ Wbgf, const float* __restrict__ bbg,
                                                   const short* __restrict__ Wbpf, const float* __restrict__ bbp,
                                                   short* __restrict__ out1, short* __restrict__ out2){
  __shared__ short xs[128*128];
  GEMM_PROLOG8
  stage128_8(X, xs, r0, tid);
  __syncthreads();
  {
    f32x4 ag[2][4], ap[2][4];
    ZERO_ACC(ag) ZERO_ACC(ap)
    gemm_core28(xs, Wagf, Wapf, wm, wn, l, ag, ap);
    FOR_EPI{
      EPI8
      float v = (ap[mt][nt][reg] + bap[col]) * sigmoidf_(ag[mt][nt][reg] + bag[col]);
      out1[(size_t)(r0+row)*128 + col] = f2b(v);
    }
  }
  {
    f32x4 bg2[2][4], bp2[2][4];
    ZERO_ACC(bg2) ZERO_ACC(bp2)
    gemm_core28(xs, Wbgf, Wbpf, wm, wn, l, bg2, bp2);
    FOR_EPI{
      EPI8
      float v = (bp2[mt][nt][reg] + bbp[col]) * sigmoidf_(bg2[mt][nt][reg] + bbg[col]);
      out2[(size_t)(r0+row)*128 + col] = f2b(v);
    }
  }
}

// ---------- fused QKV: Q=(X@Wq)*s -> out_q; K=X@Wk -> out_k; V=X@Wv -> transposed Vt ----------
__global__ void __launch_bounds__(512) k_qkv(const short* __restrict__ X,
                                             const short* __restrict__ Wqf, float sq,
                                             const short* __restrict__ Wkf,
                                             const short* __restrict__ Wvf,
                                             short* __restrict__ out_q, short* __restrict__ out_k,
                                             short* __restrict__ Vt){
  __shared__ short xs[128*128];
  GEMM_PROLOG8
  stage128_8(X, xs, r0, tid);
  __syncthreads();
  {
    f32x4 aq[2][4], ak[2][4];
    ZERO_ACC(aq) ZERO_ACC(ak)
    gemm_core28(xs, Wqf, Wkf, wm, wn, l, aq, ak);
    FOR_EPI{
      EPI8
      out_q[(size_t)(r0+row)*128 + col] = f2b(aq[mt][nt][reg]*sq);
      out_k[(size_t)(r0+row)*128 + col] = f2b(ak[mt][nt][reg]);
    }
  }
  f32x4 av[2][4];
  ZERO_ACC(av)
  gemm_core8(xs, Wvf, wm, wn, l, av);
  __syncthreads();   // everyone done reading xs
  // write V transposed into xs as [c][r] with chunk-XOR on r
  #pragma unroll
  for (int mt=0;mt<2;++mt)
    #pragma unroll
    for (int nt=0;nt<4;++nt){
      int rb  = wm*32 + mt*16 + ((l>>4)<<2);
      int col = wn*64 + nt*16 + (l&15);
      short4 s4 = { f2b(av[mt][nt][0]), f2b(av[mt][nt][1]), f2b(av[mt][nt][2]), f2b(av[mt][nt][3]) };
      *(short4*)&xs[col*128 + (((rb>>3) ^ (col&15))<<3) + (rb&7)] = s4;
    }
  __syncthreads();
  int i = r0>>8, j0 = r0&255;
  #pragma unroll
  for (int m=0;m<4;++m){
    int d = m*512 + tid;
    int c = d>>4, ch = d&15;
    int4 val = *(const int4*)&xs[c*128 + ((ch ^ (c&15))<<3)];
    *(int4*)&Vt[(size_t)((i*4 + (c>>5))*32 + (c&31))*256 + j0 + ch*8] = val;
  }
}

// ---------- fused LN(T)+tri_finish: zout = zin + (LN_c(T)@Wz+bz)*sig(X@Wg+bg) ----------
__global__ void __launch_bounds__(512) k_tri_finish(const short* __restrict__ Tb,  // bf16 [c][r]
                                                    const short* __restrict__ X,
                                                    const short* __restrict__ Wzf, const float* __restrict__ bz,
                                                    const short* __restrict__ Wgf, const float* __restrict__ bg,
                                                    const float* __restrict__ lnw, const float* __restrict__ lnb,
                                                    const float* __restrict__ zin, float* __restrict__ zout){
  __shared__ short tt[128*128];   // staged [c][rl], later overwritten as LN'd A-tile [rl][c]
  __shared__ short xs[128*128];
  __shared__ float ps[512], pq[512];
  __shared__ float mu[128], iv[128];
  GEMM_PROLOG8
  stage128_8(X, xs, r0, tid);
  #pragma unroll
  for (int m=0;m<4;++m){
    int d = m*512 + tid;
    int c = d>>4, ch = d&15;
    glds16(&Tb[(size_t)c*65536 + r0 + ch*8], tt + (size_t)(d & ~63)*8);
  }
  __syncthreads();
  // LN over c for each local row rl; thread owns (rl = tid&127, c-range cq*32..+32)
  int rl = tid & 127, cq = tid >> 7;
  float vals[32]; float s = 0.f, q = 0.f;
  #pragma unroll
  for (int cc=0; cc<32; ++cc){
    float v = b2f(tt[(cq*32+cc)*128 + rl]);
    vals[cc] = v; s += v; q += v*v;
  }
  ps[cq*128 + rl] = s; pq[cq*128 + rl] = q;
  __syncthreads();               // also guarantees all tt reads done
  if (tid < 128){
    float ss = ps[tid]+ps[128+tid]+ps[256+tid]+ps[384+tid];
    float qq = pq[tid]+pq[128+tid]+pq[256+tid]+pq[384+tid];
    float m = ss * (1.f/128.f);
    float var = qq * (1.f/128.f) - m*m;
    mu[tid] = m; iv[tid] = rsqrtf(var + 1e-5f);
  }
  __syncthreads();
  {
    float m = mu[rl], r = iv[rl];
    #pragma unroll
    for (int chq=0; chq<4; ++chq){
      short tmp[8];
      #pragma unroll
      for (int e=0;e<8;++e){
        int cc = chq*8 + e;
        int c = cq*32 + cc;
        tmp[e] = f2b((vals[cc]-m)*r*lnw[c] + lnb[c]);
      }
      int ch = cq*4 + chq;
      *(int4*)&tt[rl*128 + ((ch ^ (rl&15))<<3)] = *(int4*)tmp;
    }
  }
  __syncthreads();
  f32x4 az[2][4], ag[2][4];
  ZERO_ACC(az) ZERO_ACC(ag)
  gemm_core8(tt, Wzf, wm, wn, l, az);
  gemm_core8(xs, Wgf, wm, wn, l, ag);
  FOR_EPI{
    EPI8
    size_t idx = (size_t)(r0+row)*128 + col;
    float v = (az[mt][nt][reg] + bz[col]) * sigmoidf_(ag[mt][nt][reg] + bg[col]);
    zout[idx] = zin[idx] + v;
  }
}

// ---------- z(±T) += ((O*sigmoid(X@Wg+bg)) @ Wo + bo) ----------
template<bool TRANS>
__global__ void __launch_bounds__(512) k_attn_out(const short* __restrict__ O,
                                                  const short* __restrict__ X,
                                                  const short* __restrict__ Wgf, const float* __restrict__ bg,
                                                  const short* __restrict__ Wof, const float* __restrict__ bo,
                                                  float* __restrict__ z){
  __shared__ short xs[128*128];
  __shared__ short os[128*128];
  GEMM_PROLOG8
  stage128_8(X, xs, r0, tid);
  #pragma unroll
  for (int m=0;m<4;++m){
    int d = m*512 + tid;
    int row = d>>4, ch = d&15;
    glds16(&O[(size_t)(r0+row)*128 + ch*8], os + (size_t)(d & ~63)*8);
  }
  __syncthreads();
  f32x4 ag[2][4];
  ZERO_ACC(ag)
  gemm_core8(xs, Wgf, wm, wn, l, ag);
  __syncthreads();
  FOR_EPI{
    EPI8
    float ov = b2f(os[row*128 + col]);
    float v = ov * sigmoidf_(ag[mt][nt][reg] + bg[col]);
    xs[row*128 + (((col>>3) ^ (row&15))<<3) + (col&7)] = f2b(v);
  }
  __syncthreads();
  f32x4 a2[2][4];
  ZERO_ACC(a2)
  gemm_core8(xs, Wof, wm, wn, l, a2);
  FOR_EPI{
    EPI8
    int orow = r0+row;
    int zrow = TRANS ? (((orow&255)<<8) | (orow>>8)) : orow;
    z[(size_t)zrow*128 + col] += a2[mt][nt][reg] + bo[col];
  }
}

// ---------- pair transition: z += relu(X@W1+b1)@W2 + b2 ----------
__global__ void __launch_bounds__(512) k_pt(const short* __restrict__ X,
                                            const short* __restrict__ W1f, const float* __restrict__ b1,
                                            const short* __restrict__ W2f, const float* __restrict__ b2,
                                            float* __restrict__ z){
  __shared__ short xs[128*128];
  __shared__ short hs[128*128];
  GEMM_PROLOG8
  stage128_8(X, xs, r0, tid);
  __syncthreads();
  f32x4 a2[2][4];
  ZERO_ACC(a2)
  for (int m=0;m<4;++m){
    f32x4 a1[2][4];
    ZERO_ACC(a1)
    gemm_core8(xs, W1f + m*16384, wm, wn, l, a1);
    FOR_EPI{
      EPI8
      float v = fmaxf(a1[mt][nt][reg] + b1[m*128 + col], 0.f);
      hs[row*128 + (((col>>3) ^ (row&15))<<3) + (col&7)] = f2b(v);
    }
    __syncthreads();
    gemm_core8(hs, W2f + m*16384, wm, wn, l, a2);
    __syncthreads();
  }
  FOR_EPI{
    EPI8
    z[(size_t)(r0+row)*128 + col] += a2[mt][nt][reg] + b2[col];
  }
}

// ---------- pack: bf16 [r][c] -> per-channel bf16 [c][x][y]; r = TR ? y*256+x : x*256+y ----------
template<bool TR>
__global__ void __launch_bounds__(256) pack_cxy(const short* __restrict__ inA, const short* __restrict__ inB,
                                                short* __restrict__ outA, short* __restrict__ outB){
  __shared__ short tile[256*144];
  const short* in = blockIdx.y ? inB : inA;
  short* out      = blockIdx.y ? outB : outA;
  int x = blockIdx.x, tid = threadIdx.x;
  #pragma unroll
  for (int m=0;m<16;++m){
    int idx = m*256 + tid;
    int y = idx>>4, c0 = (idx&15)*8;
    int r = TR ? (y*256 + x) : (x*256 + y);
    *(int4*)&tile[y*144 + c0] = *(const int4*)&in[(size_t)r*128 + c0];
  }
  __syncthreads();
  int c = tid & 127, yh = tid >> 7;
  short* ob = out + (size_t)c*65536 + x*256 + yh*128;
  #pragma unroll
  for (int yc=0; yc<16; ++yc){
    short tmp[8];
    #pragma unroll
    for (int e=0;e<8;e++) tmp[e] = tile[(yh*128 + yc*8 + e)*144 + c];
    *(int4*)&ob[yc*8] = *(int4*)tmp;
  }
}

// ---------- triangle einsum: T[c][i][j] = sum_k A[c][i][k]*B[c][j][k]  (bf16 out) ----------
__global__ void __launch_bounds__(512) k_einsum(const short* __restrict__ Ab,
                                                const short* __restrict__ Bb,
                                                short* __restrict__ Tb){
  __shared__ short as[128*64];
  __shared__ short bs[128*64];
  int c = blockIdx.z;
  int i0 = blockIdx.x*128, j0 = blockIdx.y*128;
  const short* A = Ab + (size_t)c*65536;
  const short* B = Bb + (size_t)c*65536;
  int tid = threadIdx.x;
  int wid = tid>>6, l = tid&63; int wm = wid>>1, wn = wid&1;
  f32x4 acc[2][4];
  ZERO_ACC(acc)
  for (int kt=0; kt<4; ++kt){
    __syncthreads();
    #pragma unroll
    for (int m=0;m<2;++m){
      int d = m*512 + tid;
      int row = d>>3, cw = d&7;
      glds16(&A[(size_t)(i0+row)*256 + kt*64 + ((cw ^ (row&7))<<3)], as + (size_t)(d & ~63)*8);
      glds16(&B[(size_t)(j0+row)*256 + kt*64 + ((cw ^ (row&7))<<3)], bs + (size_t)(d & ~63)*8);
    }
    __syncthreads();
    #pragma unroll
    for (int ks=0; ks<2; ++ks){
      bf16x8 a[2], b[4];
      #pragma unroll
      for (int mt=0; mt<2; ++mt){
        int row = wm*32 + mt*16 + (l&15);
        int ch  = (ks*4 + (l>>4)) ^ (row&7);
        a[mt] = *(const bf16x8*)&as[row*64 + ch*8];
      }
      #pragma unroll
      for (int nt=0; nt<4; ++nt){
        int row = wn*64 + nt*16 + (l&15);
        int ch  = (ks*4 + (l>>4)) ^ (row&7);
        b[nt] = *(const bf16x8*)&bs[row*64 + ch*8];
      }
      #pragma unroll
      for (int mt=0; mt<2; ++mt)
        #pragma unroll
        for (int nt=0; nt<4; ++nt)
          acc[mt][nt] = __builtin_amdgcn_mfma_f32_16x16x32_bf16(a[mt], b[nt], acc[mt][nt], 0,0,0);
    }
  }
  short* To = Tb + (size_t)c*65536;
  FOR_EPI{
    int row = wm*32 + mt*16 + ((l>>4)<<2) + reg;
    int col = wn*64 + nt*16 + (l&15);
    To[(size_t)(i0+row)*256 + j0+col] = f2b(acc[mt][nt][reg]);
  }
}

// ---------- bias in PERMUTED C-fragment order matching Gperm ----------
__global__ void __launch_bounds__(256) bias_gemm(const short* __restrict__ X,
                                                 const float* __restrict__ bw,
                                                 float* __restrict__ BSF){
  __shared__ float xs[64][129];
  int r0 = blockIdx.x*64;
  for(int idx=threadIdx.x; idx<64*128; idx+=256)
    xs[idx>>7][idx&127] = b2f(X[(size_t)(r0+(idx>>7))*CZ + (idx&127)]);
  __syncthreads();
  int h = threadIdx.x>>6, r = threadIdx.x&63;
  float acc=0.f;
  #pragma unroll 4
  for(int k=0;k<CZ;k++) acc += xs[r][k]*bw[k*H_+h];
  int rr2 = r0 + r;
  int q = rr2 >> 8, j = rr2 & 255;
  int t = ((j>>5)<<1) + ((j>>2)&1);
  int m = (((j>>3)&3)<<2) + (j&3);
  int idx = (((h*16 + (q>>4))*16 + t) << 8) + (((m>>2)*16 + (q&15)) << 2) + (m&3);
  BSF[idx] = acc;
}

// ---------- bf16 MFMA flash attention, Gperm-K, reg-Q, transposed-V, no P LDS ----------
__global__ void __launch_bounds__(256, 3) attn_mfma(const short* __restrict__ Qg,
                                                    const short* __restrict__ Kg,
                                                    const short* __restrict__ Vt,
                                                    const float* __restrict__ BSF,
                                                    short* __restrict__ O){
  __shared__ short Kf[8192];
  __shared__ short Vf[8192];
  int i = blockIdx.x, h = blockIdx.y;
  int tid = threadIdx.x;
  #pragma unroll
  for (int m=0;m<4;++m){
    int d = m*256 + tid;
    int t = d>>6, ll = d&63;
    glds16(&Kg[(size_t)(i*N_ + Gperm(t, ll&15))*CH + h*CA + ((ll>>4)<<3)],
           Kf + (size_t)(d & ~63)*8);
    glds16(&Vt[(size_t)(((i*H_ + h)*CA) + ((t>>3)<<4) + (ll&15))*N_ + ((t&7)<<5) + ((ll>>4)<<3)],
           Vf + (size_t)(d & ~63)*8);
  }
  __syncthreads();

  int wid = tid >> 6, l = tid & 63;
  int lg = l >> 4, ln = l & 15;

  for (int ss=0; ss<4; ++ss){
    int sub = wid*4 + ss;
    bf16x8 qfrag = *(const bf16x8*)&Qg[(size_t)(i*N_ + sub*16 + ln)*CH + h*CA + (lg<<3)];
    const float* bb = BSF + (size_t)(h*16 + sub)*4096 + (l<<2);
    f32x4 acc[16];
    #pragma unroll
    for (int t=0;t<16;t++) acc[t] = *(const f32x4*)&bb[t<<8];
    #pragma unroll
    for (int t=0;t<16;t++){
      bf16x8 kf = *(const bf16x8*)&Kf[t*512 + l*8];
      acc[t] = __builtin_amdgcn_mfma_f32_16x16x32_bf16(kf, qfrag, acc[t], 0,0,0);
    }
    float mx = -1e30f;
    #pragma unroll
    for (int t=0;t<16;t++)
      mx = fmaxf(mx, fmaxf(fmaxf(acc[t][0],acc[t][1]), fmaxf(acc[t][2],acc[t][3])));
    mx = fmaxf(mx, __shfl_xor(mx,16,64));
    mx = fmaxf(mx, __shfl_xor(mx,32,64));
    float sum = 0.f;
    #pragma unroll
    for (int t=0;t<16;t++){
      #pragma unroll
      for (int r=0;r<4;r++){ float p = __expf(acc[t][r]-mx); acc[t][r]=p; sum += p; }
    }
    sum += __shfl_xor(sum,16,64);
    sum += __shfl_xor(sum,32,64);
    float iv = 1.0f / sum;
    bf16x8 pf[8];
    #pragma unroll
    for (int jt=0;jt<8;jt++){
      int4 w4;
      w4.x = pk_bf16(acc[2*jt  ][0], acc[2*jt  ][1]);
      w4.y = pk_bf16(acc[2*jt  ][2], acc[2*jt  ][3]);
      w4.z = pk_bf16(acc[2*jt+1][0], acc[2*jt+1][1]);
      w4.w = pk_bf16(acc[2*jt+1][2], acc[2*jt+1][3]);
      pf[jt] = *(bf16x8*)&w4;
    }
    #pragma unroll
    for (int ct=0; ct<2; ++ct){
      f32x4 oe = {0.f,0.f,0.f,0.f}, oo = {0.f,0.f,0.f,0.f};
      #pragma unroll
      for (int jt=0;jt<8;jt+=2){
        bf16x8 ve = *(const bf16x8*)&Vf[((ct*8 + jt  )*64 + l)*8];
        bf16x8 vo = *(const bf16x8*)&Vf[((ct*8 + jt+1)*64 + l)*8];
        oe = __builtin_amdgcn_mfma_f32_16x16x32_bf16(ve, pf[jt  ], oe, 0,0,0);
        oo = __builtin_amdgcn_mfma_f32_16x16x32_bf16(vo, pf[jt+1], oo, 0,0,0);
      }
      int q = sub*16 + ln;
      int c = ct*16 + lg*4;
      short4 ov = { f2b((oe[0]+oo[0])*iv), f2b((oe[1]+oo[1])*iv),
                    f2b((oe[2]+oo[2])*iv), f2b((oe[3]+oo[3])*iv) };
      *(short4*)&O[(size_t)(i*N_ + q)*CH + h*CA + c] = ov;
    }
  }
}

extern "C" void kernel_launch(void* const* d_in, const int* in_sizes, int n_in,
                              void* d_out, int out_size, void* d_ws, size_t ws_size,
                              hipStream_t stream) {
  const float* z_in      = (const float*)d_in[0];
  const float* tm_lnin_w = (const float*)d_in[1];
  const float* tm_lnin_b = (const float*)d_in[2];
  const float* tm_ap_w   = (const float*)d_in[3];
  const float* tm_ap_b   = (const float*)d_in[4];
  const float* tm_ag_w   = (const float*)d_in[5];
  const float* tm_ag_b   = (const float*)d_in[6];
  const float* tm_bp_w   = (const float*)d_in[7];
  const float* tm_bp_b   = (const float*)d_in[8];
  const float* tm_bg_w   = (const float*)d_in[9];
  const float* tm_bg_b   = (const float*)d_in[10];
  const float* tm_g_w    = (const float*)d_in[11];
  const float* tm_g_b    = (const float*)d_in[12];
  const float* tm_zo_w   = (const float*)d_in[13];
  const float* tm_zo_b   = (const float*)d_in[14];
  const float* tm_lno_w  = (const float*)d_in[15];
  const float* tm_lno_b  = (const float*)d_in[16];
  const float* ta_ln_w   = (const float*)d_in[17];
  const float* ta_ln_b   = (const float*)d_in[18];
  const float* ta_q_w    = (const float*)d_in[19];
  const float* ta_k_w    = (const float*)d_in[20];
  const float* ta_v_w    = (const float*)d_in[21];
  const float* ta_b_w    = (const float*)d_in[22];
  const float* ta_g_w    = (const float*)d_in[23];
  const float* ta_g_b    = (const float*)d_in[24];
  const float* ta_o_w    = (const float*)d_in[25];
  const float* ta_o_b    = (const float*)d_in[26];
  const float* pt_ln_w   = (const float*)d_in[27];
  const float* pt_ln_b   = (const float*)d_in[28];
  const float* pt_1_w    = (const float*)d_in[29];
  const float* pt_1_b    = (const float*)d_in[30];
  const float* pt_2_w    = (const float*)d_in[31];
  const float* pt_2_b    = (const float*)d_in[32];

  float* z  = (float*)d_out;
  char* base = (char*)d_ws;
  const size_t MB = 1u<<20;
  short* wf  = (short*)base;                 // 30 x 32KB frag blobs
  short* Xb  = (short*)(base + 1*MB);        // 16MB bf16 [r][c]
  short* R1  = (short*)(base + 17*MB);
  short* R2  = (short*)(base + 33*MB);
  short* R3  = (short*)(base + 49*MB);       // Vt / packed A
  short* R4  = (short*)(base + 65*MB);
  short* Tb  = (short*)(base + 81*MB);       // 16MB bf16 [c][r]
  float* BSF = (float*)(base + 113*MB);      // 1MB

  #define SL(s) (wf + (size_t)(s)*16384)

  prep_weights<<<dim3(8,30), 256, 0, stream>>>(tm_ag_w, tm_ap_w, tm_bg_w, tm_bp_w,
                                               tm_g_w, tm_zo_w,
                                               ta_q_w, ta_k_w, ta_v_w, ta_g_w, ta_o_w,
                                               pt_1_w, pt_2_w, wf);

  // ---- triangle multiplication: outgoing (i=0), incoming (i=1) ----
  for (int i=0;i<2;i++){
    const float* zsrc = (i==0) ? z_in : z;
    ln_x<false><<<NN/4, 256, 0, stream>>>(zsrc, tm_lnin_w+i*CZ, tm_lnin_b+i*CZ, Xb);
    k_quad_gate<<<NN/128, 512, 0, stream>>>(Xb, SL(i*6+0), tm_ag_b+i*CH, SL(i*6+1), tm_ap_b+i*CH,
                                            SL(i*6+2), tm_bg_b+i*CH, SL(i*6+3), tm_bp_b+i*CH,
                                            R1, R2);
    if (i==0) pack_cxy<false><<<dim3(256,2), 256, 0, stream>>>(R1, R2, R3, R4);
    else      pack_cxy<true ><<<dim3(256,2), 256, 0, stream>>>(R1, R2, R3, R4);
    k_einsum<<<dim3(2,2,128), 512, 0, stream>>>(R3, R4, Tb);
    k_tri_finish<<<NN/128, 512, 0, stream>>>(Tb, Xb, SL(i*6+5), tm_zo_b+i*CZ,
                                             SL(i*6+4), tm_g_b+i*CZ,
                                             tm_lno_w+i*CH, tm_lno_b+i*CH, zsrc, z);
  }

  // ---- triangle attention: starting (i=0), ending (i=1, transposed coords) ----
  for (int i=0;i<2;i++){
    if (i==0) ln_x<false><<<NN/4, 256, 0, stream>>>(z, ta_ln_w, ta_ln_b, Xb);
    else      ln_x<true ><<<NN/4, 256, 0, stream>>>(z, ta_ln_w+CZ, ta_ln_b+CZ, Xb);
    k_qkv<<<NN/128, 512, 0, stream>>>(Xb, SL(12+i*5+0), 0.17677669529663687f,
                                      SL(12+i*5+1), SL(12+i*5+2), R1, R2, R3);
    bias_gemm<<<NN/64, 256, 0, stream>>>(Xb, ta_b_w+i*CZ*H_, BSF);
    attn_mfma<<<dim3(N_,H_), 256, 0, stream>>>(R1, R2, R3, BSF, R4);
    if (i==0) k_attn_out<false><<<NN/128, 512, 0, stream>>>(R4, Xb, SL(12+i*5+3), ta_g_b+i*H_*CA,
                                                            SL(12+i*5+4), ta_o_b+i*CZ, z);
    else      k_attn_out<true ><<<NN/128, 512, 0, stream>>>(R4, Xb, SL(12+i*5+3), ta_g_b+i*H_*CA,
                                                            SL(12+i*5+4), ta_o_b+i*CZ, z);
  }

  // ---- pair transition ----
  ln_x<false><<<NN/4, 256, 0, stream>>>(z, pt_ln_w, pt_ln_b, Xb);
  k_pt<<<NN/128, 512, 0, stream>>>(Xb, SL(22), pt_1_b, SL(26), pt_2_b, z);
}

// Round 6
// 584.983 us; speedup vs baseline: 7.1363x; 1.0307x over previous
//
#include <hip/hip_runtime.h>
#include <math.h>

#define N_  256
#define NN  65536
#define CZ  128
#define CH  128
#define H_  4
#define CA  32

typedef __attribute__((ext_vector_type(8))) short bf16x8;
typedef __attribute__((ext_vector_type(4))) float f32x4;

__device__ __forceinline__ float sigmoidf_(float x){ return 1.f/(1.f+__expf(-x)); }

__device__ __forceinline__ short f2b(float f){
  unsigned u = __float_as_uint(f);
  unsigned r = (u + 0x7fffu + ((u>>16)&1u)) >> 16;
  return (short)r;
}
__device__ __forceinline__ float b2f(short s){
  unsigned u = ((unsigned)(unsigned short)s) << 16;
  return __uint_as_float(u);
}
__device__ __forceinline__ unsigned pk_bf16(float lo, float hi){
  unsigned r;
  asm volatile("v_cvt_pk_bf16_f32 %0, %1, %2" : "=v"(r) : "v"(lo), "v"(hi));
  return r;
}

__device__ __forceinline__ void glds16(const void* g, const void* l){
  __builtin_amdgcn_global_load_lds((const __attribute__((address_space(1))) void*)g,
                                   (__attribute__((address_space(3))) void*)l, 16, 0, 0);
}

__device__ __forceinline__ float wave_red_sum(float v){
  #pragma unroll
  for(int o=32;o>0;o>>=1) v += __shfl_xor(v,o,64);
  return v;
}

// K-row permutation: QK tile t, C-row m -> true key index j
__device__ __forceinline__ int Gperm(int t, int m){
  return ((t>>1)<<5) + ((m>>2)<<3) + ((t&1)<<2) + (m&3);
}

// ---------- weight prep: fp32 [K][N] slices -> bf16 B-fragment-packed blobs ----------
__global__ void __launch_bounds__(256) prep_weights(
    const float* tm_ag, const float* tm_ap, const float* tm_bg, const float* tm_bp,
    const float* tm_g, const float* tm_zo,
    const float* ta_q, const float* ta_k, const float* ta_v, const float* ta_g, const float* ta_o,
    const float* pt1, const float* pt2, short* Wf){
  int tid = threadIdx.x;
  int g = blockIdx.x*4 + (tid>>6);
  int l = tid & 63;
  int s = blockIdx.y;
  const float* src; int ldn = 128, koff = 0, noff = 0;
  if (s < 12){
    int i = s/6, w = s - i*6;
    switch(w){ case 0: src=tm_ag; break; case 1: src=tm_ap; break; case 2: src=tm_bg; break;
               case 3: src=tm_bp; break; case 4: src=tm_g;  break; default: src=tm_zo; }
    src += i*16384;
  } else if (s < 22){
    int t2 = s-12; int i = t2/5, w = t2 - i*5;
    switch(w){ case 0: src=ta_q; break; case 1: src=ta_k; break; case 2: src=ta_v; break;
               case 3: src=ta_g; break; default: src=ta_o; }
    src += i*16384;
  } else if (s < 26){
    src = pt1; ldn = 512; noff = (s-22)*128;
  } else {
    src = pt2; koff = (s-26)*128;
  }
  int nt = g>>2, ks = g&3;
  int n = noff + nt*16 + (l&15);
  int kb = koff + ks*32 + (l>>4)*8;
  short tmp[8];
  #pragma unroll
  for (int e=0;e<8;e++) tmp[e] = f2b(src[(size_t)(kb+e)*ldn + n]);
  short* dst = Wf + s*16384 + ((nt*4+ks)*64 + l)*8;
  *(short4*)dst     = *(short4*)&tmp[0];
  *(short4*)(dst+4) = *(short4*)&tmp[4];
}

// ---------- LayerNorm: fp32 in -> bf16 out; TRANS reads transposed grid ----------
template<bool TRANS>
__global__ void __launch_bounds__(256) ln_x(const float* __restrict__ in,
                                            const float* __restrict__ w,
                                            const float* __restrict__ b,
                                            short* __restrict__ out){
  int wid  = threadIdx.x >> 6;
  int lane = threadIdx.x & 63;
  int row  = blockIdx.x*4 + wid;
  int irow;
  if (TRANS){ int i = row >> 8, j = row & 255; irow = (j<<8) | i; } else irow = row;
  float v0 = in[(size_t)irow*CZ + lane];
  float v1 = in[(size_t)irow*CZ + lane + 64];
  float m  = wave_red_sum(v0+v1) * (1.f/128.f);
  float d0 = v0-m, d1 = v1-m;
  float var = wave_red_sum(d0*d0 + d1*d1) * (1.f/128.f);
  float r = rsqrtf(var + 1e-5f);
  out[(size_t)row*CZ + lane]      = f2b(d0*r*w[lane]    + b[lane]);
  out[(size_t)row*CZ + lane + 64] = f2b(d1*r*w[lane+64] + b[lane+64]);
}

// ---------- 8-wave GEMM helpers (512 threads, 128x128 tile) ----------
__device__ __forceinline__ void stage128_8(const short* __restrict__ g, short* xs, int r0, int tid){
  #pragma unroll
  for (int m=0;m<4;++m){
    int d = m*512 + tid;
    int row = d>>4, cw = d&15;
    glds16(&g[(size_t)(r0+row)*128 + ((cw ^ (row&15))<<3)], xs + (size_t)(d & ~63)*8);
  }
}

__device__ __forceinline__ bf16x8 ldsA(const short* xs, int row, int ch){
  return *(const bf16x8*)&xs[row*128 + ((ch ^ (row&15))<<3)];
}

// core with half-K B-batch preload: per half, 8 b-frag loads issued as a batch,
// then MFMAs; L2 latency paid once per group, covered by previous group's MFMAs.
__device__ __forceinline__ void gemm_coreP(const short* xs, const short* __restrict__ wf,
                                           int wm, int wn, int l, f32x4 (&acc)[2][4]){
  #pragma unroll
  for (int kh=0; kh<2; ++kh){
    bf16x8 b[2][4];
    #pragma unroll
    for (int ks2=0; ks2<2; ++ks2)
      #pragma unroll
      for (int nt=0; nt<4; ++nt)
        b[ks2][nt] = *(const bf16x8*)&wf[(((wn*4+nt)*4 + kh*2+ks2)*64 + l)*8];
    #pragma unroll
    for (int ks2=0; ks2<2; ++ks2){
      bf16x8 a[2];
      #pragma unroll
      for (int mt=0; mt<2; ++mt)
        a[mt] = ldsA(xs, wm*32 + mt*16 + (l&15), (kh*2+ks2)*4 + (l>>4));
      #pragma unroll
      for (int mt=0; mt<2; ++mt)
        #pragma unroll
        for (int nt=0; nt<4; ++nt)
          acc[mt][nt] = __builtin_amdgcn_mfma_f32_16x16x32_bf16(a[mt], b[ks2][nt], acc[mt][nt], 0,0,0);
    }
  }
}

#define ZERO_ACC(A) { _Pragma("unroll") for(int _a=0;_a<2;_a++) _Pragma("unroll") for(int _b=0;_b<4;_b++) A[_a][_b]=(f32x4){0,0,0,0}; }

#define GEMM_PROLOG8 \
  int tid = threadIdx.x; int r0 = blockIdx.x*128; \
  int wid = tid>>6, l = tid&63; int wm = wid>>1, wn = wid&1; (void)r0;

#define EPI8 \
  int row = wm*32 + mt*16 + ((l>>4)<<2) + reg; \
  int col = wn*64 + nt*16 + (l&15);

#define FOR_EPI for (int mt=0;mt<2;++mt) for (int nt=0;nt<4;++nt) for (int reg=0;reg<4;++reg)

// ---------- fused dual dual-gate ----------
__global__ void __launch_bounds__(512,4) k_quad_gate(const short* __restrict__ X,
                                                     const short* __restrict__ Wagf, const float* __restrict__ bag,
                                                     const short* __restrict__ Wapf, const float* __restrict__ bap,
                                                     const short* __restrict__ Wbgf, const float* __restrict__ bbg,
                                                     const short* __restrict__ Wbpf, const float* __restrict__ bbp,
                                                     short* __restrict__ out1, short* __restrict__ out2){
  __shared__ short xs[128*128];
  GEMM_PROLOG8
  stage128_8(X, xs, r0, tid);
  __syncthreads();
  {
    f32x4 ag[2][4], ap[2][4];
    ZERO_ACC(ag) ZERO_ACC(ap)
    gemm_coreP(xs, Wagf, wm, wn, l, ag);
    gemm_coreP(xs, Wapf, wm, wn, l, ap);
    FOR_EPI{
      EPI8
      float v = (ap[mt][nt][reg] + bap[col]) * sigmoidf_(ag[mt][nt][reg] + bag[col]);
      out1[(size_t)(r0+row)*128 + col] = f2b(v);
    }
  }
  {
    f32x4 bg2[2][4], bp2[2][4];
    ZERO_ACC(bg2) ZERO_ACC(bp2)
    gemm_coreP(xs, Wbgf, wm, wn, l, bg2);
    gemm_coreP(xs, Wbpf, wm, wn, l, bp2);
    FOR_EPI{
      EPI8
      float v = (bp2[mt][nt][reg] + bbp[col]) * sigmoidf_(bg2[mt][nt][reg] + bbg[col]);
      out2[(size_t)(r0+row)*128 + col] = f2b(v);
    }
  }
}

// ---------- fused QKV+bias: Q,K plain; V transposed; bias in permuted C-frag order ----------
__global__ void __launch_bounds__(512,4) k_qkv(const short* __restrict__ X,
                                               const short* __restrict__ Wqf, float sq,
                                               const short* __restrict__ Wkf,
                                               const short* __restrict__ Wvf,
                                               const float* __restrict__ bw,
                                               short* __restrict__ out_q, short* __restrict__ out_k,
                                               short* __restrict__ Vt, float* __restrict__ BSF){
  __shared__ short xs[128*128];
  GEMM_PROLOG8
  stage128_8(X, xs, r0, tid);
  __syncthreads();
  {
    f32x4 aq[2][4], ak[2][4];
    ZERO_ACC(aq) ZERO_ACC(ak)
    gemm_coreP(xs, Wqf, wm, wn, l, aq);
    gemm_coreP(xs, Wkf, wm, wn, l, ak);
    FOR_EPI{
      EPI8
      out_q[(size_t)(r0+row)*128 + col] = f2b(aq[mt][nt][reg]*sq);
      out_k[(size_t)(r0+row)*128 + col] = f2b(ak[mt][nt][reg]);
    }
  }
  f32x4 av[2][4];
  ZERO_ACC(av)
  gemm_coreP(xs, Wvf, wm, wn, l, av);
  // bias epilogue: thread (rl = tid&127, h = tid>>7) computes X[rl,:]@bw[:,h]
  {
    int rl = tid & 127, hh = tid >> 7;
    float bacc = 0.f;
    #pragma unroll
    for (int ch=0; ch<16; ++ch){
      bf16x8 v = ldsA(xs, rl, ch);
      #pragma unroll
      for (int e=0;e<8;++e) bacc += b2f(v[e]) * bw[(ch*8+e)*H_ + hh];
    }
    int r = r0 + rl;
    int qq = r >> 8, j = r & 255;
    int t = ((j>>5)<<1) + ((j>>2)&1);
    int mm = (((j>>3)&3)<<2) + (j&3);
    int idx = (((hh*16 + (qq>>4))*16 + t) << 8) + (((mm>>2)*16 + (qq&15)) << 2) + (mm&3);
    BSF[idx] = bacc;
  }
  __syncthreads();   // everyone done reading xs
  // write V transposed into xs as [c][r] with chunk-XOR on r
  #pragma unroll
  for (int mt=0;mt<2;++mt)
    #pragma unroll
    for (int nt=0;nt<4;++nt){
      int rb  = wm*32 + mt*16 + ((l>>4)<<2);
      int col = wn*64 + nt*16 + (l&15);
      short4 s4 = { f2b(av[mt][nt][0]), f2b(av[mt][nt][1]), f2b(av[mt][nt][2]), f2b(av[mt][nt][3]) };
      *(short4*)&xs[col*128 + (((rb>>3) ^ (col&15))<<3) + (rb&7)] = s4;
    }
  __syncthreads();
  int i = r0>>8, j0 = r0&255;
  #pragma unroll
  for (int m=0;m<4;++m){
    int d = m*512 + tid;
    int c = d>>4, ch = d&15;
    int4 val = *(const int4*)&xs[c*128 + ((ch ^ (c&15))<<3)];
    *(int4*)&Vt[(size_t)((i*4 + (c>>5))*32 + (c&31))*256 + j0 + ch*8] = val;
  }
}

// ---------- fused LN(T)+tri_finish ----------
__global__ void __launch_bounds__(512,4) k_tri_finish(const short* __restrict__ Tb,  // bf16 [c][r]
                                                      const short* __restrict__ X,
                                                      const short* __restrict__ Wzf, const float* __restrict__ bz,
                                                      const short* __restrict__ Wgf, const float* __restrict__ bg,
                                                      const float* __restrict__ lnw, const float* __restrict__ lnb,
                                                      const float* __restrict__ zin, float* __restrict__ zout){
  __shared__ short tt[128*128];
  __shared__ short xs[128*128];
  __shared__ float ps[512], pq[512];
  __shared__ float mu[128], iv[128];
  GEMM_PROLOG8
  stage128_8(X, xs, r0, tid);
  #pragma unroll
  for (int m=0;m<4;++m){
    int d = m*512 + tid;
    int c = d>>4, ch = d&15;
    glds16(&Tb[(size_t)c*65536 + r0 + ch*8], tt + (size_t)(d & ~63)*8);
  }
  __syncthreads();
  int rl = tid & 127, cq = tid >> 7;
  float vals[32]; float s = 0.f, q = 0.f;
  #pragma unroll
  for (int cc=0; cc<32; ++cc){
    float v = b2f(tt[(cq*32+cc)*128 + rl]);
    vals[cc] = v; s += v; q += v*v;
  }
  ps[cq*128 + rl] = s; pq[cq*128 + rl] = q;
  __syncthreads();
  if (tid < 128){
    float ss = ps[tid]+ps[128+tid]+ps[256+tid]+ps[384+tid];
    float qq = pq[tid]+pq[128+tid]+pq[256+tid]+pq[384+tid];
    float m = ss * (1.f/128.f);
    float var = qq * (1.f/128.f) - m*m;
    mu[tid] = m; iv[tid] = rsqrtf(var + 1e-5f);
  }
  __syncthreads();
  {
    float m = mu[rl], r = iv[rl];
    #pragma unroll
    for (int chq=0; chq<4; ++chq){
      short tmp[8];
      #pragma unroll
      for (int e=0;e<8;++e){
        int cc = chq*8 + e;
        int c = cq*32 + cc;
        tmp[e] = f2b((vals[cc]-m)*r*lnw[c] + lnb[c]);
      }
      int ch = cq*4 + chq;
      *(int4*)&tt[rl*128 + ((ch ^ (rl&15))<<3)] = *(int4*)tmp;
    }
  }
  __syncthreads();
  f32x4 az[2][4], ag[2][4];
  ZERO_ACC(az) ZERO_ACC(ag)
  gemm_coreP(tt, Wzf, wm, wn, l, az);
  gemm_coreP(xs, Wgf, wm, wn, l, ag);
  FOR_EPI{
    EPI8
    size_t idx = (size_t)(r0+row)*128 + col;
    float v = (az[mt][nt][reg] + bz[col]) * sigmoidf_(ag[mt][nt][reg] + bg[col]);
    zout[idx] = zin[idx] + v;
  }
}

// ---------- z(±T) += ((O*sigmoid(X@Wg+bg)) @ Wo + bo) ----------
template<bool TRANS>
__global__ void __launch_bounds__(512,4) k_attn_out(const short* __restrict__ O,
                                                    const short* __restrict__ X,
                                                    const short* __restrict__ Wgf, const float* __restrict__ bg,
                                                    const short* __restrict__ Wof, const float* __restrict__ bo,
                                                    float* __restrict__ z){
  __shared__ short xs[128*128];
  __shared__ short os[128*128];
  GEMM_PROLOG8
  stage128_8(X, xs, r0, tid);
  #pragma unroll
  for (int m=0;m<4;++m){
    int d = m*512 + tid;
    int row = d>>4, ch = d&15;
    glds16(&O[(size_t)(r0+row)*128 + ch*8], os + (size_t)(d & ~63)*8);
  }
  __syncthreads();
  f32x4 ag[2][4];
  ZERO_ACC(ag)
  gemm_coreP(xs, Wgf, wm, wn, l, ag);
  __syncthreads();
  FOR_EPI{
    EPI8
    float ov = b2f(os[row*128 + col]);
    float v = ov * sigmoidf_(ag[mt][nt][reg] + bg[col]);
    xs[row*128 + (((col>>3) ^ (row&15))<<3) + (col&7)] = f2b(v);
  }
  __syncthreads();
  f32x4 a2[2][4];
  ZERO_ACC(a2)
  gemm_coreP(xs, Wof, wm, wn, l, a2);
  FOR_EPI{
    EPI8
    int orow = r0+row;
    int zrow = TRANS ? (((orow&255)<<8) | (orow>>8)) : orow;
    z[(size_t)zrow*128 + col] += a2[mt][nt][reg] + bo[col];
  }
}

// ---------- pair transition with fused LN: z += relu(LN(z)@W1+b1)@W2 + b2 ----------
__global__ void __launch_bounds__(512,4) k_pt(const float* __restrict__ lnw, const float* __restrict__ lnb,
                                              const short* __restrict__ W1f, const float* __restrict__ b1,
                                              const short* __restrict__ W2f, const float* __restrict__ b2,
                                              float* __restrict__ z){
  __shared__ short xs[128*128];
  __shared__ short hs[128*128];
  __shared__ float ps[512], pq[512];
  __shared__ float mu[128], iv[128];
  GEMM_PROLOG8
  // LN from z directly: thread owns (rl, c-quarter)
  int rl = tid & 127, cq = tid >> 7;
  float vals[32]; float s = 0.f, q = 0.f;
  {
    const float* zr = &z[(size_t)(r0+rl)*128 + cq*32];
    #pragma unroll
    for (int cc=0; cc<32; cc+=4){
      float4 v4 = *(const float4*)&zr[cc];
      vals[cc]=v4.x; vals[cc+1]=v4.y; vals[cc+2]=v4.z; vals[cc+3]=v4.w;
      s += v4.x+v4.y+v4.z+v4.w;
      q += v4.x*v4.x + v4.y*v4.y + v4.z*v4.z + v4.w*v4.w;
    }
  }
  ps[cq*128 + rl] = s; pq[cq*128 + rl] = q;
  __syncthreads();
  if (tid < 128){
    float ss = ps[tid]+ps[128+tid]+ps[256+tid]+ps[384+tid];
    float qq = pq[tid]+pq[128+tid]+pq[256+tid]+pq[384+tid];
    float m = ss * (1.f/128.f);
    float var = qq * (1.f/128.f) - m*m;
    mu[tid] = m; iv[tid] = rsqrtf(var + 1e-5f);
  }
  __syncthreads();
  {
    float m = mu[rl], r = iv[rl];
    #pragma unroll
    for (int chq=0; chq<4; ++chq){
      short tmp[8];
      #pragma unroll
      for (int e=0;e<8;++e){
        int cc = chq*8 + e;
        int c = cq*32 + cc;
        tmp[e] = f2b((vals[cc]-m)*r*lnw[c] + lnb[c]);
      }
      int ch = cq*4 + chq;
      *(int4*)&xs[rl*128 + ((ch ^ (rl&15))<<3)] = *(int4*)tmp;
    }
  }
  __syncthreads();
  f32x4 a2[2][4];
  ZERO_ACC(a2)
  for (int m=0;m<4;++m){
    f32x4 a1[2][4];
    ZERO_ACC(a1)
    gemm_coreP(xs, W1f + m*16384, wm, wn, l, a1);
    FOR_EPI{
      EPI8
      float v = fmaxf(a1[mt][nt][reg] + b1[m*128 + col], 0.f);
      hs[row*128 + (((col>>3) ^ (row&15))<<3) + (col&7)] = f2b(v);
    }
    __syncthreads();
    gemm_coreP(hs, W2f + m*16384, wm, wn, l, a2);
    __syncthreads();
  }
  FOR_EPI{
    EPI8
    z[(size_t)(r0+row)*128 + col] += a2[mt][nt][reg] + b2[col];
  }
}

// ---------- pack: bf16 [r][c] -> per-channel bf16 [c][x][y]; r = TR ? y*256+x : x*256+y ----------
template<bool TR>
__global__ void __launch_bounds__(256) pack_cxy(const short* __restrict__ inA, const short* __restrict__ inB,
                                                short* __restrict__ outA, short* __restrict__ outB){
  __shared__ short tile[256*144];
  const short* in = blockIdx.y ? inB : inA;
  short* out      = blockIdx.y ? outB : outA;
  int x = blockIdx.x, tid = threadIdx.x;
  #pragma unroll
  for (int m=0;m<16;++m){
    int idx = m*256 + tid;
    int y = idx>>4, c0 = (idx&15)*8;
    int r = TR ? (y*256 + x) : (x*256 + y);
    *(int4*)&tile[y*144 + c0] = *(const int4*)&in[(size_t)r*128 + c0];
  }
  __syncthreads();
  int c = tid & 127, yh = tid >> 7;
  short* ob = out + (size_t)c*65536 + x*256 + yh*128;
  #pragma unroll
  for (int yc=0; yc<16; ++yc){
    short tmp[8];
    #pragma unroll
    for (int e=0;e<8;e++) tmp[e] = tile[(yh*128 + yc*8 + e)*144 + c];
    *(int4*)&ob[yc*8] = *(int4*)tmp;
  }
}

// ---------- triangle einsum, double-buffered staging ----------
__global__ void __launch_bounds__(512,4) k_einsum(const short* __restrict__ Ab,
                                                  const short* __restrict__ Bb,
                                                  short* __restrict__ Tb){
  __shared__ short as[2][128*64];
  __shared__ short bs[2][128*64];
  int c = blockIdx.z;
  int i0 = blockIdx.x*128, j0 = blockIdx.y*128;
  const short* A = Ab + (size_t)c*65536;
  const short* B = Bb + (size_t)c*65536;
  int tid = threadIdx.x;
  int wid = tid>>6, l = tid&63; int wm = wid>>1, wn = wid&1;
  f32x4 acc[2][4];
  ZERO_ACC(acc)

  #define ESTAGE(buf, kt) { \
    _Pragma("unroll") \
    for (int m_=0;m_<2;++m_){ \
      int d_ = m_*512 + tid; \
      int row_ = d_>>3, cw_ = d_&7; \
      glds16(&A[(size_t)(i0+row_)*256 + (kt)*64 + ((cw_ ^ (row_&7))<<3)], &as[buf][(d_ & ~63)*8]); \
      glds16(&B[(size_t)(j0+row_)*256 + (kt)*64 + ((cw_ ^ (row_&7))<<3)], &bs[buf][(d_ & ~63)*8]); \
    } }

  ESTAGE(0, 0)
  __syncthreads();
  for (int kt=0; kt<4; ++kt){
    int cur = kt & 1;
    if (kt < 3) ESTAGE(cur^1, kt+1)
    #pragma unroll
    for (int ks=0; ks<2; ++ks){
      bf16x8 a[2], b[4];
      #pragma unroll
      for (int mt=0; mt<2; ++mt){
        int row = wm*32 + mt*16 + (l&15);
        int ch  = (ks*4 + (l>>4)) ^ (row&7);
        a[mt] = *(const bf16x8*)&as[cur][row*64 + ch*8];
      }
      #pragma unroll
      for (int nt=0; nt<4; ++nt){
        int row = wn*64 + nt*16 + (l&15);
        int ch  = (ks*4 + (l>>4)) ^ (row&7);
        b[nt] = *(const bf16x8*)&bs[cur][row*64 + ch*8];
      }
      #pragma unroll
      for (int mt=0; mt<2; ++mt)
        #pragma unroll
        for (int nt=0; nt<4; ++nt)
          acc[mt][nt] = __builtin_amdgcn_mfma_f32_16x16x32_bf16(a[mt], b[nt], acc[mt][nt], 0,0,0);
    }
    __syncthreads();
  }
  short* To = Tb + (size_t)c*65536;
  FOR_EPI{
    int row = wm*32 + mt*16 + ((l>>4)<<2) + reg;
    int col = wn*64 + nt*16 + (l&15);
    To[(size_t)(i0+row)*256 + j0+col] = f2b(acc[mt][nt][reg]);
  }
}

// ---------- bf16 MFMA flash attention, Gperm-K, reg-Q, transposed-V, no P LDS ----------
__global__ void __launch_bounds__(256, 3) attn_mfma(const short* __restrict__ Qg,
                                                    const short* __restrict__ Kg,
                                                    const short* __restrict__ Vt,
                                                    const float* __restrict__ BSF,
                                                    short* __restrict__ O){
  __shared__ short Kf[8192];
  __shared__ short Vf[8192];
  int i = blockIdx.x, h = blockIdx.y;
  int tid = threadIdx.x;
  #pragma unroll
  for (int m=0;m<4;++m){
    int d = m*256 + tid;
    int t = d>>6, ll = d&63;
    glds16(&Kg[(size_t)(i*N_ + Gperm(t, ll&15))*CH + h*CA + ((ll>>4)<<3)],
           Kf + (size_t)(d & ~63)*8);
    glds16(&Vt[(size_t)(((i*H_ + h)*CA) + ((t>>3)<<4) + (ll&15))*N_ + ((t&7)<<5) + ((ll>>4)<<3)],
           Vf + (size_t)(d & ~63)*8);
  }
  __syncthreads();

  int wid = tid >> 6, l = tid & 63;
  int lg = l >> 4, ln = l & 15;

  for (int ss=0; ss<4; ++ss){
    int sub = wid*4 + ss;
    bf16x8 qfrag = *(const bf16x8*)&Qg[(size_t)(i*N_ + sub*16 + ln)*CH + h*CA + (lg<<3)];
    const float* bb = BSF + (size_t)(h*16 + sub)*4096 + (l<<2);
    f32x4 acc[16];
    #pragma unroll
    for (int t=0;t<16;t++) acc[t] = *(const f32x4*)&bb[t<<8];
    #pragma unroll
    for (int t=0;t<16;t++){
      bf16x8 kf = *(const bf16x8*)&Kf[t*512 + l*8];
      acc[t] = __builtin_amdgcn_mfma_f32_16x16x32_bf16(kf, qfrag, acc[t], 0,0,0);
    }
    float mx = -1e30f;
    #pragma unroll
    for (int t=0;t<16;t++)
      mx = fmaxf(mx, fmaxf(fmaxf(acc[t][0],acc[t][1]), fmaxf(acc[t][2],acc[t][3])));
    mx = fmaxf(mx, __shfl_xor(mx,16,64));
    mx = fmaxf(mx, __shfl_xor(mx,32,64));
    float sum = 0.f;
    #pragma unroll
    for (int t=0;t<16;t++){
      #pragma unroll
      for (int r=0;r<4;r++){ float p = __expf(acc[t][r]-mx); acc[t][r]=p; sum += p; }
    }
    sum += __shfl_xor(sum,16,64);
    sum += __shfl_xor(sum,32,64);
    float iv = 1.0f / sum;
    bf16x8 pf[8];
    #pragma unroll
    for (int jt=0;jt<8;jt++){
      int4 w4;
      w4.x = pk_bf16(acc[2*jt  ][0], acc[2*jt  ][1]);
      w4.y = pk_bf16(acc[2*jt  ][2], acc[2*jt  ][3]);
      w4.z = pk_bf16(acc[2*jt+1][0], acc[2*jt+1][1]);
      w4.w = pk_bf16(acc[2*jt+1][2], acc[2*jt+1][3]);
      pf[jt] = *(bf16x8*)&w4;
    }
    #pragma unroll
    for (int ct=0; ct<2; ++ct){
      f32x4 oe = {0.f,0.f,0.f,0.f}, oo = {0.f,0.f,0.f,0.f};
      #pragma unroll
      for (int jt=0;jt<8;jt+=2){
        bf16x8 ve = *(const bf16x8*)&Vf[((ct*8 + jt  )*64 + l)*8];
        bf16x8 vo = *(const bf16x8*)&Vf[((ct*8 + jt+1)*64 + l)*8];
        oe = __builtin_amdgcn_mfma_f32_16x16x32_bf16(ve, pf[jt  ], oe, 0,0,0);
        oo = __builtin_amdgcn_mfma_f32_16x16x32_bf16(vo, pf[jt+1], oo, 0,0,0);
      }
      int q = sub*16 + ln;
      int c = ct*16 + lg*4;
      short4 ov = { f2b((oe[0]+oo[0])*iv), f2b((oe[1]+oo[1])*iv),
                    f2b((oe[2]+oo[2])*iv), f2b((oe[3]+oo[3])*iv) };
      *(short4*)&O[(size_t)(i*N_ + q)*CH + h*CA + c] = ov;
    }
  }
}

extern "C" void kernel_launch(void* const* d_in, const int* in_sizes, int n_in,
                              void* d_out, int out_size, void* d_ws, size_t ws_size,
                              hipStream_t stream) {
  const float* z_in      = (const float*)d_in[0];
  const float* tm_lnin_w = (const float*)d_in[1];
  const float* tm_lnin_b = (const float*)d_in[2];
  const float* tm_ap_w   = (const float*)d_in[3];
  const float* tm_ap_b   = (const float*)d_in[4];
  const float* tm_ag_w   = (const float*)d_in[5];
  const float* tm_ag_b   = (const float*)d_in[6];
  const float* tm_bp_w   = (const float*)d_in[7];
  const float* tm_bp_b   = (const float*)d_in[8];
  const float* tm_bg_w   = (const float*)d_in[9];
  const float* tm_bg_b   = (const float*)d_in[10];
  const float* tm_g_w    = (const float*)d_in[11];
  const float* tm_g_b    = (const float*)d_in[12];
  const float* tm_zo_w   = (const float*)d_in[13];
  const float* tm_zo_b   = (const float*)d_in[14];
  const float* tm_lno_w  = (const float*)d_in[15];
  const float* tm_lno_b  = (const float*)d_in[16];
  const float* ta_ln_w   = (const float*)d_in[17];
  const float* ta_ln_b   = (const float*)d_in[18];
  const float* ta_q_w    = (const float*)d_in[19];
  const float* ta_k_w    = (const float*)d_in[20];
  const float* ta_v_w    = (const float*)d_in[21];
  const float* ta_b_w    = (const float*)d_in[22];
  const float* ta_g_w    = (const float*)d_in[23];
  const float* ta_g_b    = (const float*)d_in[24];
  const float* ta_o_w    = (const float*)d_in[25];
  const float* ta_o_b    = (const float*)d_in[26];
  const float* pt_ln_w   = (const float*)d_in[27];
  const float* pt_ln_b   = (const float*)d_in[28];
  const float* pt_1_w    = (const float*)d_in[29];
  const float* pt_1_b    = (const float*)d_in[30];
  const float* pt_2_w    = (const float*)d_in[31];
  const float* pt_2_b    = (const float*)d_in[32];

  float* z  = (float*)d_out;
  char* base = (char*)d_ws;
  const size_t MB = 1u<<20;
  short* wf  = (short*)base;                 // 30 x 32KB frag blobs
  short* Xb  = (short*)(base + 1*MB);        // 16MB bf16 [r][c]
  short* R1  = (short*)(base + 17*MB);
  short* R2  = (short*)(base + 33*MB);
  short* R3  = (short*)(base + 49*MB);       // Vt / packed A
  short* R4  = (short*)(base + 65*MB);
  short* Tb  = (short*)(base + 81*MB);       // 16MB bf16 [c][r]
  float* BSF = (float*)(base + 113*MB);      // 1MB

  #define SL(s) (wf + (size_t)(s)*16384)

  prep_weights<<<dim3(8,30), 256, 0, stream>>>(tm_ag_w, tm_ap_w, tm_bg_w, tm_bp_w,
                                               tm_g_w, tm_zo_w,
                                               ta_q_w, ta_k_w, ta_v_w, ta_g_w, ta_o_w,
                                               pt_1_w, pt_2_w, wf);

  // ---- triangle multiplication: outgoing (i=0), incoming (i=1) ----
  for (int i=0;i<2;i++){
    const float* zsrc = (i==0) ? z_in : z;
    ln_x<false><<<NN/4, 256, 0, stream>>>(zsrc, tm_lnin_w+i*CZ, tm_lnin_b+i*CZ, Xb);
    k_quad_gate<<<NN/128, 512, 0, stream>>>(Xb, SL(i*6+0), tm_ag_b+i*CH, SL(i*6+1), tm_ap_b+i*CH,
                                            SL(i*6+2), tm_bg_b+i*CH, SL(i*6+3), tm_bp_b+i*CH,
                                            R1, R2);
    if (i==0) pack_cxy<false><<<dim3(256,2), 256, 0, stream>>>(R1, R2, R3, R4);
    else      pack_cxy<true ><<<dim3(256,2), 256, 0, stream>>>(R1, R2, R3, R4);
    k_einsum<<<dim3(2,2,128), 512, 0, stream>>>(R3, R4, Tb);
    k_tri_finish<<<NN/128, 512, 0, stream>>>(Tb, Xb, SL(i*6+5), tm_zo_b+i*CZ,
                                             SL(i*6+4), tm_g_b+i*CZ,
                                             tm_lno_w+i*CH, tm_lno_b+i*CH, zsrc, z);
  }

  // ---- triangle attention: starting (i=0), ending (i=1, transposed coords) ----
  for (int i=0;i<2;i++){
    if (i==0) ln_x<false><<<NN/4, 256, 0, stream>>>(z, ta_ln_w, ta_ln_b, Xb);
    else      ln_x<true ><<<NN/4, 256, 0, stream>>>(z, ta_ln_w+CZ, ta_ln_b+CZ, Xb);
    k_qkv<<<NN/128, 512, 0, stream>>>(Xb, SL(12+i*5+0), 0.17677669529663687f,
                                      SL(12+i*5+1), SL(12+i*5+2), ta_b_w+i*CZ*H_,
                                      R1, R2, R3, BSF);
    attn_mfma<<<dim3(N_,H_), 256, 0, stream>>>(R1, R2, R3, BSF, R4);
    if (i==0) k_attn_out<false><<<NN/128, 512, 0, stream>>>(R4, Xb, SL(12+i*5+3), ta_g_b+i*H_*CA,
                                                            SL(12+i*5+4), ta_o_b+i*CZ, z);
    else      k_attn_out<true ><<<NN/128, 512, 0, stream>>>(R4, Xb, SL(12+i*5+3), ta_g_b+i*H_*CA,
                                                            SL(12+i*5+4), ta_o_b+i*CZ, z);
  }

  // ---- pair transition (LN fused) ----
  k_pt<<<NN/128, 512, 0, stream>>>(pt_ln_w, pt_ln_b, SL(22), pt_1_b, SL(26), pt_2_b, z);
}

// Round 7
// 534.880 us; speedup vs baseline: 7.8048x; 1.0937x over previous
//
#include <hip/hip_runtime.h>
#include <math.h>

#define N_  256
#define NN  65536
#define CZ  128
#define CH  128
#define H_  4
#define CA  32

typedef __attribute__((ext_vector_type(8))) short bf16x8;
typedef __attribute__((ext_vector_type(4))) float f32x4;

__device__ __forceinline__ float sigmoidf_(float x){ return 1.f/(1.f+__expf(-x)); }

__device__ __forceinline__ short f2b(float f){
  unsigned u = __float_as_uint(f);
  unsigned r = (u + 0x7fffu + ((u>>16)&1u)) >> 16;
  return (short)r;
}
__device__ __forceinline__ float b2f(short s){
  unsigned u = ((unsigned)(unsigned short)s) << 16;
  return __uint_as_float(u);
}
__device__ __forceinline__ unsigned pk_bf16(float lo, float hi){
  unsigned r;
  asm volatile("v_cvt_pk_bf16_f32 %0, %1, %2" : "=v"(r) : "v"(lo), "v"(hi));
  return r;
}

__device__ __forceinline__ void glds16(const void* g, const void* l){
  __builtin_amdgcn_global_load_lds((const __attribute__((address_space(1))) void*)g,
                                   (__attribute__((address_space(3))) void*)l, 16, 0, 0);
}

__device__ __forceinline__ float wave_red_sum(float v){
  #pragma unroll
  for(int o=32;o>0;o>>=1) v += __shfl_xor(v,o,64);
  return v;
}

// K-row permutation: QK tile t, C-row m -> true key index j
__device__ __forceinline__ int Gperm(int t, int m){
  return ((t>>1)<<5) + ((m>>2)<<3) + ((t&1)<<2) + (m&3);
}

// ---------- weight prep: fp32 [K][N] slices -> bf16 B-fragment-packed blobs ----------
__global__ void __launch_bounds__(256) prep_weights(
    const float* tm_ag, const float* tm_ap, const float* tm_bg, const float* tm_bp,
    const float* tm_g, const float* tm_zo,
    const float* ta_q, const float* ta_k, const float* ta_v, const float* ta_g, const float* ta_o,
    const float* pt1, const float* pt2, short* Wf){
  int tid = threadIdx.x;
  int g = blockIdx.x*4 + (tid>>6);
  int l = tid & 63;
  int s = blockIdx.y;
  const float* src; int ldn = 128, koff = 0, noff = 0;
  if (s < 12){
    int i = s/6, w = s - i*6;
    switch(w){ case 0: src=tm_ag; break; case 1: src=tm_ap; break; case 2: src=tm_bg; break;
               case 3: src=tm_bp; break; case 4: src=tm_g;  break; default: src=tm_zo; }
    src += i*16384;
  } else if (s < 22){
    int t2 = s-12; int i = t2/5, w = t2 - i*5;
    switch(w){ case 0: src=ta_q; break; case 1: src=ta_k; break; case 2: src=ta_v; break;
               case 3: src=ta_g; break; default: src=ta_o; }
    src += i*16384;
  } else if (s < 26){
    src = pt1; ldn = 512; noff = (s-22)*128;
  } else {
    src = pt2; koff = (s-26)*128;
  }
  int nt = g>>2, ks = g&3;
  int n = noff + nt*16 + (l&15);
  int kb = koff + ks*32 + (l>>4)*8;
  short tmp[8];
  #pragma unroll
  for (int e=0;e<8;e++) tmp[e] = f2b(src[(size_t)(kb+e)*ldn + n]);
  short* dst = Wf + s*16384 + ((nt*4+ks)*64 + l)*8;
  *(short4*)dst     = *(short4*)&tmp[0];
  *(short4*)(dst+4) = *(short4*)&tmp[4];
}

// ---------- LayerNorm: fp32 in -> bf16 out; TRANS reads transposed grid ----------
template<bool TRANS>
__global__ void __launch_bounds__(256) ln_x(const float* __restrict__ in,
                                            const float* __restrict__ w,
                                            const float* __restrict__ b,
                                            short* __restrict__ out){
  int wid  = threadIdx.x >> 6;
  int lane = threadIdx.x & 63;
  int row  = blockIdx.x*4 + wid;
  int irow;
  if (TRANS){ int i = row >> 8, j = row & 255; irow = (j<<8) | i; } else irow = row;
  float v0 = in[(size_t)irow*CZ + lane];
  float v1 = in[(size_t)irow*CZ + lane + 64];
  float m  = wave_red_sum(v0+v1) * (1.f/128.f);
  float d0 = v0-m, d1 = v1-m;
  float var = wave_red_sum(d0*d0 + d1*d1) * (1.f/128.f);
  float r = rsqrtf(var + 1e-5f);
  out[(size_t)row*CZ + lane]      = f2b(d0*r*w[lane]    + b[lane]);
  out[(size_t)row*CZ + lane + 64] = f2b(d1*r*w[lane+64] + b[lane+64]);
}

// ---------- 8-wave GEMM helpers (512 threads, 128x128 tile) ----------
__device__ __forceinline__ void stage128_8(const short* __restrict__ g, short* xs, int r0, int tid){
  #pragma unroll
  for (int m=0;m<4;++m){
    int d = m*512 + tid;
    int row = d>>4, cw = d&15;
    glds16(&g[(size_t)(r0+row)*128 + ((cw ^ (row&15))<<3)], xs + (size_t)(d & ~63)*8);
  }
}

__device__ __forceinline__ bf16x8 ldsA(const short* xs, int row, int ch){
  return *(const bf16x8*)&xs[row*128 + ((ch ^ (row&15))<<3)];
}

// stage one K-half (64 of 128 K) of a weight frag-blob into a 16KB LDS buffer.
// wb half layout: hchunk = nt8*2 + ks2 (1KB each); src chunk = nt8*4 + h*2 + ks2.
__device__ __forceinline__ void stageW(const short* __restrict__ wf, int h, short* wb, int tid){
  #pragma unroll
  for (int r=0;r<2;++r){
    int s = r*512 + tid;
    int ch = s>>6, ln = s&63;
    glds16(wf + (size_t)(((ch>>1)*4 + h*2 + (ch&1))*64 + ln)*8, wb + (size_t)(s & ~63)*8);
  }
}

// consume one K-half: A from swizzled LDS tile, B from wb half buffer
__device__ __forceinline__ void core_half(const short* xs, const short* wb, int h,
                                          int wm, int wn, int l, f32x4 (&acc)[2][4]){
  #pragma unroll
  for (int ks2=0; ks2<2; ++ks2){
    bf16x8 a[2], b[4];
    #pragma unroll
    for (int mt=0; mt<2; ++mt)
      a[mt] = ldsA(xs, wm*32 + mt*16 + (l&15), (h*2+ks2)*4 + (l>>4));
    #pragma unroll
    for (int nt=0; nt<4; ++nt)
      b[nt] = *(const bf16x8*)&wb[(size_t)(((wn*4+nt)*2 + ks2)*64 + l)*8];
    #pragma unroll
    for (int mt=0; mt<2; ++mt)
      #pragma unroll
      for (int nt=0; nt<4; ++nt)
        acc[mt][nt] = __builtin_amdgcn_mfma_f32_16x16x32_bf16(a[mt], b[nt], acc[mt][nt], 0,0,0);
  }
}

#define ZERO_ACC(A) { _Pragma("unroll") for(int _a=0;_a<2;_a++) _Pragma("unroll") for(int _b=0;_b<4;_b++) A[_a][_b]=(f32x4){0,0,0,0}; }

#define GEMM_PROLOG8 \
  int tid = threadIdx.x; int r0 = blockIdx.x*128; \
  int wid = tid>>6, l = tid&63; int wm = wid>>1, wn = wid&1; (void)r0;

#define EPI8 \
  int row = wm*32 + mt*16 + ((l>>4)<<2) + reg; \
  int col = wn*64 + nt*16 + (l&15);

#define FOR_EPI for (int mt=0;mt<2;++mt) for (int nt=0;nt<4;++nt) for (int reg=0;reg<4;++reg)

// scatter a packed bf16 C-tile (int2 per (mt,nt)) into swizzled LDS
#define SCATTER_PACKED(P, LDSBUF) \
  _Pragma("unroll") \
  for (int mt=0;mt<2;++mt) \
    _Pragma("unroll") \
    for (int nt=0;nt<4;++nt){ \
      int row0 = wm*32 + mt*16 + ((l>>4)<<2); \
      int col  = wn*64 + nt*16 + (l&15); \
      unsigned lo = (unsigned)P[mt][nt].x, hi = (unsigned)P[mt][nt].y; \
      LDSBUF[(row0  )*128 + (((col>>3) ^ ((row0  )&15))<<3) + (col&7)] = (short)(lo & 0xffff); \
      LDSBUF[(row0+1)*128 + (((col>>3) ^ ((row0+1)&15))<<3) + (col&7)] = (short)(lo >> 16); \
      LDSBUF[(row0+2)*128 + (((col>>3) ^ ((row0+2)&15))<<3) + (col&7)] = (short)(hi & 0xffff); \
      LDSBUF[(row0+3)*128 + (((col>>3) ^ ((row0+3)&15))<<3) + (col&7)] = (short)(hi >> 16); \
    }

#define STORE_TILE(OUT, LDSBUF) \
  _Pragma("unroll") \
  for (int m2=0;m2<4;++m2){ \
    int d = m2*512 + tid; int row = d>>4, ch = d&15; \
    *(int4*)&OUT[(size_t)(r0+row)*128 + ch*8] = *(const int4*)&LDSBUF[row*128 + ((ch ^ (row&15))<<3)]; \
  }

// ---------- fused dual dual-gate: out1 = sig(X@Wag+bag)*(X@Wap+bap); out2 likewise ----------
__global__ void __launch_bounds__(512,4) k_quad_gate(const short* __restrict__ X,
                                                     const short* __restrict__ Wagf, const float* __restrict__ bag,
                                                     const short* __restrict__ Wapf, const float* __restrict__ bap,
                                                     const short* __restrict__ Wbgf, const float* __restrict__ bbg,
                                                     const short* __restrict__ Wbpf, const float* __restrict__ bbp,
                                                     short* __restrict__ out1, short* __restrict__ out2){
  __shared__ short xs[16384];
  __shared__ short wb[2][8192];
  short* wbf = &wb[0][0];
  GEMM_PROLOG8
  stageW(Wagf, 0, wb[0], tid);
  stage128_8(X, xs, r0, tid);
  __syncthreads();
  int2 o1[2][4], o2[2][4];
  {
    f32x4 ag[2][4], ap[2][4];
    ZERO_ACC(ag) ZERO_ACC(ap)
    stageW(Wagf, 1, wb[1], tid); core_half(xs, wb[0], 0, wm, wn, l, ag); __syncthreads();
    stageW(Wapf, 0, wb[0], tid); core_half(xs, wb[1], 1, wm, wn, l, ag); __syncthreads();
    stageW(Wapf, 1, wb[1], tid); core_half(xs, wb[0], 0, wm, wn, l, ap); __syncthreads();
    stageW(Wbgf, 0, wb[0], tid); core_half(xs, wb[1], 1, wm, wn, l, ap); __syncthreads();
    #pragma unroll
    for (int mt=0;mt<2;++mt)
      #pragma unroll
      for (int nt=0;nt<4;++nt){
        int col = wn*64 + nt*16 + (l&15);
        float bgc = bag[col], bpc = bap[col];
        float v0 = (ap[mt][nt][0]+bpc)*sigmoidf_(ag[mt][nt][0]+bgc);
        float v1 = (ap[mt][nt][1]+bpc)*sigmoidf_(ag[mt][nt][1]+bgc);
        float v2 = (ap[mt][nt][2]+bpc)*sigmoidf_(ag[mt][nt][2]+bgc);
        float v3 = (ap[mt][nt][3]+bpc)*sigmoidf_(ag[mt][nt][3]+bgc);
        o1[mt][nt].x = (int)pk_bf16(v0,v1);
        o1[mt][nt].y = (int)pk_bf16(v2,v3);
      }
  }
  {
    f32x4 bg2[2][4], bp2[2][4];
    ZERO_ACC(bg2) ZERO_ACC(bp2)
    stageW(Wbgf, 1, wb[1], tid); core_half(xs, wb[0], 0, wm, wn, l, bg2); __syncthreads();
    stageW(Wbpf, 0, wb[0], tid); core_half(xs, wb[1], 1, wm, wn, l, bg2); __syncthreads();
    stageW(Wbpf, 1, wb[1], tid); core_half(xs, wb[0], 0, wm, wn, l, bp2); __syncthreads();
    core_half(xs, wb[1], 1, wm, wn, l, bp2);
    #pragma unroll
    for (int mt=0;mt<2;++mt)
      #pragma unroll
      for (int nt=0;nt<4;++nt){
        int col = wn*64 + nt*16 + (l&15);
        float bgc = bbg[col], bpc = bbp[col];
        float v0 = (bp2[mt][nt][0]+bpc)*sigmoidf_(bg2[mt][nt][0]+bgc);
        float v1 = (bp2[mt][nt][1]+bpc)*sigmoidf_(bg2[mt][nt][1]+bgc);
        float v2 = (bp2[mt][nt][2]+bpc)*sigmoidf_(bg2[mt][nt][2]+bgc);
        float v3 = (bp2[mt][nt][3]+bpc)*sigmoidf_(bg2[mt][nt][3]+bgc);
        o2[mt][nt].x = (int)pk_bf16(v0,v1);
        o2[mt][nt].y = (int)pk_bf16(v2,v3);
      }
  }
  __syncthreads();                 // wb free
  SCATTER_PACKED(o1, wbf)
  __syncthreads();
  STORE_TILE(out1, wbf)
  __syncthreads();
  SCATTER_PACKED(o2, wbf)
  __syncthreads();
  STORE_TILE(out2, wbf)
}

// ---------- fused QKV+bias: Q,K plain; V transposed; bias in permuted C-frag order ----------
__global__ void __launch_bounds__(512,4) k_qkv(const short* __restrict__ X,
                                               const short* __restrict__ Wqf, float sq,
                                               const short* __restrict__ Wkf,
                                               const short* __restrict__ Wvf,
                                               const float* __restrict__ bw,
                                               short* __restrict__ out_q, short* __restrict__ out_k,
                                               short* __restrict__ Vt, float* __restrict__ BSF){
  __shared__ short xs[16384];
  __shared__ short wb[2][8192];
  short* wbf = &wb[0][0];
  GEMM_PROLOG8
  stageW(Wqf, 0, wb[0], tid);
  stage128_8(X, xs, r0, tid);
  __syncthreads();
  int2 oq[2][4], ok[2][4];
  {
    f32x4 aq[2][4], ak[2][4];
    ZERO_ACC(aq) ZERO_ACC(ak)
    stageW(Wqf, 1, wb[1], tid); core_half(xs, wb[0], 0, wm, wn, l, aq); __syncthreads();
    stageW(Wkf, 0, wb[0], tid); core_half(xs, wb[1], 1, wm, wn, l, aq); __syncthreads();
    #pragma unroll
    for (int mt=0;mt<2;++mt)
      #pragma unroll
      for (int nt=0;nt<4;++nt){
        oq[mt][nt].x = (int)pk_bf16(aq[mt][nt][0]*sq, aq[mt][nt][1]*sq);
        oq[mt][nt].y = (int)pk_bf16(aq[mt][nt][2]*sq, aq[mt][nt][3]*sq);
      }
    stageW(Wkf, 1, wb[1], tid); core_half(xs, wb[0], 0, wm, wn, l, ak); __syncthreads();
    stageW(Wvf, 0, wb[0], tid); core_half(xs, wb[1], 1, wm, wn, l, ak); __syncthreads();
    #pragma unroll
    for (int mt=0;mt<2;++mt)
      #pragma unroll
      for (int nt=0;nt<4;++nt){
        ok[mt][nt].x = (int)pk_bf16(ak[mt][nt][0], ak[mt][nt][1]);
        ok[mt][nt].y = (int)pk_bf16(ak[mt][nt][2], ak[mt][nt][3]);
      }
  }
  f32x4 av[2][4];
  ZERO_ACC(av)
  stageW(Wvf, 1, wb[1], tid); core_half(xs, wb[0], 0, wm, wn, l, av); __syncthreads();
  core_half(xs, wb[1], 1, wm, wn, l, av);
  // bias epilogue: thread (rl = tid&127, h = tid>>7) computes X[rl,:]@bw[:,h]
  {
    int rl = tid & 127, hh = tid >> 7;
    float bacc = 0.f;
    #pragma unroll
    for (int ch=0; ch<16; ++ch){
      bf16x8 v = ldsA(xs, rl, ch);
      #pragma unroll
      for (int e=0;e<8;++e) bacc += b2f(v[e]) * bw[(ch*8+e)*H_ + hh];
    }
    int r = r0 + rl;
    int qq = r >> 8, j = r & 255;
    int t = ((j>>5)<<1) + ((j>>2)&1);
    int mm = (((j>>3)&3)<<2) + (j&3);
    int idx = (((hh*16 + (qq>>4))*16 + t) << 8) + (((mm>>2)*16 + (qq&15)) << 2) + (mm&3);
    BSF[idx] = bacc;
  }
  __syncthreads();   // everyone done reading xs
  // write V transposed into xs as [c][r] with chunk-XOR on r
  #pragma unroll
  for (int mt=0;mt<2;++mt)
    #pragma unroll
    for (int nt=0;nt<4;++nt){
      int rb  = wm*32 + mt*16 + ((l>>4)<<2);
      int col = wn*64 + nt*16 + (l&15);
      short4 s4 = { f2b(av[mt][nt][0]), f2b(av[mt][nt][1]), f2b(av[mt][nt][2]), f2b(av[mt][nt][3]) };
      *(short4*)&xs[col*128 + (((rb>>3) ^ (col&15))<<3) + (rb&7)] = s4;
    }
  __syncthreads();
  int i = r0>>8, j0 = r0&255;
  #pragma unroll
  for (int m=0;m<4;++m){
    int d = m*512 + tid;
    int c = d>>4, ch = d&15;
    int4 val = *(const int4*)&xs[c*128 + ((ch ^ (c&15))<<3)];
    *(int4*)&Vt[(size_t)((i*4 + (c>>5))*32 + (c&31))*256 + j0 + ch*8] = val;
  }
  // bounce q and k through wb for vectorized stores
  SCATTER_PACKED(oq, wbf)
  __syncthreads();
  STORE_TILE(out_q, wbf)
  __syncthreads();
  SCATTER_PACKED(ok, wbf)
  __syncthreads();
  STORE_TILE(out_k, wbf)
}

// ---------- fused LN(T)+tri_finish ----------
__global__ void __launch_bounds__(512,2) k_tri_finish(const short* __restrict__ Tb,  // bf16 [c][r]
                                                      const short* __restrict__ X,
                                                      const short* __restrict__ Wzf, const float* __restrict__ bz,
                                                      const short* __restrict__ Wgf, const float* __restrict__ bg,
                                                      const float* __restrict__ lnw, const float* __restrict__ lnb,
                                                      const float* __restrict__ zin, float* __restrict__ zout){
  __shared__ short tt[16384];
  __shared__ short xs[16384];
  __shared__ short wb[2][8192];
  __shared__ float ps[512], pq[512];
  __shared__ float mu[128], iv[128];
  GEMM_PROLOG8
  stageW(Wzf, 0, wb[0], tid);
  stage128_8(X, xs, r0, tid);
  #pragma unroll
  for (int m=0;m<4;++m){
    int d = m*512 + tid;
    int c = d>>4, ch = d&15;
    glds16(&Tb[(size_t)c*65536 + r0 + ch*8], tt + (size_t)(d & ~63)*8);
  }
  __syncthreads();
  int rl = tid & 127, cq = tid >> 7;
  float vals[32]; float s = 0.f, q = 0.f;
  #pragma unroll
  for (int cc=0; cc<32; ++cc){
    float v = b2f(tt[(cq*32+cc)*128 + rl]);
    vals[cc] = v; s += v; q += v*v;
  }
  ps[cq*128 + rl] = s; pq[cq*128 + rl] = q;
  __syncthreads();
  if (tid < 128){
    float ss = ps[tid]+ps[128+tid]+ps[256+tid]+ps[384+tid];
    float qq = pq[tid]+pq[128+tid]+pq[256+tid]+pq[384+tid];
    float m = ss * (1.f/128.f);
    float var = qq * (1.f/128.f) - m*m;
    mu[tid] = m; iv[tid] = rsqrtf(var + 1e-5f);
  }
  __syncthreads();
  {
    float m = mu[rl], r = iv[rl];
    #pragma unroll
    for (int chq=0; chq<4; ++chq){
      short tmp[8];
      #pragma unroll
      for (int e=0;e<8;++e){
        int cc = chq*8 + e;
        int c = cq*32 + cc;
        tmp[e] = f2b((vals[cc]-m)*r*lnw[c] + lnb[c]);
      }
      int ch = cq*4 + chq;
      *(int4*)&tt[rl*128 + ((ch ^ (rl&15))<<3)] = *(int4*)tmp;
    }
  }
  __syncthreads();
  f32x4 az[2][4], ag[2][4];
  ZERO_ACC(az) ZERO_ACC(ag)
  stageW(Wzf, 1, wb[1], tid); core_half(tt, wb[0], 0, wm, wn, l, az); __syncthreads();
  stageW(Wgf, 0, wb[0], tid); core_half(tt, wb[1], 1, wm, wn, l, az); __syncthreads();
  stageW(Wgf, 1, wb[1], tid); core_half(xs, wb[0], 0, wm, wn, l, ag); __syncthreads();
  core_half(xs, wb[1], 1, wm, wn, l, ag);
  FOR_EPI{
    EPI8
    size_t idx = (size_t)(r0+row)*128 + col;
    float v = (az[mt][nt][reg] + bz[col]) * sigmoidf_(ag[mt][nt][reg] + bg[col]);
    zout[idx] = zin[idx] + v;
  }
}

// ---------- z(±T) += ((O*sigmoid(X@Wg+bg)) @ Wo + bo) ----------
template<bool TRANS>
__global__ void __launch_bounds__(512,2) k_attn_out(const short* __restrict__ O,
                                                    const short* __restrict__ X,
                                                    const short* __restrict__ Wgf, const float* __restrict__ bg,
                                                    const short* __restrict__ Wof, const float* __restrict__ bo,
                                                    float* __restrict__ z){
  __shared__ short xs[16384];
  __shared__ short os[16384];
  __shared__ short wb[2][8192];
  GEMM_PROLOG8
  stageW(Wgf, 0, wb[0], tid);
  stage128_8(X, xs, r0, tid);
  #pragma unroll
  for (int m=0;m<4;++m){
    int d = m*512 + tid;
    int row = d>>4, ch = d&15;
    glds16(&O[(size_t)(r0+row)*128 + ch*8], os + (size_t)(d & ~63)*8);
  }
  __syncthreads();
  f32x4 ag[2][4];
  ZERO_ACC(ag)
  stageW(Wgf, 1, wb[1], tid); core_half(xs, wb[0], 0, wm, wn, l, ag); __syncthreads();
  stageW(Wof, 0, wb[0], tid); core_half(xs, wb[1], 1, wm, wn, l, ag); __syncthreads();
  stageW(Wof, 1, wb[1], tid);
  FOR_EPI{
    EPI8
    float ov = b2f(os[row*128 + col]);
    float v = ov * sigmoidf_(ag[mt][nt][reg] + bg[col]);
    xs[row*128 + (((col>>3) ^ (row&15))<<3) + (col&7)] = f2b(v);
  }
  __syncthreads();
  f32x4 a2[2][4];
  ZERO_ACC(a2)
  core_half(xs, wb[0], 0, wm, wn, l, a2);
  core_half(xs, wb[1], 1, wm, wn, l, a2);
  FOR_EPI{
    EPI8
    int orow = r0+row;
    int zrow = TRANS ? (((orow&255)<<8) | (orow>>8)) : orow;
    z[(size_t)zrow*128 + col] += a2[mt][nt][reg] + bo[col];
  }
}

// ---------- pair transition with fused LN: z += relu(LN(z)@W1+b1)@W2 + b2 ----------
__global__ void __launch_bounds__(512,2) k_pt(const float* __restrict__ lnw, const float* __restrict__ lnb,
                                              const short* __restrict__ W1f, const float* __restrict__ b1,
                                              const short* __restrict__ W2f, const float* __restrict__ b2,
                                              float* __restrict__ z){
  __shared__ short xs[16384];
  __shared__ short hs[16384];
  __shared__ short wb[2][8192];
  __shared__ float ps[512], pq[512];
  __shared__ float mu[128], iv[128];
  GEMM_PROLOG8
  stageW(W1f, 0, wb[0], tid);
  // LN from z directly: thread owns (rl, c-quarter)
  int rl = tid & 127, cq = tid >> 7;
  float vals[32]; float s = 0.f, q = 0.f;
  {
    const float* zr = &z[(size_t)(r0+rl)*128 + cq*32];
    #pragma unroll
    for (int cc=0; cc<32; cc+=4){
      float4 v4 = *(const float4*)&zr[cc];
      vals[cc]=v4.x; vals[cc+1]=v4.y; vals[cc+2]=v4.z; vals[cc+3]=v4.w;
      s += v4.x+v4.y+v4.z+v4.w;
      q += v4.x*v4.x + v4.y*v4.y + v4.z*v4.z + v4.w*v4.w;
    }
  }
  ps[cq*128 + rl] = s; pq[cq*128 + rl] = q;
  __syncthreads();
  if (tid < 128){
    float ss = ps[tid]+ps[128+tid]+ps[256+tid]+ps[384+tid];
    float qq = pq[tid]+pq[128+tid]+pq[256+tid]+pq[384+tid];
    float m = ss * (1.f/128.f);
    float var = qq * (1.f/128.f) - m*m;
    mu[tid] = m; iv[tid] = rsqrtf(var + 1e-5f);
  }
  __syncthreads();
  {
    float m = mu[rl], r = iv[rl];
    #pragma unroll
    for (int chq=0; chq<4; ++chq){
      short tmp[8];
      #pragma unroll
      for (int e=0;e<8;++e){
        int cc = chq*8 + e;
        int c = cq*32 + cc;
        tmp[e] = f2b((vals[cc]-m)*r*lnw[c] + lnb[c]);
      }
      int ch = cq*4 + chq;
      *(int4*)&xs[rl*128 + ((ch ^ (rl&15))<<3)] = *(int4*)tmp;
    }
  }
  __syncthreads();
  f32x4 a2[2][4];
  ZERO_ACC(a2)
  for (int m=0;m<4;++m){
    f32x4 a1[2][4];
    ZERO_ACC(a1)
    stageW(W1f + m*16384, 1, wb[1], tid); core_half(xs, wb[0], 0, wm, wn, l, a1); __syncthreads();
    stageW(W2f + m*16384, 0, wb[0], tid); core_half(xs, wb[1], 1, wm, wn, l, a1); __syncthreads();
    stageW(W2f + m*16384, 1, wb[1], tid);
    FOR_EPI{
      EPI8
      float v = fmaxf(a1[mt][nt][reg] + b1[m*128 + col], 0.f);
      hs[row*128 + (((col>>3) ^ (row&15))<<3) + (col&7)] = f2b(v);
    }
    __syncthreads();
    core_half(hs, wb[0], 0, wm, wn, l, a2);
    __syncthreads();
    if (m<3) stageW(W1f + (m+1)*16384, 0, wb[0], tid);
    core_half(hs, wb[1], 1, wm, wn, l, a2);
    __syncthreads();
  }
  FOR_EPI{
    EPI8
    z[(size_t)(r0+row)*128 + col] += a2[mt][nt][reg] + b2[col];
  }
}

// ---------- pack: bf16 [r][c] -> per-channel bf16 [c][x][y]; r = TR ? y*256+x : x*256+y ----------
template<bool TR>
__global__ void __launch_bounds__(256) pack_cxy(const short* __restrict__ inA, const short* __restrict__ inB,
                                                short* __restrict__ outA, short* __restrict__ outB){
  __shared__ short tile[256*144];
  const short* in = blockIdx.y ? inB : inA;
  short* out      = blockIdx.y ? outB : outA;
  int x = blockIdx.x, tid = threadIdx.x;
  #pragma unroll
  for (int m=0;m<16;++m){
    int idx = m*256 + tid;
    int y = idx>>4, c0 = (idx&15)*8;
    int r = TR ? (y*256 + x) : (x*256 + y);
    *(int4*)&tile[y*144 + c0] = *(const int4*)&in[(size_t)r*128 + c0];
  }
  __syncthreads();
  int c = tid & 127, yh = tid >> 7;
  short* ob = out + (size_t)c*65536 + x*256 + yh*128;
  #pragma unroll
  for (int yc=0; yc<16; ++yc){
    short tmp[8];
    #pragma unroll
    for (int e=0;e<8;e++) tmp[e] = tile[(yh*128 + yc*8 + e)*144 + c];
    *(int4*)&ob[yc*8] = *(int4*)tmp;
  }
}

// ---------- triangle einsum, double-buffered staging ----------
__global__ void __launch_bounds__(512,4) k_einsum(const short* __restrict__ Ab,
                                                  const short* __restrict__ Bb,
                                                  short* __restrict__ Tb){
  __shared__ short as[2][128*64];
  __shared__ short bs[2][128*64];
  int c = blockIdx.z;
  int i0 = blockIdx.x*128, j0 = blockIdx.y*128;
  const short* A = Ab + (size_t)c*65536;
  const short* B = Bb + (size_t)c*65536;
  int tid = threadIdx.x;
  int wid = tid>>6, l = tid&63; int wm = wid>>1, wn = wid&1;
  f32x4 acc[2][4];
  ZERO_ACC(acc)

  #define ESTAGE(buf, kt) { \
    _Pragma("unroll") \
    for (int m_=0;m_<2;++m_){ \
      int d_ = m_*512 + tid; \
      int row_ = d_>>3, cw_ = d_&7; \
      glds16(&A[(size_t)(i0+row_)*256 + (kt)*64 + ((cw_ ^ (row_&7))<<3)], &as[buf][(d_ & ~63)*8]); \
      glds16(&B[(size_t)(j0+row_)*256 + (kt)*64 + ((cw_ ^ (row_&7))<<3)], &bs[buf][(d_ & ~63)*8]); \
    } }

  ESTAGE(0, 0)
  __syncthreads();
  for (int kt=0; kt<4; ++kt){
    int cur = kt & 1;
    if (kt < 3) ESTAGE(cur^1, kt+1)
    #pragma unroll
    for (int ks=0; ks<2; ++ks){
      bf16x8 a[2], b[4];
      #pragma unroll
      for (int mt=0; mt<2; ++mt){
        int row = wm*32 + mt*16 + (l&15);
        int ch  = (ks*4 + (l>>4)) ^ (row&7);
        a[mt] = *(const bf16x8*)&as[cur][row*64 + ch*8];
      }
      #pragma unroll
      for (int nt=0; nt<4; ++nt){
        int row = wn*64 + nt*16 + (l&15);
        int ch  = (ks*4 + (l>>4)) ^ (row&7);
        b[nt] = *(const bf16x8*)&bs[cur][row*64 + ch*8];
      }
      #pragma unroll
      for (int mt=0; mt<2; ++mt)
        #pragma unroll
        for (int nt=0; nt<4; ++nt)
          acc[mt][nt] = __builtin_amdgcn_mfma_f32_16x16x32_bf16(a[mt], b[nt], acc[mt][nt], 0,0,0);
    }
    __syncthreads();
  }
  short* To = Tb + (size_t)c*65536;
  FOR_EPI{
    int row = wm*32 + mt*16 + ((l>>4)<<2) + reg;
    int col = wn*64 + nt*16 + (l&15);
    To[(size_t)(i0+row)*256 + j0+col] = f2b(acc[mt][nt][reg]);
  }
}

// ---------- bf16 MFMA flash attention, Gperm-K, reg-Q, transposed-V, no P LDS ----------
__global__ void __launch_bounds__(256, 3) attn_mfma(const short* __restrict__ Qg,
                                                    const short* __restrict__ Kg,
                                                    const short* __restrict__ Vt,
                                                    const float* __restrict__ BSF,
                                                    short* __restrict__ O){
  __shared__ short Kf[8192];
  __shared__ short Vf[8192];
  int i = blockIdx.x, h = blockIdx.y;
  int tid = threadIdx.x;
  #pragma unroll
  for (int m=0;m<4;++m){
    int d = m*256 + tid;
    int t = d>>6, ll = d&63;
    glds16(&Kg[(size_t)(i*N_ + Gperm(t, ll&15))*CH + h*CA + ((ll>>4)<<3)],
           Kf + (size_t)(d & ~63)*8);
    glds16(&Vt[(size_t)(((i*H_ + h)*CA) + ((t>>3)<<4) + (ll&15))*N_ + ((t&7)<<5) + ((ll>>4)<<3)],
           Vf + (size_t)(d & ~63)*8);
  }
  __syncthreads();

  int wid = tid >> 6, l = tid & 63;
  int lg = l >> 4, ln = l & 15;

  for (int ss=0; ss<4; ++ss){
    int sub = wid*4 + ss;
    bf16x8 qfrag = *(const bf16x8*)&Qg[(size_t)(i*N_ + sub*16 + ln)*CH + h*CA + (lg<<3)];
    const float* bb = BSF + (size_t)(h*16 + sub)*4096 + (l<<2);
    f32x4 acc[16];
    #pragma unroll
    for (int t=0;t<16;t++) acc[t] = *(const f32x4*)&bb[t<<8];
    #pragma unroll
    for (int t=0;t<16;t++){
      bf16x8 kf = *(const bf16x8*)&Kf[t*512 + l*8];
      acc[t] = __builtin_amdgcn_mfma_f32_16x16x32_bf16(kf, qfrag, acc[t], 0,0,0);
    }
    float mx = -1e30f;
    #pragma unroll
    for (int t=0;t<16;t++)
      mx = fmaxf(mx, fmaxf(fmaxf(acc[t][0],acc[t][1]), fmaxf(acc[t][2],acc[t][3])));
    mx = fmaxf(mx, __shfl_xor(mx,16,64));
    mx = fmaxf(mx, __shfl_xor(mx,32,64));
    float sum = 0.f;
    #pragma unroll
    for (int t=0;t<16;t++){
      #pragma unroll
      for (int r=0;r<4;r++){ float p = __expf(acc[t][r]-mx); acc[t][r]=p; sum += p; }
    }
    sum += __shfl_xor(sum,16,64);
    sum += __shfl_xor(sum,32,64);
    float iv = 1.0f / sum;
    bf16x8 pf[8];
    #pragma unroll
    for (int jt=0;jt<8;jt++){
      int4 w4;
      w4.x = pk_bf16(acc[2*jt  ][0], acc[2*jt  ][1]);
      w4.y = pk_bf16(acc[2*jt  ][2], acc[2*jt  ][3]);
      w4.z = pk_bf16(acc[2*jt+1][0], acc[2*jt+1][1]);
      w4.w = pk_bf16(acc[2*jt+1][2], acc[2*jt+1][3]);
      pf[jt] = *(bf16x8*)&w4;
    }
    #pragma unroll
    for (int ct=0; ct<2; ++ct){
      f32x4 oe = {0.f,0.f,0.f,0.f}, oo = {0.f,0.f,0.f,0.f};
      #pragma unroll
      for (int jt=0;jt<8;jt+=2){
        bf16x8 ve = *(const bf16x8*)&Vf[((ct*8 + jt  )*64 + l)*8];
        bf16x8 vo = *(const bf16x8*)&Vf[((ct*8 + jt+1)*64 + l)*8];
        oe = __builtin_amdgcn_mfma_f32_16x16x32_bf16(ve, pf[jt  ], oe, 0,0,0);
        oo = __builtin_amdgcn_mfma_f32_16x16x32_bf16(vo, pf[jt+1], oo, 0,0,0);
      }
      int q = sub*16 + ln;
      int c = ct*16 + lg*4;
      short4 ov = { f2b((oe[0]+oo[0])*iv), f2b((oe[1]+oo[1])*iv),
                    f2b((oe[2]+oo[2])*iv), f2b((oe[3]+oo[3])*iv) };
      *(short4*)&O[(size_t)(i*N_ + q)*CH + h*CA + c] = ov;
    }
  }
}

extern "C" void kernel_launch(void* const* d_in, const int* in_sizes, int n_in,
                              void* d_out, int out_size, void* d_ws, size_t ws_size,
                              hipStream_t stream) {
  const float* z_in      = (const float*)d_in[0];
  const float* tm_lnin_w = (const float*)d_in[1];
  const float* tm_lnin_b = (const float*)d_in[2];
  const float* tm_ap_w   = (const float*)d_in[3];
  const float* tm_ap_b   = (const float*)d_in[4];
  const float* tm_ag_w   = (const float*)d_in[5];
  const float* tm_ag_b   = (const float*)d_in[6];
  const float* tm_bp_w   = (const float*)d_in[7];
  const float* tm_bp_b   = (const float*)d_in[8];
  const float* tm_bg_w   = (const float*)d_in[9];
  const float* tm_bg_b   = (const float*)d_in[10];
  const float* tm_g_w    = (const float*)d_in[11];
  const float* tm_g_b    = (const float*)d_in[12];
  const float* tm_zo_w   = (const float*)d_in[13];
  const float* tm_zo_b   = (const float*)d_in[14];
  const float* tm_lno_w  = (const float*)d_in[15];
  const float* tm_lno_b  = (const float*)d_in[16];
  const float* ta_ln_w   = (const float*)d_in[17];
  const float* ta_ln_b   = (const float*)d_in[18];
  const float* ta_q_w    = (const float*)d_in[19];
  const float* ta_k_w    = (const float*)d_in[20];
  const float* ta_v_w    = (const float*)d_in[21];
  const float* ta_b_w    = (const float*)d_in[22];
  const float* ta_g_w    = (const float*)d_in[23];
  const float* ta_g_b    = (const float*)d_in[24];
  const float* ta_o_w    = (const float*)d_in[25];
  const float* ta_o_b    = (const float*)d_in[26];
  const float* pt_ln_w   = (const float*)d_in[27];
  const float* pt_ln_b   = (const float*)d_in[28];
  const float* pt_1_w    = (const float*)d_in[29];
  const float* pt_1_b    = (const float*)d_in[30];
  const float* pt_2_w    = (const float*)d_in[31];
  const float* pt_2_b    = (const float*)d_in[32];

  float* z  = (float*)d_out;
  char* base = (char*)d_ws;
  const size_t MB = 1u<<20;
  short* wf  = (short*)base;                 // 30 x 32KB frag blobs
  short* Xb  = (short*)(base + 1*MB);        // 16MB bf16 [r][c]
  short* R1  = (short*)(base + 17*MB);
  short* R2  = (short*)(base + 33*MB);
  short* R3  = (short*)(base + 49*MB);       // Vt / packed A
  short* R4  = (short*)(base + 65*MB);
  short* Tb  = (short*)(base + 81*MB);       // 16MB bf16 [c][r]
  float* BSF = (float*)(base + 113*MB);      // 1MB

  #define SL(s) (wf + (size_t)(s)*16384)

  prep_weights<<<dim3(8,30), 256, 0, stream>>>(tm_ag_w, tm_ap_w, tm_bg_w, tm_bp_w,
                                               tm_g_w, tm_zo_w,
                                               ta_q_w, ta_k_w, ta_v_w, ta_g_w, ta_o_w,
                                               pt_1_w, pt_2_w, wf);

  // ---- triangle multiplication: outgoing (i=0), incoming (i=1) ----
  for (int i=0;i<2;i++){
    const float* zsrc = (i==0) ? z_in : z;
    ln_x<false><<<NN/4, 256, 0, stream>>>(zsrc, tm_lnin_w+i*CZ, tm_lnin_b+i*CZ, Xb);
    k_quad_gate<<<NN/128, 512, 0, stream>>>(Xb, SL(i*6+0), tm_ag_b+i*CH, SL(i*6+1), tm_ap_b+i*CH,
                                            SL(i*6+2), tm_bg_b+i*CH, SL(i*6+3), tm_bp_b+i*CH,
                                            R1, R2);
    if (i==0) pack_cxy<false><<<dim3(256,2), 256, 0, stream>>>(R1, R2, R3, R4);
    else      pack_cxy<true ><<<dim3(256,2), 256, 0, stream>>>(R1, R2, R3, R4);
    k_einsum<<<dim3(2,2,128), 512, 0, stream>>>(R3, R4, Tb);
    k_tri_finish<<<NN/128, 512, 0, stream>>>(Tb, Xb, SL(i*6+5), tm_zo_b+i*CZ,
                                             SL(i*6+4), tm_g_b+i*CZ,
                                             tm_lno_w+i*CH, tm_lno_b+i*CH, zsrc, z);
  }

  // ---- triangle attention: starting (i=0), ending (i=1, transposed coords) ----
  for (int i=0;i<2;i++){
    if (i==0) ln_x<false><<<NN/4, 256, 0, stream>>>(z, ta_ln_w, ta_ln_b, Xb);
    else      ln_x<true ><<<NN/4, 256, 0, stream>>>(z, ta_ln_w+CZ, ta_ln_b+CZ, Xb);
    k_qkv<<<NN/128, 512, 0, stream>>>(Xb, SL(12+i*5+0), 0.17677669529663687f,
                                      SL(12+i*5+1), SL(12+i*5+2), ta_b_w+i*CZ*H_,
                                      R1, R2, R3, BSF);
    attn_mfma<<<dim3(N_,H_), 256, 0, stream>>>(R1, R2, R3, BSF, R4);
    if (i==0) k_attn_out<false><<<NN/128, 512, 0, stream>>>(R4, Xb, SL(12+i*5+3), ta_g_b+i*H_*CA,
                                                            SL(12+i*5+4), ta_o_b+i*CZ, z);
    else      k_attn_out<true ><<<NN/128, 512, 0, stream>>>(R4, Xb, SL(12+i*5+3), ta_g_b+i*H_*CA,
                                                            SL(12+i*5+4), ta_o_b+i*CZ, z);
  }

  // ---- pair transition (LN fused) ----
  k_pt<<<NN/128, 512, 0, stream>>>(pt_ln_w, pt_ln_b, SL(22), pt_1_b, SL(26), pt_2_b, z);
}

// Round 9
// 516.080 us; speedup vs baseline: 8.0891x; 1.0364x over previous
//
#include <hip/hip_runtime.h>
#include <math.h>

#define N_  256
#define NN  65536
#define CZ  128
#define CH  128
#define H_  4
#define CA  32

typedef __attribute__((ext_vector_type(8))) short bf16x8;
typedef __attribute__((ext_vector_type(4))) float f32x4;

__device__ __forceinline__ float sigmoidf_(float x){ return 1.f/(1.f+__expf(-x)); }

__device__ __forceinline__ short f2b(float f){
  unsigned u = __float_as_uint(f);
  unsigned r = (u + 0x7fffu + ((u>>16)&1u)) >> 16;
  return (short)r;
}
__device__ __forceinline__ float b2f(short s){
  unsigned u = ((unsigned)(unsigned short)s) << 16;
  return __uint_as_float(u);
}
__device__ __forceinline__ unsigned pk_bf16(float lo, float hi){
  unsigned r;
  asm volatile("v_cvt_pk_bf16_f32 %0, %1, %2" : "=v"(r) : "v"(lo), "v"(hi));
  return r;
}

__device__ __forceinline__ void glds16(const void* g, const void* l){
  __builtin_amdgcn_global_load_lds((const __attribute__((address_space(1))) void*)g,
                                   (__attribute__((address_space(3))) void*)l, 16, 0, 0);
}

// K-row permutation: QK tile t, C-row m -> true key index j
__device__ __forceinline__ int Gperm(int t, int m){
  return ((t>>1)<<5) + ((m>>2)<<3) + ((t&1)<<2) + (m&3);
}

// ---------- weight prep: fp32 [K][N] slices -> bf16 B-fragment-packed blobs ----------
__global__ void __launch_bounds__(256) prep_weights(
    const float* tm_ag, const float* tm_ap, const float* tm_bg, const float* tm_bp,
    const float* tm_g, const float* tm_zo,
    const float* ta_q, const float* ta_k, const float* ta_v, const float* ta_g, const float* ta_o,
    const float* pt1, const float* pt2, short* Wf){
  int tid = threadIdx.x;
  int g = blockIdx.x*4 + (tid>>6);
  int l = tid & 63;
  int s = blockIdx.y;
  const float* src; int ldn = 128, koff = 0, noff = 0;
  if (s < 12){
    int i = s/6, w = s - i*6;
    switch(w){ case 0: src=tm_ag; break; case 1: src=tm_ap; break; case 2: src=tm_bg; break;
               case 3: src=tm_bp; break; case 4: src=tm_g;  break; default: src=tm_zo; }
    src += i*16384;
  } else if (s < 22){
    int t2 = s-12; int i = t2/5, w = t2 - i*5;
    switch(w){ case 0: src=ta_q; break; case 1: src=ta_k; break; case 2: src=ta_v; break;
               case 3: src=ta_g; break; default: src=ta_o; }
    src += i*16384;
  } else if (s < 26){
    src = pt1; ldn = 512; noff = (s-22)*128;
  } else {
    src = pt2; koff = (s-26)*128;
  }
  int nt = g>>2, ks = g&3;
  int n = noff + nt*16 + (l&15);
  int kb = koff + ks*32 + (l>>4)*8;
  short tmp[8];
  #pragma unroll
  for (int e=0;e<8;e++) tmp[e] = f2b(src[(size_t)(kb+e)*ldn + n]);
  short* dst = Wf + s*16384 + ((nt*4+ks)*64 + l)*8;
  *(short4*)dst     = *(short4*)&tmp[0];
  *(short4*)(dst+4) = *(short4*)&tmp[4];
}

// ---------- 4-wave GEMM helpers (256 threads, 64x128 tile) ----------
__device__ __forceinline__ void stage64(const short* __restrict__ g, short* xs, int r0, int tid){
  #pragma unroll
  for (int m=0;m<4;++m){
    int d = m*256 + tid;
    int row = d>>4, cw = d&15;
    glds16(&g[(size_t)(r0+row)*128 + ((cw ^ (row&15))<<3)], xs + (size_t)(d & ~63)*8);
  }
}

__device__ __forceinline__ bf16x8 ldsA(const short* xs, int row, int ch){
  return *(const bf16x8*)&xs[row*128 + ((ch ^ (row&15))<<3)];
}

// stage one K-half (64 of 128 K) of a weight frag-blob into a 16KB LDS buffer.
__device__ __forceinline__ void stageW(const short* __restrict__ wf, int h, short* wb, int tid){
  #pragma unroll
  for (int r=0;r<4;++r){
    int s = r*256 + tid;
    int ch = s>>6, ln = s&63;
    glds16(wf + (size_t)(((ch>>1)*4 + h*2 + (ch&1))*64 + ln)*8, wb + (size_t)(s & ~63)*8);
  }
}

// consume one K-half: A from swizzled LDS tile, B from wb half buffer
__device__ __forceinline__ void core_half(const short* xs, const short* wb, int h,
                                          int wm, int wn, int l, f32x4 (&acc)[2][4]){
  #pragma unroll
  for (int ks2=0; ks2<2; ++ks2){
    bf16x8 a[2], b[4];
    #pragma unroll
    for (int mt=0; mt<2; ++mt)
      a[mt] = ldsA(xs, wm*32 + mt*16 + (l&15), (h*2+ks2)*4 + (l>>4));
    #pragma unroll
    for (int nt=0; nt<4; ++nt)
      b[nt] = *(const bf16x8*)&wb[(size_t)(((wn*4+nt)*2 + ks2)*64 + l)*8];
    #pragma unroll
    for (int mt=0; mt<2; ++mt)
      #pragma unroll
      for (int nt=0; nt<4; ++nt)
        acc[mt][nt] = __builtin_amdgcn_mfma_f32_16x16x32_bf16(a[mt], b[nt], acc[mt][nt], 0,0,0);
  }
}

#define ZERO_ACC(A) { _Pragma("unroll") for(int _a=0;_a<2;_a++) _Pragma("unroll") for(int _b=0;_b<4;_b++) A[_a][_b]=(f32x4){0,0,0,0}; }

#define GEMM_PROLOG \
  int tid = threadIdx.x; int r0 = blockIdx.x*64; \
  int wid = tid>>6, l = tid&63; int wm = wid>>1, wn = wid&1; (void)r0;

#define EPI8 \
  int row = wm*32 + mt*16 + ((l>>4)<<2) + reg; \
  int col = wn*64 + nt*16 + (l&15);

#define FOR_EPI for (int mt=0;mt<2;++mt) for (int nt=0;nt<4;++nt) for (int reg=0;reg<4;++reg)

// scatter a packed bf16 C-tile (int2 per (mt,nt)) into swizzled [64][128] LDS
#define SCATTER_PACKED(P, LDSBUF) \
  _Pragma("unroll") \
  for (int mt=0;mt<2;++mt) \
    _Pragma("unroll") \
    for (int nt=0;nt<4;++nt){ \
      int row0 = wm*32 + mt*16 + ((l>>4)<<2); \
      int col  = wn*64 + nt*16 + (l&15); \
      unsigned lo = (unsigned)P[mt][nt].x, hi = (unsigned)P[mt][nt].y; \
      LDSBUF[(row0  )*128 + (((col>>3) ^ ((row0  )&15))<<3) + (col&7)] = (short)(lo & 0xffff); \
      LDSBUF[(row0+1)*128 + (((col>>3) ^ ((row0+1)&15))<<3) + (col&7)] = (short)(lo >> 16); \
      LDSBUF[(row0+2)*128 + (((col>>3) ^ ((row0+2)&15))<<3) + (col&7)] = (short)(hi & 0xffff); \
      LDSBUF[(row0+3)*128 + (((col>>3) ^ ((row0+3)&15))<<3) + (col&7)] = (short)(hi >> 16); \
    }

#define STORE_TILE(OUT, LDSBUF) \
  _Pragma("unroll") \
  for (int m2=0;m2<4;++m2){ \
    int d = m2*256 + tid; int row = d>>4, ch = d&15; \
    *(int4*)&OUT[(size_t)(r0+row)*128 + ch*8] = *(const int4*)&LDSBUF[row*128 + ((ch ^ (row&15))<<3)]; \
  }

// fused LayerNorm prologue: LN 64 rows of fp32 zsrc (TRANS: transposed gather)
// into swizzled bf16 xs. Contains 2 internal barriers; caller syncs after.
template<bool TRANS>
__device__ __forceinline__ void ln_prolog(const float* __restrict__ zsrc,
                                          const float* __restrict__ lnw,
                                          const float* __restrict__ lnb,
                                          int r0, int tid, short* xs,
                                          float* ps, float* pq, float* mu, float* iv){
  int rl = tid & 63, cq = tid >> 6;
  int r = r0 + rl;
  int sr = TRANS ? (((r&255)<<8) | (r>>8)) : r;
  float vals[32]; float s=0.f, q=0.f;
  const float* zr = &zsrc[(size_t)sr*128 + cq*32];
  #pragma unroll
  for (int cc=0; cc<32; cc+=4){
    float4 v4 = *(const float4*)&zr[cc];
    vals[cc]=v4.x; vals[cc+1]=v4.y; vals[cc+2]=v4.z; vals[cc+3]=v4.w;
    s += v4.x+v4.y+v4.z+v4.w;
    q += v4.x*v4.x+v4.y*v4.y+v4.z*v4.z+v4.w*v4.w;
  }
  ps[cq*64+rl]=s; pq[cq*64+rl]=q;
  __syncthreads();
  if (tid < 64){
    float ss = ps[tid]+ps[64+tid]+ps[128+tid]+ps[192+tid];
    float qq = pq[tid]+pq[64+tid]+pq[128+tid]+pq[192+tid];
    float m = ss*(1.f/128.f);
    float var = qq*(1.f/128.f) - m*m;
    mu[tid]=m; iv[tid]=rsqrtf(var+1e-5f);
  }
  __syncthreads();
  float m = mu[rl], rv = iv[rl];
  #pragma unroll
  for (int chq=0; chq<4; ++chq){
    short tmp[8];
    #pragma unroll
    for (int e=0;e<8;++e){
      int cc = chq*8+e, c = cq*32+cc;
      tmp[e] = f2b((vals[cc]-m)*rv*lnw[c] + lnb[c]);
    }
    int ch = cq*4 + chq;
    *(int4*)&xs[rl*128 + ((ch ^ (rl&15))<<3)] = *(int4*)tmp;
  }
}

// ---------- fused LN + quad-gate: Xb=LN(z); out1=sig(X@Wag+bag)*(X@Wap+bap); out2 likewise ----------
__global__ void __launch_bounds__(256,4) k_gg(const float* __restrict__ zsrc,
                                              const float* __restrict__ lnw, const float* __restrict__ lnb,
                                              const short* __restrict__ Wagf, const float* __restrict__ bag,
                                              const short* __restrict__ Wapf, const float* __restrict__ bap,
                                              const short* __restrict__ Wbgf, const float* __restrict__ bbg,
                                              const short* __restrict__ Wbpf, const float* __restrict__ bbp,
                                              short* __restrict__ Xb,
                                              short* __restrict__ out1, short* __restrict__ out2){
  __shared__ short xs[8192];
  __shared__ short wb[2][8192];
  __shared__ float ps[256], pq[256], mu[64], iv[64];
  GEMM_PROLOG
  stageW(Wagf, 0, wb[0], tid);
  ln_prolog<false>(zsrc, lnw, lnb, r0, tid, xs, ps, pq, mu, iv);
  __syncthreads();
  STORE_TILE(Xb, xs)
  int2 o1[2][4], o2[2][4];
  {
    f32x4 ag[2][4]; ZERO_ACC(ag)
    stageW(Wagf,1,wb[1],tid); core_half(xs,wb[0],0,wm,wn,l,ag); __syncthreads();
    stageW(Wapf,0,wb[0],tid); core_half(xs,wb[1],1,wm,wn,l,ag); __syncthreads();
    f32x4 ap[2][4]; ZERO_ACC(ap)
    stageW(Wapf,1,wb[1],tid); core_half(xs,wb[0],0,wm,wn,l,ap); __syncthreads();
    stageW(Wbgf,0,wb[0],tid); core_half(xs,wb[1],1,wm,wn,l,ap); __syncthreads();
    #pragma unroll
    for (int mt=0;mt<2;++mt)
      #pragma unroll
      for (int nt=0;nt<4;++nt){
        int col = wn*64 + nt*16 + (l&15);
        float bgc = bag[col], bpc = bap[col];
        o1[mt][nt].x = (int)pk_bf16((ap[mt][nt][0]+bpc)*sigmoidf_(ag[mt][nt][0]+bgc),
                                    (ap[mt][nt][1]+bpc)*sigmoidf_(ag[mt][nt][1]+bgc));
        o1[mt][nt].y = (int)pk_bf16((ap[mt][nt][2]+bpc)*sigmoidf_(ag[mt][nt][2]+bgc),
                                    (ap[mt][nt][3]+bpc)*sigmoidf_(ag[mt][nt][3]+bgc));
      }
  }
  {
    f32x4 bg2[2][4]; ZERO_ACC(bg2)
    stageW(Wbgf,1,wb[1],tid); core_half(xs,wb[0],0,wm,wn,l,bg2); __syncthreads();
    stageW(Wbpf,0,wb[0],tid); core_half(xs,wb[1],1,wm,wn,l,bg2); __syncthreads();
    f32x4 bp2[2][4]; ZERO_ACC(bp2)
    stageW(Wbpf,1,wb[1],tid); core_half(xs,wb[0],0,wm,wn,l,bp2); __syncthreads();
    core_half(xs,wb[1],1,wm,wn,l,bp2);
    #pragma unroll
    for (int mt=0;mt<2;++mt)
      #pragma unroll
      for (int nt=0;nt<4;++nt){
        int col = wn*64 + nt*16 + (l&15);
        float bgc = bbg[col], bpc = bbp[col];
        o2[mt][nt].x = (int)pk_bf16((bp2[mt][nt][0]+bpc)*sigmoidf_(bg2[mt][nt][0]+bgc),
                                    (bp2[mt][nt][1]+bpc)*sigmoidf_(bg2[mt][nt][1]+bgc));
        o2[mt][nt].y = (int)pk_bf16((bp2[mt][nt][2]+bpc)*sigmoidf_(bg2[mt][nt][2]+bgc),
                                    (bp2[mt][nt][3]+bpc)*sigmoidf_(bg2[mt][nt][3]+bgc));
      }
  }
  __syncthreads();
  SCATTER_PACKED(o1, xs)
  __syncthreads();
  STORE_TILE(out1, xs)
  __syncthreads();
  SCATTER_PACKED(o2, xs)
  __syncthreads();
  STORE_TILE(out2, xs)
}

// ---------- fused LN + QKV + bias: Xb=LN(z±T); Q,K plain; V transposed; bias permuted ----------
template<bool TRANS>
__global__ void __launch_bounds__(256,4) k_qkv(const float* __restrict__ zsrc,
                                               const float* __restrict__ lnw, const float* __restrict__ lnb,
                                               const short* __restrict__ Wqf, float sq,
                                               const short* __restrict__ Wkf,
                                               const short* __restrict__ Wvf,
                                               const float* __restrict__ bw,
                                               short* __restrict__ Xb,
                                               short* __restrict__ out_q, short* __restrict__ out_k,
                                               short* __restrict__ Vt, float* __restrict__ BSF){
  __shared__ short xs[8192];
  __shared__ short wb[2][8192];
  __shared__ float ps[256], pq[256], mu[64], iv[64];
  GEMM_PROLOG
  stageW(Wqf, 0, wb[0], tid);
  ln_prolog<TRANS>(zsrc, lnw, lnb, r0, tid, xs, ps, pq, mu, iv);
  __syncthreads();
  STORE_TILE(Xb, xs)
  int2 oq[2][4], ok[2][4];
  f32x4 av[2][4];
  {
    f32x4 aq[2][4]; ZERO_ACC(aq)
    stageW(Wqf,1,wb[1],tid); core_half(xs,wb[0],0,wm,wn,l,aq); __syncthreads();
    stageW(Wkf,0,wb[0],tid); core_half(xs,wb[1],1,wm,wn,l,aq); __syncthreads();
    #pragma unroll
    for (int mt=0;mt<2;++mt)
      #pragma unroll
      for (int nt=0;nt<4;++nt){
        oq[mt][nt].x = (int)pk_bf16(aq[mt][nt][0]*sq, aq[mt][nt][1]*sq);
        oq[mt][nt].y = (int)pk_bf16(aq[mt][nt][2]*sq, aq[mt][nt][3]*sq);
      }
  }
  {
    f32x4 ak[2][4]; ZERO_ACC(ak)
    stageW(Wkf,1,wb[1],tid); core_half(xs,wb[0],0,wm,wn,l,ak); __syncthreads();
    stageW(Wvf,0,wb[0],tid); core_half(xs,wb[1],1,wm,wn,l,ak); __syncthreads();
    #pragma unroll
    for (int mt=0;mt<2;++mt)
      #pragma unroll
      for (int nt=0;nt<4;++nt){
        ok[mt][nt].x = (int)pk_bf16(ak[mt][nt][0], ak[mt][nt][1]);
        ok[mt][nt].y = (int)pk_bf16(ak[mt][nt][2], ak[mt][nt][3]);
      }
  }
  ZERO_ACC(av)
  stageW(Wvf,1,wb[1],tid); core_half(xs,wb[0],0,wm,wn,l,av); __syncthreads();
  core_half(xs,wb[1],1,wm,wn,l,av);
  // bias epilogue: thread (rl, hh) computes X[rl,:]@bw[:,hh]
  {
    int rl = tid & 63, hh = tid >> 6;
    float bacc = 0.f;
    #pragma unroll
    for (int ch=0; ch<16; ++ch){
      bf16x8 v = ldsA(xs, rl, ch);
      #pragma unroll
      for (int e=0;e<8;++e) bacc += b2f(v[e]) * bw[(ch*8+e)*H_ + hh];
    }
    int r = r0 + rl;
    int qq = r >> 8, j = r & 255;
    int t = ((j>>5)<<1) + ((j>>2)&1);
    int mm = (((j>>3)&3)<<2) + (j&3);
    int idx = (((hh*16 + (qq>>4))*16 + t) << 8) + (((mm>>2)*16 + (qq&15)) << 2) + (mm&3);
    BSF[idx] = bacc;
  }
  __syncthreads();   // xs free
  // V^T into xs as [c][64 j], chunk-XOR on j
  #pragma unroll
  for (int mt=0;mt<2;++mt)
    #pragma unroll
    for (int nt=0;nt<4;++nt){
      int rb  = wm*32 + mt*16 + ((l>>4)<<2);
      int col = wn*64 + nt*16 + (l&15);
      short4 s4 = { f2b(av[mt][nt][0]), f2b(av[mt][nt][1]), f2b(av[mt][nt][2]), f2b(av[mt][nt][3]) };
      *(short4*)&xs[col*64 + (((rb>>3) ^ (col&7))<<3) + (rb&7)] = s4;
    }
  __syncthreads();
  {
    int i = r0>>8, j0 = r0&255;
    #pragma unroll
    for (int m=0;m<4;++m){              // FIX: full [c 0..127] coverage (was m<2)
      int d = m*256 + tid;
      int c = d>>3, jch = d&7;
      int4 val = *(const int4*)&xs[c*64 + ((jch ^ (c&7))<<3)];
      *(int4*)&Vt[(size_t)((i*4 + (c>>5))*32 + (c&31))*256 + j0 + jch*8] = val;
    }
  }
  __syncthreads();
  SCATTER_PACKED(oq, xs)
  __syncthreads();
  STORE_TILE(out_q, xs)
  __syncthreads();
  SCATTER_PACKED(ok, xs)
  __syncthreads();
  STORE_TILE(out_k, xs)
}

// ---------- fused LN(T)+tri_finish: zout = zin + (LN_c(T)@Wz+bz)*sig(X@Wg+bg) ----------
__global__ void __launch_bounds__(256,3) k_tri_finish(const short* __restrict__ Tb,  // bf16 [c][r]
                                                      const short* __restrict__ X,
                                                      const short* __restrict__ Wzf, const float* __restrict__ bz,
                                                      const short* __restrict__ Wgf, const float* __restrict__ bg,
                                                      const float* __restrict__ lnw, const float* __restrict__ lnb,
                                                      const float* __restrict__ zin, float* __restrict__ zout){
  __shared__ short tt[8192];   // [c][64] staged, rewritten as LN'd [64][128]
  __shared__ short xs[8192];
  __shared__ short wb[2][8192];
  __shared__ float ps[256], pq[256], mu[64], iv[64];
  GEMM_PROLOG
  stageW(Wzf, 0, wb[0], tid);
  stage64(X, xs, r0, tid);
  #pragma unroll
  for (int m=0;m<4;++m){
    int d = m*256 + tid;
    int c = d>>3, jch = d&7;
    glds16(&Tb[(size_t)c*65536 + r0 + jch*8], tt + (size_t)(d & ~63)*8);
  }
  __syncthreads();
  int rl = tid & 63, cq = tid >> 6;
  float vals[32]; float s = 0.f, q = 0.f;
  #pragma unroll
  for (int cc=0; cc<32; ++cc){
    float v = b2f(tt[(cq*32+cc)*64 + rl]);
    vals[cc] = v; s += v; q += v*v;
  }
  ps[cq*64 + rl] = s; pq[cq*64 + rl] = q;
  __syncthreads();
  if (tid < 64){
    float ss = ps[tid]+ps[64+tid]+ps[128+tid]+ps[192+tid];
    float qq = pq[tid]+pq[64+tid]+pq[128+tid]+pq[192+tid];
    float m = ss * (1.f/128.f);
    float var = qq * (1.f/128.f) - m*m;
    mu[tid] = m; iv[tid] = rsqrtf(var + 1e-5f);
  }
  __syncthreads();
  {
    float m = mu[rl], rv = iv[rl];
    #pragma unroll
    for (int chq=0; chq<4; ++chq){
      short tmp[8];
      #pragma unroll
      for (int e=0;e<8;++e){
        int cc = chq*8 + e;
        int c = cq*32 + cc;
        tmp[e] = f2b((vals[cc]-m)*rv*lnw[c] + lnb[c]);
      }
      int ch = cq*4 + chq;
      *(int4*)&tt[rl*128 + ((ch ^ (rl&15))<<3)] = *(int4*)tmp;
    }
  }
  __syncthreads();
  f32x4 az[2][4], ag[2][4];
  ZERO_ACC(az) ZERO_ACC(ag)
  stageW(Wzf, 1, wb[1], tid); core_half(tt, wb[0], 0, wm, wn, l, az); __syncthreads();
  stageW(Wgf, 0, wb[0], tid); core_half(tt, wb[1], 1, wm, wn, l, az); __syncthreads();
  stageW(Wgf, 1, wb[1], tid); core_half(xs, wb[0], 0, wm, wn, l, ag); __syncthreads();
  core_half(xs, wb[1], 1, wm, wn, l, ag);
  FOR_EPI{
    EPI8
    size_t idx = (size_t)(r0+row)*128 + col;
    float v = (az[mt][nt][reg] + bz[col]) * sigmoidf_(ag[mt][nt][reg] + bg[col]);
    zout[idx] = zin[idx] + v;
  }
}

// ---------- z(±T) += ((O*sigmoid(X@Wg+bg)) @ Wo + bo) ----------
template<bool TRANS>
__global__ void __launch_bounds__(256,3) k_attn_out(const short* __restrict__ O,
                                                    const short* __restrict__ X,
                                                    const short* __restrict__ Wgf, const float* __restrict__ bg,
                                                    const short* __restrict__ Wof, const float* __restrict__ bo,
                                                    float* __restrict__ z){
  __shared__ short xs[8192];
  __shared__ short os[8192];
  __shared__ short wb[2][8192];
  GEMM_PROLOG
  stageW(Wgf, 0, wb[0], tid);
  stage64(X, xs, r0, tid);
  #pragma unroll
  for (int m=0;m<4;++m){
    int d = m*256 + tid;
    int row = d>>4, ch = d&15;
    glds16(&O[(size_t)(r0+row)*128 + ch*8], os + (size_t)(d & ~63)*8);
  }
  __syncthreads();
  f32x4 ag[2][4];
  ZERO_ACC(ag)
  stageW(Wgf, 1, wb[1], tid); core_half(xs, wb[0], 0, wm, wn, l, ag); __syncthreads();
  stageW(Wof, 0, wb[0], tid); core_half(xs, wb[1], 1, wm, wn, l, ag); __syncthreads();
  stageW(Wof, 1, wb[1], tid);
  FOR_EPI{
    EPI8
    float ov = b2f(os[row*128 + col]);
    float v = ov * sigmoidf_(ag[mt][nt][reg] + bg[col]);
    xs[row*128 + (((col>>3) ^ (row&15))<<3) + (col&7)] = f2b(v);
  }
  __syncthreads();
  f32x4 a2[2][4];
  ZERO_ACC(a2)
  core_half(xs, wb[0], 0, wm, wn, l, a2);
  core_half(xs, wb[1], 1, wm, wn, l, a2);
  FOR_EPI{
    EPI8
    int orow = r0+row;
    int zrow = TRANS ? (((orow&255)<<8) | (orow>>8)) : orow;
    z[(size_t)zrow*128 + col] += a2[mt][nt][reg] + bo[col];
  }
}

// ---------- pair transition with fused LN: z += relu(LN(z)@W1+b1)@W2 + b2 ----------
__global__ void __launch_bounds__(256,3) k_pt(const float* __restrict__ lnw, const float* __restrict__ lnb,
                                              const short* __restrict__ W1f, const float* __restrict__ b1,
                                              const short* __restrict__ W2f, const float* __restrict__ b2,
                                              float* __restrict__ z){
  __shared__ short xs[8192];
  __shared__ short hs[8192];
  __shared__ short wb[2][8192];
  __shared__ float ps[256], pq[256], mu[64], iv[64];
  GEMM_PROLOG
  stageW(W1f, 0, wb[0], tid);
  ln_prolog<false>(z, lnw, lnb, r0, tid, xs, ps, pq, mu, iv);
  __syncthreads();
  f32x4 a2[2][4];
  ZERO_ACC(a2)
  for (int m=0;m<4;++m){
    f32x4 a1[2][4];
    ZERO_ACC(a1)
    stageW(W1f + m*16384, 1, wb[1], tid); core_half(xs, wb[0], 0, wm, wn, l, a1); __syncthreads();
    stageW(W2f + m*16384, 0, wb[0], tid); core_half(xs, wb[1], 1, wm, wn, l, a1); __syncthreads();
    stageW(W2f + m*16384, 1, wb[1], tid);
    FOR_EPI{
      EPI8
      float v = fmaxf(a1[mt][nt][reg] + b1[m*128 + col], 0.f);
      hs[row*128 + (((col>>3) ^ (row&15))<<3) + (col&7)] = f2b(v);
    }
    __syncthreads();
    core_half(hs, wb[0], 0, wm, wn, l, a2);
    __syncthreads();
    if (m<3) stageW(W1f + (m+1)*16384, 0, wb[0], tid);
    core_half(hs, wb[1], 1, wm, wn, l, a2);
    __syncthreads();
  }
  FOR_EPI{
    EPI8
    z[(size_t)(r0+row)*128 + col] += a2[mt][nt][reg] + b2[col];
  }
}

// ---------- pack: bf16 [r][c] -> per-channel bf16 [c][x][y]; r = TR ? y*256+x : x*256+y ----------
template<bool TR>
__global__ void __launch_bounds__(256) pack_cxy(const short* __restrict__ inA, const short* __restrict__ inB,
                                                short* __restrict__ outA, short* __restrict__ outB){
  __shared__ short tile[256*144];
  const short* in = blockIdx.y ? inB : inA;
  short* out      = blockIdx.y ? outB : outA;
  int x = blockIdx.x, tid = threadIdx.x;
  #pragma unroll
  for (int m=0;m<16;++m){
    int idx = m*256 + tid;
    int y = idx>>4, c0 = (idx&15)*8;
    int r = TR ? (y*256 + x) : (x*256 + y);
    *(int4*)&tile[y*144 + c0] = *(const int4*)&in[(size_t)r*128 + c0];
  }
  __syncthreads();
  int c = tid & 127, yh = tid >> 7;
  short* ob = out + (size_t)c*65536 + x*256 + yh*128;
  #pragma unroll
  for (int yc=0; yc<16; ++yc){
    short tmp[8];
    #pragma unroll
    for (int e=0;e<8;e++) tmp[e] = tile[(yh*128 + yc*8 + e)*144 + c];
    *(int4*)&ob[yc*8] = *(int4*)tmp;
  }
}

// ---------- triangle einsum, double-buffered staging (512 thr, 128x128 tile) ----------
__global__ void __launch_bounds__(512,4) k_einsum(const short* __restrict__ Ab,
                                                  const short* __restrict__ Bb,
                                                  short* __restrict__ Tb){
  __shared__ short as[2][128*64];
  __shared__ short bs[2][128*64];
  int c = blockIdx.z;
  int i0 = blockIdx.x*128, j0 = blockIdx.y*128;
  const short* A = Ab + (size_t)c*65536;
  const short* B = Bb + (size_t)c*65536;
  int tid = threadIdx.x;
  int wid = tid>>6, l = tid&63; int wm = wid>>1, wn = wid&1;
  f32x4 acc[2][4];
  ZERO_ACC(acc)

  #define ESTAGE(buf, kt) { \
    _Pragma("unroll") \
    for (int m_=0;m_<2;++m_){ \
      int d_ = m_*512 + tid; \
      int row_ = d_>>3, cw_ = d_&7; \
      glds16(&A[(size_t)(i0+row_)*256 + (kt)*64 + ((cw_ ^ (row_&7))<<3)], &as[buf][(d_ & ~63)*8]); \
      glds16(&B[(size_t)(j0+row_)*256 + (kt)*64 + ((cw_ ^ (row_&7))<<3)], &bs[buf][(d_ & ~63)*8]); \
    } }

  ESTAGE(0, 0)
  __syncthreads();
  for (int kt=0; kt<4; ++kt){
    int cur = kt & 1;
    if (kt < 3) ESTAGE(cur^1, kt+1)
    #pragma unroll
    for (int ks=0; ks<2; ++ks){
      bf16x8 a[2], b[4];
      #pragma unroll
      for (int mt=0; mt<2; ++mt){
        int row = wm*32 + mt*16 + (l&15);
        int ch  = (ks*4 + (l>>4)) ^ (row&7);
        a[mt] = *(const bf16x8*)&as[cur][row*64 + ch*8];
      }
      #pragma unroll
      for (int nt=0; nt<4; ++nt){
        int row = wn*64 + nt*16 + (l&15);
        int ch  = (ks*4 + (l>>4)) ^ (row&7);
        b[nt] = *(const bf16x8*)&bs[cur][row*64 + ch*8];
      }
      #pragma unroll
      for (int mt=0; mt<2; ++mt)
        #pragma unroll
        for (int nt=0; nt<4; ++nt)
          acc[mt][nt] = __builtin_amdgcn_mfma_f32_16x16x32_bf16(a[mt], b[nt], acc[mt][nt], 0,0,0);
    }
    __syncthreads();
  }
  short* To = Tb + (size_t)c*65536;
  FOR_EPI{
    int row = wm*32 + mt*16 + ((l>>4)<<2) + reg;
    int col = wn*64 + nt*16 + (l&15);
    To[(size_t)(i0+row)*256 + j0+col] = f2b(acc[mt][nt][reg]);
  }
}

// ---------- bf16 MFMA flash attention, Gperm-K, reg-Q, transposed-V, no P LDS ----------
__global__ void __launch_bounds__(256, 3) attn_mfma(const short* __restrict__ Qg,
                                                    const short* __restrict__ Kg,
                                                    const short* __restrict__ Vt,
                                                    const float* __restrict__ BSF,
                                                    short* __restrict__ O){
  __shared__ short Kf[8192];
  __shared__ short Vf[8192];
  int i = blockIdx.x, h = blockIdx.y;
  int tid = threadIdx.x;
  #pragma unroll
  for (int m=0;m<4;++m){
    int d = m*256 + tid;
    int t = d>>6, ll = d&63;
    glds16(&Kg[(size_t)(i*N_ + Gperm(t, ll&15))*CH + h*CA + ((ll>>4)<<3)],
           Kf + (size_t)(d & ~63)*8);
    glds16(&Vt[(size_t)(((i*H_ + h)*CA) + ((t>>3)<<4) + (ll&15))*N_ + ((t&7)<<5) + ((ll>>4)<<3)],
           Vf + (size_t)(d & ~63)*8);
  }
  __syncthreads();

  int wid = tid >> 6, l = tid & 63;
  int lg = l >> 4, ln = l & 15;

  for (int ss=0; ss<4; ++ss){
    int sub = wid*4 + ss;
    bf16x8 qfrag = *(const bf16x8*)&Qg[(size_t)(i*N_ + sub*16 + ln)*CH + h*CA + (lg<<3)];
    const float* bb = BSF + (size_t)(h*16 + sub)*4096 + (l<<2);
    f32x4 acc[16];
    #pragma unroll
    for (int t=0;t<16;t++) acc[t] = *(const f32x4*)&bb[t<<8];
    #pragma unroll
    for (int t=0;t<16;t++){
      bf16x8 kf = *(const bf16x8*)&Kf[t*512 + l*8];
      acc[t] = __builtin_amdgcn_mfma_f32_16x16x32_bf16(kf, qfrag, acc[t], 0,0,0);
    }
    float mx = -1e30f;
    #pragma unroll
    for (int t=0;t<16;t++)
      mx = fmaxf(mx, fmaxf(fmaxf(acc[t][0],acc[t][1]), fmaxf(acc[t][2],acc[t][3])));
    mx = fmaxf(mx, __shfl_xor(mx,16,64));
    mx = fmaxf(mx, __shfl_xor(mx,32,64));
    float sum = 0.f;
    #pragma unroll
    for (int t=0;t<16;t++){
      #pragma unroll
      for (int r=0;r<4;r++){ float p = __expf(acc[t][r]-mx); acc[t][r]=p; sum += p; }
    }
    sum += __shfl_xor(sum,16,64);
    sum += __shfl_xor(sum,32,64);
    float iv = 1.0f / sum;
    bf16x8 pf[8];
    #pragma unroll
    for (int jt=0;jt<8;jt++){
      int4 w4;
      w4.x = pk_bf16(acc[2*jt  ][0], acc[2*jt  ][1]);
      w4.y = pk_bf16(acc[2*jt  ][2], acc[2*jt  ][3]);
      w4.z = pk_bf16(acc[2*jt+1][0], acc[2*jt+1][1]);
      w4.w = pk_bf16(acc[2*jt+1][2], acc[2*jt+1][3]);
      pf[jt] = *(bf16x8*)&w4;
    }
    #pragma unroll
    for (int ct=0; ct<2; ++ct){
      f32x4 oe = {0.f,0.f,0.f,0.f}, oo = {0.f,0.f,0.f,0.f};
      #pragma unroll
      for (int jt=0;jt<8;jt+=2){
        bf16x8 ve = *(const bf16x8*)&Vf[((ct*8 + jt  )*64 + l)*8];
        bf16x8 vo = *(const bf16x8*)&Vf[((ct*8 + jt+1)*64 + l)*8];
        oe = __builtin_amdgcn_mfma_f32_16x16x32_bf16(ve, pf[jt  ], oe, 0,0,0);
        oo = __builtin_amdgcn_mfma_f32_16x16x32_bf16(vo, pf[jt+1], oo, 0,0,0);
      }
      int q = sub*16 + ln;
      int c = ct*16 + lg*4;
      short4 ov = { f2b((oe[0]+oo[0])*iv), f2b((oe[1]+oo[1])*iv),
                    f2b((oe[2]+oo[2])*iv), f2b((oe[3]+oo[3])*iv) };
      *(short4*)&O[(size_t)(i*N_ + q)*CH + h*CA + c] = ov;
    }
  }
}

extern "C" void kernel_launch(void* const* d_in, const int* in_sizes, int n_in,
                              void* d_out, int out_size, void* d_ws, size_t ws_size,
                              hipStream_t stream) {
  const float* z_in      = (const float*)d_in[0];
  const float* tm_lnin_w = (const float*)d_in[1];
  const float* tm_lnin_b = (const float*)d_in[2];
  const float* tm_ap_w   = (const float*)d_in[3];
  const float* tm_ap_b   = (const float*)d_in[4];
  const float* tm_ag_w   = (const float*)d_in[5];
  const float* tm_ag_b   = (const float*)d_in[6];
  const float* tm_bp_w   = (const float*)d_in[7];
  const float* tm_bp_b   = (const float*)d_in[8];
  const float* tm_bg_w   = (const float*)d_in[9];
  const float* tm_bg_b   = (const float*)d_in[10];
  const float* tm_g_w    = (const float*)d_in[11];
  const float* tm_g_b    = (const float*)d_in[12];
  const float* tm_zo_w   = (const float*)d_in[13];
  const float* tm_zo_b   = (const float*)d_in[14];
  const float* tm_lno_w  = (const float*)d_in[15];
  const float* tm_lno_b  = (const float*)d_in[16];
  const float* ta_ln_w   = (const float*)d_in[17];
  const float* ta_ln_b   = (const float*)d_in[18];
  const float* ta_q_w    = (const float*)d_in[19];
  const float* ta_k_w    = (const float*)d_in[20];
  const float* ta_v_w    = (const float*)d_in[21];
  const float* ta_b_w    = (const float*)d_in[22];
  const float* ta_g_w    = (const float*)d_in[23];
  const float* ta_g_b    = (const float*)d_in[24];
  const float* ta_o_w    = (const float*)d_in[25];
  const float* ta_o_b    = (const float*)d_in[26];
  const float* pt_ln_w   = (const float*)d_in[27];
  const float* pt_ln_b   = (const float*)d_in[28];
  const float* pt_1_w    = (const float*)d_in[29];
  const float* pt_1_b    = (const float*)d_in[30];
  const float* pt_2_w    = (const float*)d_in[31];
  const float* pt_2_b    = (const float*)d_in[32];

  float* z  = (float*)d_out;
  char* base = (char*)d_ws;
  const size_t MB = 1u<<20;
  short* wf  = (short*)base;                 // 30 x 32KB frag blobs
  short* Xb  = (short*)(base + 1*MB);        // 16MB bf16 [r][c]
  short* R1  = (short*)(base + 17*MB);
  short* R2  = (short*)(base + 33*MB);
  short* R3  = (short*)(base + 49*MB);       // Vt / packed A
  short* R4  = (short*)(base + 65*MB);
  short* Tb  = (short*)(base + 81*MB);       // 16MB bf16 [c][r]
  float* BSF = (float*)(base + 113*MB);      // 1MB

  #define SL(s) (wf + (size_t)(s)*16384)

  prep_weights<<<dim3(8,30), 256, 0, stream>>>(tm_ag_w, tm_ap_w, tm_bg_w, tm_bp_w,
                                               tm_g_w, tm_zo_w,
                                               ta_q_w, ta_k_w, ta_v_w, ta_g_w, ta_o_w,
                                               pt_1_w, pt_2_w, wf);

  // ---- triangle multiplication: outgoing (i=0), incoming (i=1) ----
  for (int i=0;i<2;i++){
    const float* zsrc = (i==0) ? z_in : z;
    k_gg<<<NN/64, 256, 0, stream>>>(zsrc, tm_lnin_w+i*CZ, tm_lnin_b+i*CZ,
                                    SL(i*6+0), tm_ag_b+i*CH, SL(i*6+1), tm_ap_b+i*CH,
                                    SL(i*6+2), tm_bg_b+i*CH, SL(i*6+3), tm_bp_b+i*CH,
                                    Xb, R1, R2);
    if (i==0) pack_cxy<false><<<dim3(256,2), 256, 0, stream>>>(R1, R2, R3, R4);
    else      pack_cxy<true ><<<dim3(256,2), 256, 0, stream>>>(R1, R2, R3, R4);
    k_einsum<<<dim3(2,2,128), 512, 0, stream>>>(R3, R4, Tb);
    k_tri_finish<<<NN/64, 256, 0, stream>>>(Tb, Xb, SL(i*6+5), tm_zo_b+i*CZ,
                                            SL(i*6+4), tm_g_b+i*CZ,
                                            tm_lno_w+i*CH, tm_lno_b+i*CH, zsrc, z);
  }

  // ---- triangle attention: starting (i=0), ending (i=1, transposed coords) ----
  for (int i=0;i<2;i++){
    if (i==0)
      k_qkv<false><<<NN/64, 256, 0, stream>>>(z, ta_ln_w, ta_ln_b,
                                              SL(12+0), 0.17677669529663687f, SL(12+1), SL(12+2),
                                              ta_b_w, Xb, R1, R2, R3, BSF);
    else
      k_qkv<true ><<<NN/64, 256, 0, stream>>>(z, ta_ln_w+CZ, ta_ln_b+CZ,
                                              SL(17+0), 0.17677669529663687f, SL(17+1), SL(17+2),
                                              ta_b_w+CZ*H_, Xb, R1, R2, R3, BSF);
    attn_mfma<<<dim3(N_,H_), 256, 0, stream>>>(R1, R2, R3, BSF, R4);
    if (i==0) k_attn_out<false><<<NN/64, 256, 0, stream>>>(R4, Xb, SL(12+3), ta_g_b,
                                                           SL(12+4), ta_o_b, z);
    else      k_attn_out<true ><<<NN/64, 256, 0, stream>>>(R4, Xb, SL(17+3), ta_g_b+H_*CA,
                                                           SL(17+4), ta_o_b+CZ, z);
  }

  // ---- pair transition (LN fused) ----
  k_pt<<<NN/64, 256, 0, stream>>>(pt_ln_w, pt_ln_b, SL(22), pt_1_b, SL(26), pt_2_b, z);
}